// Round 3
// baseline (758.413 us; speedup 1.0000x reference)
//
#include <hip/hip_runtime.h>
#include <math.h>

// B=8, m=197, dim=512, heads=8, depth=2, F=8, tdim=1576, cdim=64, ncls=1000.
namespace {

typedef unsigned short u16;
typedef __attribute__((ext_vector_type(8))) short bf16x8;
typedef __attribute__((ext_vector_type(4))) float f32x4;

constexpr int NB = 8, NM = 197, ND = 512, NH = 8, NTD = 1576, NC = 64;
constexpr long XSZ = (long)NB * NM * ND;        // 806912
constexpr long QSZ = (long)NH * XSZ;            // 6455296 (h, b*m, e)
constexpr long TABSZ = 50432;                   // 197*256 == 64*788
constexpr int MP = 208;                         // padded 197 (16B-aligned bf16 rows)

__device__ __forceinline__ u16 f2bf(float f) {
  union { float f; unsigned u; } v; v.f = f;
  unsigned r = v.u + 0x7FFF + ((v.u >> 16) & 1);
  return (u16)(r >> 16);
}
__device__ __forceinline__ void async_cp16(const void* g, void* l) {
  __builtin_amdgcn_global_load_lds((const __attribute__((address_space(1))) unsigned*)g,
                                   (__attribute__((address_space(3))) unsigned*)l, 16, 0, 0);
}

// Bijective XCD-chunk swizzle (m204).
__device__ __forceinline__ int xcd_swz(int orig, int nwg) {
  int q = nwg >> 3, r = nwg & 7, x = orig & 7, i = orig >> 3;
  return (x < r ? x * (q + 1) : r * (q + 1) + (x - r) * q) + i;
}
__device__ __forceinline__ int swz_flat() {
  int nwg = gridDim.x * gridDim.y * gridDim.z;
  int orig = blockIdx.x + gridDim.x * (blockIdx.y + gridDim.y * blockIdx.z);
  return xcd_swz(orig, nwg);
}

// ---------------------------------------------------------------------------
// Single-output MFMA GEMM core: acc += A(M x KL) * B^T(N x KL), 128x128 tile,
// BK=32, depth-2 prefetch, 3-slot LDS ring, raw s_barrier + counted vmcnt.
__device__ __forceinline__ void gemm_core(
    const u16* __restrict__ A, int lda, int M, int row0,
    const u16* __restrict__ B, int ldb, int N, int col0,
    int KL, u16* As, u16* Bs, f32x4 (&acc)[4][4],
    int tid, int wm, int wn, int l15, int quad) {
  const int nfull = KL >> 5, tail = KL & 31;
  const int r = tid >> 2;
  const int cs = (((tid & 3) ^ ((r >> 1) & 3)) << 3);
  int gr0 = row0 + r;      if (gr0 >= M) gr0 = M - 1;
  int gr1 = row0 + r + 64; if (gr1 >= M) gr1 = M - 1;
  int gc0 = col0 + r;      if (gc0 >= N) gc0 = N - 1;
  int gc1 = col0 + r + 64; if (gc1 >= N) gc1 = N - 1;
  const u16* pa0 = A + (long)gr0 * lda + cs;
  const u16* pa1 = A + (long)gr1 * lda + cs;
  const u16* pb0 = B + (long)gc0 * ldb + cs;
  const u16* pb1 = B + (long)gc1 * ldb + cs;
  const int lb0 = (tid & ~63) * 8;
  const int lb1 = lb0 + 2048;

  auto stage = [&](int k0, int bi) {
    async_cp16(pa0 + k0, &As[bi + lb0]);
    async_cp16(pa1 + k0, &As[bi + lb1]);
    async_cp16(pb0 + k0, &Bs[bi + lb0]);
    async_cp16(pb1 + k0, &Bs[bi + lb1]);
  };
  auto compute = [&](int bi) {
    bf16x8 af[4], bg[4];
#pragma unroll
    for (int i = 0; i < 4; i++) {
      int row = wm * 64 + i * 16 + l15;
      af[i] = *(const bf16x8*)&As[bi + row * 32 + ((quad ^ ((row >> 1) & 3)) << 3)];
    }
#pragma unroll
    for (int j = 0; j < 4; j++) {
      int row = wn * 64 + j * 16 + l15;
      bg[j] = *(const bf16x8*)&Bs[bi + row * 32 + ((quad ^ ((row >> 1) & 3)) << 3)];
    }
#pragma unroll
    for (int i = 0; i < 4; i++)
#pragma unroll
      for (int j = 0; j < 4; j++)
        acc[i][j] = __builtin_amdgcn_mfma_f32_16x16x32_bf16(af[i], bg[j], acc[i][j], 0, 0, 0);
  };

  if (nfull > 0) {
    stage(0, 0);
    if (nfull > 1) stage(32, 4096);
    for (int ch = 0; ch < nfull; ch++) {
      if (ch + 1 < nfull) {
        asm volatile("s_waitcnt vmcnt(4)" ::: "memory");
      } else {
        asm volatile("s_waitcnt vmcnt(0)" ::: "memory");
      }
      __builtin_amdgcn_s_barrier();
      if (ch + 2 < nfull) stage((ch + 2) << 5, ((ch + 2) % 3) * 4096);
      compute((ch % 3) * 4096);
    }
  }
  if (tail) {
    const int tb = (nfull % 3) * 4096;
    const int k0f = nfull << 5;
    if (nfull > 0) __syncthreads();
    for (int idx2 = tid; idx2 < 4096; idx2 += 256) {
      int rr = idx2 >> 5, cc = idx2 & 31;
      int g = ((((cc >> 3) ^ ((rr >> 1) & 3)) << 3)) | (cc & 7);
      int grr = row0 + rr; if (grr >= M) grr = M - 1;
      int gcc = col0 + rr; if (gcc >= N) gcc = N - 1;
      As[tb + idx2] = (g < tail) ? A[(long)grr * lda + k0f + g] : (u16)0;
      Bs[tb + idx2] = (g < tail) ? B[(long)gcc * ldb + k0f + g] : (u16)0;
    }
    __syncthreads();
    compute(tb);
  }
}

// ---------------------------------------------------------------------------
// Dual-output MFMA GEMM core: one SHARED operand panel X staged once, two
// private operand panels Y1,Y2 -> two accumulators. 32 MFMA/wave/step.
// SHA=true : C1 = X*Y1^T, C2 = X*Y2^T (X is the M-side).
// SHA=false: C1 = Y1*X^T, C2 = Y2*X^T (X is the N-side).
// Same 3-slot ring / raw-barrier / counted-vmcnt skeleton; 6 loads/stage,
// steady-state vmcnt(6) (= one stage's loads kept in flight).
template <bool SHA>
__device__ __forceinline__ void gemm_core2(
    const u16* __restrict__ X, int ldx, int MX, int x0,
    const u16* __restrict__ Y1, const u16* __restrict__ Y2,
    int ldy, int MY, int y0,
    int KL, u16* Xs, u16* Y1s, u16* Y2s,
    f32x4 (&acc1)[4][4], f32x4 (&acc2)[4][4],
    int tid, int wm, int wn, int l15, int quad) {
  const int nfull = KL >> 5, tail = KL & 31;
  const int r = tid >> 2;
  const int cs = (((tid & 3) ^ ((r >> 1) & 3)) << 3);
  int gx0 = x0 + r;      if (gx0 >= MX) gx0 = MX - 1;
  int gx1 = x0 + r + 64; if (gx1 >= MX) gx1 = MX - 1;
  int gy0 = y0 + r;      if (gy0 >= MY) gy0 = MY - 1;
  int gy1 = y0 + r + 64; if (gy1 >= MY) gy1 = MY - 1;
  const u16* px0 = X + (long)gx0 * ldx + cs;
  const u16* px1 = X + (long)gx1 * ldx + cs;
  const u16* p10 = Y1 + (long)gy0 * ldy + cs;
  const u16* p11 = Y1 + (long)gy1 * ldy + cs;
  const u16* p20 = Y2 + (long)gy0 * ldy + cs;
  const u16* p21 = Y2 + (long)gy1 * ldy + cs;
  const int lb0 = (tid & ~63) * 8;
  const int lb1 = lb0 + 2048;

  auto stage = [&](int k0, int bi) {
    async_cp16(px0 + k0, &Xs[bi + lb0]);
    async_cp16(px1 + k0, &Xs[bi + lb1]);
    async_cp16(p10 + k0, &Y1s[bi + lb0]);
    async_cp16(p11 + k0, &Y1s[bi + lb1]);
    async_cp16(p20 + k0, &Y2s[bi + lb0]);
    async_cp16(p21 + k0, &Y2s[bi + lb1]);
  };
  auto compute = [&](int bi) {
    bf16x8 xf[4], y1f[4], y2f[4];
    const int xw = SHA ? wm : wn;   // shared operand's 64-row block
    const int yw = SHA ? wn : wm;   // private operands' 64-row block
#pragma unroll
    for (int i = 0; i < 4; i++) {
      int rx = xw * 64 + i * 16 + l15;
      xf[i] = *(const bf16x8*)&Xs[bi + rx * 32 + ((quad ^ ((rx >> 1) & 3)) << 3)];
      int ry = yw * 64 + i * 16 + l15;
      int so = ((quad ^ ((ry >> 1) & 3)) << 3);
      y1f[i] = *(const bf16x8*)&Y1s[bi + ry * 32 + so];
      y2f[i] = *(const bf16x8*)&Y2s[bi + ry * 32 + so];
    }
#pragma unroll
    for (int i = 0; i < 4; i++)
#pragma unroll
      for (int j = 0; j < 4; j++) {
        if (SHA) {
          acc1[i][j] = __builtin_amdgcn_mfma_f32_16x16x32_bf16(xf[i], y1f[j], acc1[i][j], 0, 0, 0);
          acc2[i][j] = __builtin_amdgcn_mfma_f32_16x16x32_bf16(xf[i], y2f[j], acc2[i][j], 0, 0, 0);
        } else {
          acc1[i][j] = __builtin_amdgcn_mfma_f32_16x16x32_bf16(y1f[i], xf[j], acc1[i][j], 0, 0, 0);
          acc2[i][j] = __builtin_amdgcn_mfma_f32_16x16x32_bf16(y2f[i], xf[j], acc2[i][j], 0, 0, 0);
        }
      }
  };

  if (nfull > 0) {
    stage(0, 0);
    if (nfull > 1) stage(32, 4096);
    for (int ch = 0; ch < nfull; ch++) {
      if (ch + 1 < nfull) {
        asm volatile("s_waitcnt vmcnt(6)" ::: "memory");
      } else {
        asm volatile("s_waitcnt vmcnt(0)" ::: "memory");
      }
      __builtin_amdgcn_s_barrier();
      if (ch + 2 < nfull) stage((ch + 2) << 5, ((ch + 2) % 3) * 4096);
      compute((ch % 3) * 4096);
    }
  }
  if (tail) {
    const int tb = (nfull % 3) * 4096;
    const int k0f = nfull << 5;
    if (nfull > 0) __syncthreads();
    for (int idx2 = tid; idx2 < 4096; idx2 += 256) {
      int rr = idx2 >> 5, cc = idx2 & 31;
      int g = ((((cc >> 3) ^ ((rr >> 1) & 3)) << 3)) | (cc & 7);
      int gxr = x0 + rr; if (gxr >= MX) gxr = MX - 1;
      int gyr = y0 + rr; if (gyr >= MY) gyr = MY - 1;
      Xs[tb + idx2]  = (g < tail) ? X[(long)gxr * ldx + k0f + g] : (u16)0;
      Y1s[tb + idx2] = (g < tail) ? Y1[(long)gyr * ldy + k0f + g] : (u16)0;
      Y2s[tb + idx2] = (g < tail) ? Y2[(long)gyr * ldy + k0f + g] : (u16)0;
    }
    __syncthreads();
    compute(tb);
  }
}

// ---------------------------------------------------------------------------
// init: RoPE tables + patch gather + cls fill, one launch. grid 5114 x 256.
// Spatial table is written INTERLEAVED (cos,sin) float2 into the cosP region
// for the fused qkv-epilogue RoPE.
__global__ void init_kernel(const float* __restrict__ img, const float* __restrict__ cls,
                            float* cosP, float* sinP, float* cosT, float* sinT,
                            u16* __restrict__ pimg, float* __restrict__ x) {
  long idx = (long)blockIdx.x * 256 + threadIdx.x;
  if (idx < 197 * 256) {
    int p = (int)(idx / 256), i = (int)(idx % 256);
    float theta = powf(10000.f, -2.f * ((float)i - 1.f) / 512.f);
    float a = (float)p * theta;
    cosP[2 * idx] = cosf(a); cosP[2 * idx + 1] = sinf(a);
    return;
  }
  long j = idx - 197 * 256;
  if (j < 64 * 788) {
    int p = (int)(j / 788), i = (int)(j % 788);
    float theta = powf(10000.f, -2.f * ((float)i - 1.f) / 1576.f);
    float a = (float)p * theta;
    cosT[j] = cosf(a); sinT[j] = sinf(a);
    return;
  }
  long k2 = j - 64 * 788;
  if (k2 < 1568L * 768) {
    int r = (int)(k2 / 768), k = (int)(k2 % 768);
    int b = r / 196, p = r - b * 196;
    int pi = p / 14, pj = p - pi * 14;
    int cc = k % 3, pq = k / 3, pp = pq >> 4, qq = pq & 15;
    pimg[k2] = f2bf(img[((long)(b * 3 + cc) * 224 + pi * 16 + pp) * 224 + pj * 16 + qq]);
    return;
  }
  long c2 = k2 - 1568L * 768;
  if (c2 < 8 * 512) {
    int b = (int)(c2 >> 9), e = (int)(c2 & 511);
    x[((long)b * NM) * ND + e] = cls[e];
  }
}

// ---------------------------------------------------------------------------
// Two-stage per-batch RMS.
__global__ void rms_part_kernel(const float* __restrict__ x, float* __restrict__ part64) {
  int i = blockIdx.x, b = blockIdx.y;
  const float* p = x + (long)b * NM * ND + (long)i * 12608;
  float s = 0.f;
  for (int j = threadIdx.x; j < 12608; j += 256) { float v = p[j]; s += v * v; }
  __shared__ float red[256];
  red[threadIdx.x] = s; __syncthreads();
  for (int off = 128; off; off >>= 1) {
    if (threadIdx.x < off) red[threadIdx.x] += red[threadIdx.x + off];
    __syncthreads();
  }
  if (threadIdx.x == 0) part64[b * 8 + i] = red[0];
}

__device__ __forceinline__ float rms_inv(const float* part64, int b) {
  float ssum = 0.f;
#pragma unroll
  for (int i = 0; i < 8; i++) ssum += part64[b * 8 + i];
  return sqrtf((float)(NM * ND) / ssum);
}

__global__ void rms_apply_kernel(const float* __restrict__ x, const float* __restrict__ scale,
                                 const float* __restrict__ part64, float* __restrict__ xn,
                                 u16* __restrict__ xnb) {
  long idx = (long)blockIdx.x * 256 + threadIdx.x;
  if (idx >= XSZ) return;
  int b = (int)(idx / (NM * ND));
  long md = idx % (NM * ND);
  float v = x[idx] * scale[md] * rms_inv(part64, b);
  xn[idx] = v;
  xnb[idx] = f2bf(v);
}

// Phase-B: writes xn and the permuted token matrix yb[(b*64+c)*1576 + f*197+mm].
__global__ void rms_apply_tok_kernel(const float* __restrict__ x, const float* __restrict__ scale,
                                     const float* __restrict__ part64, float* __restrict__ xn,
                                     u16* __restrict__ yb) {
  long idx = (long)blockIdx.x * 256 + threadIdx.x;
  if (idx >= XSZ) return;
  int b = (int)(idx / (NM * ND));
  long md = idx % (NM * ND);
  float v = x[idx] * scale[md] * rms_inv(part64, b);
  xn[idx] = v;
  int mm = (int)(md / ND), d = (int)(md % ND);
  int c = d >> 3, f = d & 7;
  yb[((long)b * 64 + c) * NTD + f * 197 + mm] = f2bf(v);
}

// ---------------------------------------------------------------------------
// Spatial QKV, one launch. grid (4,13,12), XCD-chunked.
// z<8 : merged q+k for head h=z. Shared A-panel = xnb (staged once), two
//       B slabs Wq[h], Wk[h] -> two accs. RoPE fused in epilogue.
// z>=8: merged v pair h0=2*(z-8), h0+1. Shared N-side panel = xnb, two
//       A slabs Wv[h0], Wv[h0+1] -> vt (h,b,e,m_pad).
__global__ __launch_bounds__(256, 2) void qkv_kernel(const u16* __restrict__ xnb,
                                                     const u16* __restrict__ WtL,
                                                     u16* __restrict__ q,
                                                     const float* __restrict__ csP) {
  int wg = swz_flat();
  int bx = wg & 3, tmp = wg >> 2;
  int by = tmp % 13, z = tmp / 13;
  __shared__ __align__(16) u16 Xs[3 * 4096];
  __shared__ __align__(16) u16 Y1s[3 * 4096];
  __shared__ __align__(16) u16 Y2s[3 * 4096];
  const int tid = threadIdx.x;
  const int lane = tid & 63, wave = tid >> 6;
  const int wm = wave >> 1, wn = wave & 1;
  const int l15 = lane & 15, quad = lane >> 4;
  f32x4 acc1[4][4] = {};
  f32x4 acc2[4][4] = {};

  if (z < 8) {
    int h = z;
    int row0 = by * 128, col0 = bx * 128;
    const u16* Bq = WtL + ((long)h) * 262144;
    const u16* Bk = WtL + ((long)(8 + h)) * 262144;
    gemm_core2<true>(xnb, 512, 1576, row0, Bq, Bk, 512, 512, col0, 512,
                     Xs, Y1s, Y2s, acc1, acc2, tid, wm, wn, l15, quad);
    const float2* cs2 = (const float2*)csP;
    long bq = (long)h * XSZ;
    long bk = QSZ + (long)h * XSZ;
#pragma unroll
    for (int i = 0; i < 4; i++)
#pragma unroll
      for (int j = 0; j < 4; j++)
#pragma unroll
        for (int reg = 0; reg < 4; reg++) {
          int gr = row0 + wm * 64 + i * 16 + quad * 4 + reg;
          int gc = col0 + wn * 64 + j * 16 + l15;
          float v1 = acc1[i][j][reg];
          float p1 = __shfl_xor(v1, 1);
          float v2 = acc2[i][j][reg];
          float p2 = __shfl_xor(v2, 1);
          int t = gr % 197;
          float2 cs = cs2[t * 256 + (gc >> 1)];
          float s1 = (gc & 1) ? -p1 * cs.y : p1 * cs.y;
          float s2 = (gc & 1) ? -p2 * cs.y : p2 * cs.y;
          if (gr < 1576) {
            q[bq + (long)gr * 512 + gc] = f2bf(v1 * cs.x + s1);
            q[bk + (long)gr * 512 + gc] = f2bf(v2 * cs.x + s2);
          }
        }
  } else {
    int h0 = 2 * (z - 8);
    int row0 = bx * 128, col0 = by * 128;
    const u16* A0 = WtL + ((long)(16 + h0)) * 262144;
    const u16* A1 = WtL + ((long)(16 + h0 + 1)) * 262144;
    gemm_core2<false>(xnb, 512, 1576, col0, A0, A1, 512, 512, row0, 512,
                      Xs, Y1s, Y2s, acc1, acc2, tid, wm, wn, l15, quad);
#pragma unroll
    for (int i = 0; i < 4; i++)
#pragma unroll
      for (int j = 0; j < 4; j++)
#pragma unroll
        for (int reg = 0; reg < 4; reg++) {
          int gr = row0 + wm * 64 + i * 16 + quad * 4 + reg;  // e
          int gc = col0 + wn * 64 + j * 16 + l15;             // b*197+mm
          if (gr < 512 && gc < 1576) {
            int b = gc / 197, mm = gc - b * 197;
            q[2 * QSZ + ((long)(h0 * 8 + b) * 512 + gr) * MP + mm] = f2bf(acc1[i][j][reg]);
            q[2 * QSZ + ((long)((h0 + 1) * 8 + b) * 512 + gr) * MP + mm] = f2bf(acc2[i][j][reg]);
          }
        }
  }
}

// ---------------------------------------------------------------------------
// Token QKV, one launch. grid (4,13,4), XCD-chunked.
// z<2 : merged tq+tk split-K partials (seg=z). Shared A-panel = yb rows,
//       two B slabs tWq, tWk -> tprt[0+seg] (tq), tprt[2+seg] (tk).
// z>=2: tv^T split-K (seg=z-2): C = tWv^T(1576x1576) @ yb^T -> tprt[4+seg].
__global__ __launch_bounds__(256, 2) void tok_qkv_kernel(const u16* __restrict__ yb,
                                                         const u16* __restrict__ tWt, int l,
                                                         float* __restrict__ tprt) {
  int wg = swz_flat();
  int bx = wg & 3, tmp = wg >> 2;
  int by = tmp % 13, z = tmp / 13;
  __shared__ __align__(16) u16 Xs[3 * 4096];
  __shared__ __align__(16) u16 Y1s[3 * 4096];
  __shared__ __align__(16) u16 Y2s[3 * 4096];
  const int tid = threadIdx.x;
  const int lane = tid & 63, wave = tid >> 6;
  const int wm = wave >> 1, wn = wave & 1;
  const int l15 = lane & 15, quad = lane >> 4;

  if (z < 2) {
    int seg = z;
    int kbeg = seg * 800, KL = seg ? 776 : 800;
    int row0 = bx * 128, col0 = by * 128;
    const u16* A = yb + kbeg;
    const u16* B1 = tWt + ((long)(0 * 2 + l)) * 2483776 + kbeg;
    const u16* B2 = tWt + ((long)(1 * 2 + l)) * 2483776 + kbeg;
    f32x4 acc1[4][4] = {};
    f32x4 acc2[4][4] = {};
    gemm_core2<true>(A, 1576, 512, row0, B1, B2, 1576, 1576, col0, KL,
                     Xs, Y1s, Y2s, acc1, acc2, tid, wm, wn, l15, quad);
    float* d1 = tprt + (long)(0 + seg) * XSZ;
    float* d2 = tprt + (long)(2 + seg) * XSZ;
#pragma unroll
    for (int i = 0; i < 4; i++)
#pragma unroll
      for (int j = 0; j < 4; j++)
#pragma unroll
        for (int reg = 0; reg < 4; reg++) {
          int gr = row0 + wm * 64 + i * 16 + quad * 4 + reg;
          int gc = col0 + wn * 64 + j * 16 + l15;
          if (gr < 512 && gc < 1576) {
            d1[(long)gr * 1576 + gc] = acc1[i][j][reg];
            d2[(long)gr * 1576 + gc] = acc2[i][j][reg];
          }
        }
  } else {
    int seg = z - 2;
    int kbeg = seg * 800, KL = seg ? 776 : 800;
    int row0 = by * 128, col0 = bx * 128;
    const u16* A = tWt + ((long)(4 + l)) * 2483776 + kbeg;
    const u16* B = yb + kbeg;
    f32x4 acc[4][4] = {};
    gemm_core(A, 1576, 1576, row0, B, 1576, 512, col0, KL, Xs, Y1s, acc,
              tid, wm, wn, l15, quad);
    float* dst = tprt + (long)(4 + seg) * XSZ;
#pragma unroll
    for (int i = 0; i < 4; i++)
#pragma unroll
      for (int j = 0; j < 4; j++)
#pragma unroll
        for (int reg = 0; reg < 4; reg++) {
          int gr = row0 + wm * 64 + i * 16 + quad * 4 + reg;
          int gc = col0 + wn * 64 + j * 16 + l15;
          if (gr < 1576 && gc < 512) dst[(long)gr * 512 + gc] = acc[i][j][reg];
        }
  }
}

// Reduce token split-K partials: rope(tq), rope(tk), transpose(tv) -> bf16.
// tqb layout contract: tkb = tqb + XSZ, tvt = tqb + 2*XSZ.
__global__ void token_finish_kernel(const float* __restrict__ tp,
                                    const float* __restrict__ cosT,
                                    const float* __restrict__ sinT,
                                    u16* __restrict__ tqb) {
  long idx = (long)blockIdx.x * 256 + threadIdx.x;
  if (idx >= XSZ) return;
  int r = (int)(idx / NTD), g = (int)(idx - (long)r * NTD);
  int t = r & 63, ii = g >> 1;
  float cv = cosT[(long)t * 788 + ii];
  float sv = sinT[(long)t * 788 + ii];
  long re = (long)r * NTD + (g & ~1), ro = re + 1;
  float ve = tp[re] + tp[XSZ + re], vo = tp[ro] + tp[XSZ + ro];
  tqb[idx] = f2bf((g & 1) ? (-ve * sv + vo * cv) : (ve * cv + vo * sv));
  ve = tp[2 * XSZ + re] + tp[3 * XSZ + re];
  vo = tp[2 * XSZ + ro] + tp[3 * XSZ + ro];
  tqb[XSZ + idx] = f2bf((g & 1) ? (-ve * sv + vo * cv) : (ve * cv + vo * sv));
  // tv: idx = g2*512 + r2 in the (1576 x 512) partial layout
  int g2 = (int)(idx >> 9), r2 = (int)(idx & 511);
  float v = tp[4 * XSZ + idx] + tp[5 * XSZ + idx];
  tqb[2 * XSZ + ((long)(r2 >> 6) * NTD + g2) * 64 + (r2 & 63)] = f2bf(v);
}

// ---------------------------------------------------------------------------
// Generic MFMA GEMM for the remaining shapes. XCD-chunked work mapping.
enum { EPI_BF16 = 0, EPI_F32 = 1, EPI_TOKPV = 3, EPI_PATCH = 4 };

template <int EPI>
__global__ __launch_bounds__(256) void mfma_gemm(
    const u16* __restrict__ A, const u16* __restrict__ B, void* __restrict__ Cv,
    const float* __restrict__ resid,
    int M, int N, int K, int lda, int ldb, int ldc, float alpha, int nz2,
    long aS2, long bS1, long bS2, long cS1, long cS2) {
  int wg = swz_flat();
  int bx = wg % gridDim.x; int tmp = wg / gridDim.x;
  int by = tmp % gridDim.y; int z = tmp / gridDim.y;
  int z1 = z / nz2, z2 = z - z1 * nz2;
  A += z2 * aS2;
  B += z1 * bS1 + z2 * bS2;
  __shared__ __align__(16) u16 As[3 * 4096];
  __shared__ __align__(16) u16 Bs[3 * 4096];
  const int tid = threadIdx.x;
  const int lane = tid & 63, wave = tid >> 6;
  const int wm = wave >> 1, wn = wave & 1;
  const int l15 = lane & 15, quad = lane >> 4;
  const int row0 = by * 128, col0 = bx * 128;
  f32x4 acc[4][4] = {};
  gemm_core(A, lda, M, row0, B, ldb, N, col0, K, As, Bs, acc, tid, wm, wn, l15, quad);

  float* Cf = (float*)Cv;
  u16* Ch = (u16*)Cv;
  const long cbase = z1 * cS1 + z2 * cS2;
#pragma unroll
  for (int i = 0; i < 4; i++)
#pragma unroll
    for (int j = 0; j < 4; j++)
#pragma unroll
      for (int reg = 0; reg < 4; reg++) {
        int gr = row0 + wm * 64 + i * 16 + quad * 4 + reg;
        int gc = col0 + wn * 64 + j * 16 + l15;
        if (gr >= M || gc >= N) continue;
        float vv = acc[i][j][reg] * alpha;
        if (EPI == EPI_BF16) {
          Ch[cbase + (long)gr * ldc + gc] = f2bf(vv);
        } else if (EPI == EPI_F32) {
          Cf[cbase + (long)gr * ldc + gc] = vv;
        } else if (EPI == EPI_TOKPV) {    // x[b][mm][c*8+f] = acc + xn
          int f = gc / 197, mm = gc - f * 197;
          long o = ((long)z2 * 197 + mm) * 512 + gr * 8 + f;
          Cf[o] = vv + resid[o];
        } else {                          // PATCH: x[b][1+p][gc] = acc + bias
          int b = gr / 196, p = gr - b * 196;
          Cf[((long)b * 197 + 1 + p) * 512 + gc] = vv + resid[gc];
        }
      }
}

// ---------------------------------------------------------------------------
// Token scores, split-K: grid (split=8, b=8). tsp[(s*8+b)][64][64] partials.
__global__ __launch_bounds__(256) void token_scores_kernel(const u16* __restrict__ tq,
                                                           const u16* __restrict__ tk,
                                                           float* __restrict__ tsp) {
  int s = blockIdx.x, b = blockIdx.y;
  const u16* A = tq + (long)b * 64 * NTD;
  const u16* B = tk + (long)b * 64 * NTD;
  __shared__ __align__(16) u16 As[64 * 32];
  __shared__ __align__(16) u16 Bs[64 * 32];
  int tid = threadIdx.x, lane = tid & 63, w = tid >> 6;
  int l15 = lane & 15, quad = lane >> 4;
  f32x4 acc[4] = {};
  int ch0 = s * 6, ch1 = (s == 7) ? 49 : s * 6 + 6;
  for (int ch = ch0; ch < ch1; ch++) {
    __syncthreads();
    int r = tid >> 2, slot = tid & 3;
    int c = ((slot ^ ((r >> 1) & 3)) << 3);
    async_cp16(A + (long)r * NTD + ch * 32 + c, &As[(tid & ~63) * 8]);
    async_cp16(B + (long)r * NTD + ch * 32 + c, &Bs[(tid & ~63) * 8]);
    __syncthreads();
    int row = w * 16 + l15;
    bf16x8 av = *(const bf16x8*)&As[row * 32 + ((quad ^ ((row >> 1) & 3)) << 3)];
#pragma unroll
    for (int j = 0; j < 4; j++) {
      int rb = j * 16 + l15;
      bf16x8 bv = *(const bf16x8*)&Bs[rb * 32 + ((quad ^ ((rb >> 1) & 3)) << 3)];
      acc[j] = __builtin_amdgcn_mfma_f32_16x16x32_bf16(av, bv, acc[j], 0, 0, 0);
    }
  }
  if (s == 7) {  // 8-element K tail
    __syncthreads();
    for (int idx = tid; idx < 64 * 32; idx += 256) {
      int r = idx >> 5, c = idx & 31;
      int g = ((((c >> 3) ^ ((r >> 1) & 3)) << 3)) | (c & 7);
      As[idx] = (g < 8) ? A[(long)r * NTD + 1568 + g] : (u16)0;
      Bs[idx] = (g < 8) ? B[(long)r * NTD + 1568 + g] : (u16)0;
    }
    __syncthreads();
    int row = w * 16 + l15;
    bf16x8 av = *(const bf16x8*)&As[row * 32 + ((quad ^ ((row >> 1) & 3)) << 3)];
#pragma unroll
    for (int j = 0; j < 4; j++) {
      int rb = j * 16 + l15;
      bf16x8 bv = *(const bf16x8*)&Bs[rb * 32 + ((quad ^ ((rb >> 1) & 3)) << 3)];
      acc[j] = __builtin_amdgcn_mfma_f32_16x16x32_bf16(av, bv, acc[j], 0, 0, 0);
    }
  }
  const float sc = rsqrtf(1576.f);
  float* dst = tsp + ((long)(s * 8 + b)) * 4096;
#pragma unroll
  for (int j = 0; j < 4; j++)
#pragma unroll
    for (int reg = 0; reg < 4; reg++) {
      int row = w * 16 + quad * 4 + reg, col = j * 16 + l15;
      dst[row * 64 + col] = acc[j][reg] * sc;
    }
}

// ---------------------------------------------------------------------------
// Spatial softmax: s fp32 (64,197,197) -> pb bf16 (64,197,208). 4 rows/block.
__global__ void softmax_spatial_kernel(const float* __restrict__ s, u16* __restrict__ pb) {
  int row = blockIdx.x * 4 + (threadIdx.x >> 6);
  int lane = threadIdx.x & 63;
  const float* p = s + (long)row * 197;
  int hb = row / 197, mm = row - hb * 197;
  u16* q = pb + (long)hb * 197 * MP + (long)mm * MP;
  float mx = -INFINITY;
  for (int j = lane; j < 197; j += 64) mx = fmaxf(mx, p[j]);
#pragma unroll
  for (int off = 32; off; off >>= 1) mx = fmaxf(mx, __shfl_xor(mx, off));
  float sum = 0.f;
  float ev[4];
  int cnt = 0;
  for (int j = lane; j < 197; j += 64) { ev[cnt] = expf(p[j] - mx); sum += ev[cnt]; cnt++; }
#pragma unroll
  for (int off = 32; off; off >>= 1) sum += __shfl_xor(sum, off);
  float inv = 1.f / sum;
  cnt = 0;
  for (int j = lane; j < 197; j += 64) { q[j] = f2bf(ev[cnt] * inv); cnt++; }
}

// Token softmax: sums 8 split-K partials, softmaxes, writes Pb bf16.
__global__ void softmax_token_kernel(const float* __restrict__ tsp, u16* __restrict__ Pb) {
  int row = blockIdx.x * 4 + (threadIdx.x >> 6);  // 0..511 = b*64+r
  int lane = threadIdx.x & 63;
  int b = row >> 6, r = row & 63;
  float v = 0.f;
#pragma unroll
  for (int p = 0; p < 8; p++) v += tsp[((long)(p * 8 + b)) * 4096 + r * 64 + lane];
  float mx = v;
#pragma unroll
  for (int off = 32; off; off >>= 1) mx = fmaxf(mx, __shfl_xor(mx, off));
  float e = expf(v - mx);
  float sum = e;
#pragma unroll
  for (int off = 32; off; off >>= 1) sum += __shfl_xor(sum, off);
  Pb[(long)row * 64 + lane] = f2bf(e / sum);
}

// ---------------------------------------------------------------------------
__global__ void attn_reduce_kernel(const float* __restrict__ part, const float* __restrict__ bias,
                                   const float* __restrict__ resid, float* __restrict__ x) {
  long idx = (long)blockIdx.x * 256 + threadIdx.x;
  if (idx >= XSZ) return;
  int col = (int)(idx % ND);
  float s = resid[idx] + bias[col];
#pragma unroll
  for (int h = 0; h < 8; h++) s += part[(long)h * XSZ + idx];
  x[idx] = s;
}

// ---------------------------------------------------------------------------
// Merged Wqkv (48 slabs, z = l*24 + w*8 + h) + attn_W (16 slabs: l*8 + i).
// grid (16,16,64).
__global__ void transpose_wa_kernel(const float* __restrict__ Wq, const float* __restrict__ Wk,
                                    const float* __restrict__ Wv, const float* __restrict__ attn_W,
                                    u16* __restrict__ Wt16, u16* __restrict__ Wat16) {
  int z = blockIdx.z;
  const float* src;
  u16* dst;
  long dld;
  if (z < 48) {
    int l = z / 24, rem = z - l * 24, w = rem >> 3, h = rem & 7;
    src = (w == 0 ? Wq : w == 1 ? Wk : Wv) + (long)(l * 8 + h) * 262144;
    dst = Wt16 + (long)z * 262144;
    dld = 512;
  } else {
    int za = z - 48, l = za >> 3, i = za & 7;   // 8 row-blocks per layer
    src = attn_W + (long)l * 4096 * 512 + (long)i * 512 * 512;
    dst = Wat16 + (long)l * 512 * 4096 + (long)i * 512;
    dld = 4096;
  }
  __shared__ float t[32][33];
  int c0 = blockIdx.x * 32, r0 = blockIdx.y * 32;
  int tx = threadIdx.x, ty = threadIdx.y;
#pragma unroll
  for (int i = 0; i < 4; i++)
    t[ty + i * 8][tx] = src[(long)(r0 + ty + i * 8) * 512 + c0 + tx];
  __syncthreads();
#pragma unroll
  for (int i = 0; i < 4; i++)
    dst[(long)(c0 + ty + i * 8) * dld + r0 + tx] = f2bf(t[tx][ty + i * 8]);
}

// Generic transpose fp32 (RxC) -> bf16 (CxR) (used for patch_W).
__global__ void transpose_bf16_kernel(const float* __restrict__ src, u16* __restrict__ dst,
                                      int R, int C) {
  __shared__ float t[32][33];
  int c0 = blockIdx.x * 32, r0 = blockIdx.y * 32;
  int tx = threadIdx.x, ty = threadIdx.y;
#pragma unroll
  for (int i = 0; i < 4; i++) {
    int r = r0 + ty + i * 8;
    if (r < R && c0 + tx < C) t[ty + i * 8][tx] = src[(long)r * C + c0 + tx];
  }
  __syncthreads();
#pragma unroll
  for (int i = 0; i < 4; i++) {
    int c = c0 + ty + i * 8;
    if (c < C && r0 + tx < R) dst[(long)c * R + r0 + tx] = f2bf(t[tx][ty + i * 8]);
  }
}

// Merged tWq/tWk/tWv transpose: grid (50,50,6), z = w*2 + l.
__global__ void t_transpose3_kernel(const float* __restrict__ Wq, const float* __restrict__ Wk,
                                    const float* __restrict__ Wv, u16* __restrict__ dst0) {
  int z = blockIdx.z;
  int w = z >> 1, l = z & 1;
  const float* src = (w == 0 ? Wq : w == 1 ? Wk : Wv) + (long)l * NTD * NTD;
  u16* d = dst0 + (long)z * NTD * NTD;
  __shared__ float t[32][33];
  int c0 = blockIdx.x * 32, r0 = blockIdx.y * 32;
  int tx = threadIdx.x, ty = threadIdx.y;
#pragma unroll
  for (int i = 0; i < 4; i++) {
    int r = r0 + ty + i * 8;
    if (r < NTD && c0 + tx < NTD) t[ty + i * 8][tx] = src[(long)r * NTD + c0 + tx];
  }
  __syncthreads();
#pragma unroll
  for (int i = 0; i < 4; i++) {
    int c = c0 + ty + i * 8;
    if (c < NTD && r0 + tx < NTD) d[(long)c * NTD + r0 + tx] = f2bf(t[tx][ty + i * 8]);
  }
}

// ---------------------------------------------------------------------------
// Fused cls LayerNorm + head GEMM. grid (4,8), 256 thr (LN redone per block).
__global__ void ln_head_kernel(const float* __restrict__ x, const float* __restrict__ g,
                               const float* __restrict__ bb, const float* __restrict__ W,
                               const float* __restrict__ hb, float* __restrict__ out) {
  int b = blockIdx.y, t = threadIdx.x;
  __shared__ float xs[512];
  __shared__ float red[256];
  float v0 = x[(long)b * NM * ND + t];
  float v1 = x[(long)b * NM * ND + 256 + t];
  red[t] = v0 + v1; __syncthreads();
  for (int o = 128; o; o >>= 1) { if (t < o) red[t] += red[t + o]; __syncthreads(); }
  float mu = red[0] / 512.f; __syncthreads();
  float d0 = v0 - mu, d1 = v1 - mu;
  red[t] = d0 * d0 + d1 * d1; __syncthreads();
  for (int o = 128; o; o >>= 1) { if (t < o) red[t] += red[t + o]; __syncthreads(); }
  float inv = rsqrtf(red[0] / 512.f + 1e-5f); __syncthreads();
  xs[t] = d0 * inv * g[t] + bb[t];
  xs[256 + t] = d1 * inv * g[256 + t] + bb[256 + t];
  __syncthreads();
  int n = blockIdx.x * 250 + t;
  if (t < 250 && n < 1000) {
    float acc = hb[n];
    for (int dd = 0; dd < 512; dd++) acc += xs[dd] * W[(long)dd * 1000 + n];
    out[(long)b * 1000 + n] = acc;
  }
}

}  // namespace

extern "C" void kernel_launch(void* const* d_in, const int* in_sizes, int n_in,
                              void* d_out, int out_size, void* d_ws, size_t ws_size,
                              hipStream_t stream) {
  const float* img     = (const float*)d_in[0];
  const float* patch_W = (const float*)d_in[1];
  const float* patch_b = (const float*)d_in[2];
  const float* cls_tok = (const float*)d_in[3];
  const float* rms_s   = (const float*)d_in[4];
  const float* Wq      = (const float*)d_in[5];
  const float* Wk      = (const float*)d_in[6];
  const float* Wv      = (const float*)d_in[7];
  const float* attn_W  = (const float*)d_in[8];
  const float* attn_b  = (const float*)d_in[9];
  const float* tWq     = (const float*)d_in[10];
  const float* tWk     = (const float*)d_in[11];
  const float* tWv     = (const float*)d_in[12];
  const float* ln_g    = (const float*)d_in[13];
  const float* ln_b    = (const float*)d_in[14];
  const float* head_W  = (const float*)d_in[15];
  const float* head_b  = (const float*)d_in[16];
  float* out = (float*)d_out;

  // ---- workspace layout (floats) ----
  float* base = (float*)d_ws;
  long off = 0;
  auto alloc = [&](long n) { float* r = base + off; off += (n + 15) & ~15L; return r; };
  float* cosP = alloc(TABSZ);       // interleaved (cos,sin) float2 table spans
  float* sinP = alloc(TABSZ);       //   cosP..sinP (2*TABSZ floats contiguous)
  float* cosT = alloc(TABSZ);
  float* sinT = alloc(TABSZ);
  float* x    = alloc(XSZ);
  float* xn   = alloc(XSZ);
  float* Wt_f   = alloc(6291456);   // 48 slabs 512x512 bf16, z = l*24+w*8+h
  float* Wat_f  = alloc(2097152);   // (l) 512x4096 bf16
  float* tWt_f  = alloc(7451328);   // (w,l) 1576x1576 bf16
  float* xnb_f  = alloc(XSZ / 2);
  float* pimg_f = alloc(602112);    // 1568x768 bf16
  float* pWt_f  = alloc(196608);    // 512x768 bf16
  float* U      = alloc(16885824);  // union region
  float* ff     = alloc(64);

  u16* Wt16  = (u16*)Wt_f;
  u16* Wat16 = (u16*)Wat_f;
  u16* tWt16 = (u16*)tWt_f;
  u16* xnb   = (u16*)xnb_f;
  u16* pimg  = (u16*)pimg_f;
  u16* pWt   = (u16*)pWt_f;
  // phase A overlay (contract: kk = q + QSZ, vt = q + 2*QSZ)
  u16* q   = (u16*)U;                 // 6455296 (h, b*m, e)
  u16* kk  = q + QSZ;                 // 6455296
  u16* vt  = kk + QSZ;                // 6815744 (h,b,e,m_pad)
  float* s = (float*)(vt + 6815744);  // 2483776 f (hb,197,197)
  u16* pb  = (u16*)(s + 2483776);     // 2622464 (hb,197,208)
  u16* o   = pb + 2622464;            // 6455296 (h, b*m, e)
  float* part = (float*)q;            // 8*XSZ fp32 (aliases dead q,kk)
  // phase B overlay (contract: tkb = tqb + XSZ, tvt = tqb + 2*XSZ)
  u16* yb     = (u16*)U;              // 806912 (b*64+c, 1576)
  float* tprt = (float*)(yb + XSZ);   // 6*XSZ fp32 split partials
  u16* tqb    = (u16*)(tprt + 6 * XSZ);
  u16* tvt    = tqb + 2 * XSZ;        // (b, 1576, 64)
  float* tsp  = (float*)(tvt + XSZ);  // 8 x 8 x 64 x 64
  u16* Pb     = (u16*)(tsp + 262144); // 8*64*64

  const float rs512 = 1.f / sqrtf(512.f);
  const dim3 tt(32, 8);

  // ---- setup ----
  init_kernel<<<5114, 256, 0, stream>>>(img, cls_tok, cosP, sinP, cosT, sinT, pimg, x);
  transpose_bf16_kernel<<<dim3(16, 24), tt, 0, stream>>>(patch_W, pWt, 768, 512);
  transpose_wa_kernel<<<dim3(16, 16, 64), tt, 0, stream>>>(Wq, Wk, Wv, attn_W, Wt16, Wat16);
  t_transpose3_kernel<<<dim3(50, 50, 6), tt, 0, stream>>>(tWq, tWk, tWv, tWt16);
  mfma_gemm<EPI_PATCH><<<dim3(4, 13, 1), 256, 0, stream>>>(
      pimg, pWt, x, patch_b, 1568, 512, 768, 768, 768, 512, 1.f, 1, 0, 0, 0, 0, 0);

  for (int l = 0; l < 2; l++) {
    const float* scale = rms_s + (long)l * NM * ND;
    // ---- spatial attention ----
    rms_part_kernel<<<dim3(8, 8), 256, 0, stream>>>(x, ff);
    rms_apply_kernel<<<3152, 256, 0, stream>>>(x, scale, ff, xn, xnb);

    // merged q+k (shared xnb panel) + merged v pairs; RoPE fused in epilogue
    qkv_kernel<<<dim3(4, 13, 12), 256, 0, stream>>>(xnb, Wt16 + (long)l * 24 * 262144, q, cosP);

    // scores (fp32, scaled)
    mfma_gemm<EPI_F32><<<dim3(2, 2, 64), 256, 0, stream>>>(
        q, kk, s, nullptr, 197, 197, 512, 512, 512, 197, rs512, 64,
        197L * 512, 0, 197L * 512, 0, 197L * 197);
    softmax_spatial_kernel<<<3152, 256, 0, stream>>>(s, pb);
    // o = P @ v
    mfma_gemm<EPI_BF16><<<dim3(4, 2, 64), 256, 0, stream>>>(
        pb, vt, o, nullptr, 197, 512, 197, MP, MP, 512, 1.f, 64,
        197L * MP, 0, 512L * MP, 0, 197L * 512);
    // attn-proj head partials
    mfma_gemm<EPI_F32><<<dim3(4, 13, 8), 256, 0, stream>>>(
        o, Wat16 + (long)l * 2097152, part, nullptr, 1576, 512, 512, 512, 4096, 512, 1.f, 8,
        XSZ, 0, 512, 0, XSZ);
    attn_reduce_kernel<<<3152, 256, 0, stream>>>(part, attn_b + (long)l * ND, xn, x);

    // ---- token mixing ----
    rms_part_kernel<<<dim3(8, 8), 256, 0, stream>>>(x, ff);
    rms_apply_tok_kernel<<<3152, 256, 0, stream>>>(x, scale, ff, xn, yb);

    // merged tq+tk (shared yb panel) + tv split-K
    tok_qkv_kernel<<<dim3(4, 13, 4), 256, 0, stream>>>(yb, tWt16, l, tprt);
    token_finish_kernel<<<3152, 256, 0, stream>>>(tprt, cosT, sinT, tqb);

    token_scores_kernel<<<dim3(8, 8), 256, 0, stream>>>(tqb, tqb + XSZ, tsp);
    softmax_token_kernel<<<128, 256, 0, stream>>>(tsp, Pb);
    // token PV: scatter + residual into fp32 x
    mfma_gemm<EPI_TOKPV><<<dim3(13, 1, 8), 256, 0, stream>>>(
        Pb, tvt, x, xn, 64, 1576, 64, 64, 64, 0, 1.f, 8,
        4096, 0, 1576L * 64, 0, 0);
  }

  ln_head_kernel<<<dim3(4, 8), 256, 0, stream>>>(x, ln_g, ln_b, head_W, head_b, out);
}

// Round 4
// 745.924 us; speedup vs baseline: 1.0167x; 1.0167x over previous
//
#include <hip/hip_runtime.h>
#include <math.h>

// B=8, m=197, dim=512, heads=8, depth=2, F=8, tdim=1576, cdim=64, ncls=1000.
namespace {

typedef unsigned short u16;
typedef __attribute__((ext_vector_type(8))) short bf16x8;
typedef __attribute__((ext_vector_type(4))) float f32x4;

constexpr int NB = 8, NM = 197, ND = 512, NH = 8, NTD = 1576, NC = 64;
constexpr long XSZ = (long)NB * NM * ND;        // 806912
constexpr long QSZ = (long)NH * XSZ;            // 6455296 (h, b*m, e)
constexpr long TABSZ = 50432;                   // 197*256 == 64*788
constexpr int MP = 208;                         // padded 197 (16B-aligned bf16 rows)

__device__ __forceinline__ u16 f2bf(float f) {
  union { float f; unsigned u; } v; v.f = f;
  unsigned r = v.u + 0x7FFF + ((v.u >> 16) & 1);
  return (u16)(r >> 16);
}
__device__ __forceinline__ void async_cp16(const void* g, void* l) {
  __builtin_amdgcn_global_load_lds((const __attribute__((address_space(1))) unsigned*)g,
                                   (__attribute__((address_space(3))) unsigned*)l, 16, 0, 0);
}

// Bijective XCD-chunk swizzle (m204).
__device__ __forceinline__ int xcd_swz(int orig, int nwg) {
  int q = nwg >> 3, r = nwg & 7, x = orig & 7, i = orig >> 3;
  return (x < r ? x * (q + 1) : r * (q + 1) + (x - r) * q) + i;
}
__device__ __forceinline__ int swz_flat() {
  int nwg = gridDim.x * gridDim.y * gridDim.z;
  int orig = blockIdx.x + gridDim.x * (blockIdx.y + gridDim.y * blockIdx.z);
  return xcd_swz(orig, nwg);
}

// ---------------------------------------------------------------------------
// Shared MFMA GEMM core: acc += A(M x KL) * B^T(N x KL), 128x128 tile, BK=32.
// Depth-2 prefetch: 3-slot LDS ring, raw s_barrier + counted vmcnt(4).
// Ring safety: compute(ch)=ch%3, in-flight stage(ch+1), newly issued
// stage(ch+2) are distinct mod 3. Per-wave vmcnt before the barrier
// guarantees stage(ch) landed; compiler lgkmcnt before MFMA use guarantees
// ds_reads of buffer (ch-1) are consumed before the wave reaches the barrier
// preceding the stage(ch+2) overwrite of that slot.
__device__ __forceinline__ void gemm_core(
    const u16* __restrict__ A, int lda, int M, int row0,
    const u16* __restrict__ B, int ldb, int N, int col0,
    int KL, u16* As, u16* Bs, f32x4 (&acc)[4][4],
    int tid, int wm, int wn, int l15, int quad) {
  const int nfull = KL >> 5, tail = KL & 31;
  const int r = tid >> 2;
  const int cs = (((tid & 3) ^ ((r >> 1) & 3)) << 3);
  int gr0 = row0 + r;      if (gr0 >= M) gr0 = M - 1;
  int gr1 = row0 + r + 64; if (gr1 >= M) gr1 = M - 1;
  int gc0 = col0 + r;      if (gc0 >= N) gc0 = N - 1;
  int gc1 = col0 + r + 64; if (gc1 >= N) gc1 = N - 1;
  const u16* pa0 = A + (long)gr0 * lda + cs;
  const u16* pa1 = A + (long)gr1 * lda + cs;
  const u16* pb0 = B + (long)gc0 * ldb + cs;
  const u16* pb1 = B + (long)gc1 * ldb + cs;
  const int lb0 = (tid & ~63) * 8;
  const int lb1 = lb0 + 2048;

  auto stage = [&](int k0, int bi) {
    async_cp16(pa0 + k0, &As[bi + lb0]);
    async_cp16(pa1 + k0, &As[bi + lb1]);
    async_cp16(pb0 + k0, &Bs[bi + lb0]);
    async_cp16(pb1 + k0, &Bs[bi + lb1]);
  };
  auto compute = [&](int bi) {
    bf16x8 af[4], bg[4];
#pragma unroll
    for (int i = 0; i < 4; i++) {
      int row = wm * 64 + i * 16 + l15;
      af[i] = *(const bf16x8*)&As[bi + row * 32 + ((quad ^ ((row >> 1) & 3)) << 3)];
    }
#pragma unroll
    for (int j = 0; j < 4; j++) {
      int row = wn * 64 + j * 16 + l15;
      bg[j] = *(const bf16x8*)&Bs[bi + row * 32 + ((quad ^ ((row >> 1) & 3)) << 3)];
    }
#pragma unroll
    for (int i = 0; i < 4; i++)
#pragma unroll
      for (int j = 0; j < 4; j++)
        acc[i][j] = __builtin_amdgcn_mfma_f32_16x16x32_bf16(af[i], bg[j], acc[i][j], 0, 0, 0);
  };

  if (nfull > 0) {
    stage(0, 0);
    if (nfull > 1) stage(32, 4096);
    for (int ch = 0; ch < nfull; ch++) {
      if (ch + 1 < nfull) {
        asm volatile("s_waitcnt vmcnt(4)" ::: "memory");
      } else {
        asm volatile("s_waitcnt vmcnt(0)" ::: "memory");
      }
      __builtin_amdgcn_s_barrier();
      if (ch + 2 < nfull) stage((ch + 2) << 5, ((ch + 2) % 3) * 4096);
      compute((ch % 3) * 4096);
    }
  }
  if (tail) {
    const int tb = (nfull % 3) * 4096;
    const int k0f = nfull << 5;
    if (nfull > 0) __syncthreads();
    for (int idx2 = tid; idx2 < 4096; idx2 += 256) {
      int rr = idx2 >> 5, cc = idx2 & 31;
      int g = ((((cc >> 3) ^ ((rr >> 1) & 3)) << 3)) | (cc & 7);
      int grr = row0 + rr; if (grr >= M) grr = M - 1;
      int gcc = col0 + rr; if (gcc >= N) gcc = N - 1;
      As[tb + idx2] = (g < tail) ? A[(long)grr * lda + k0f + g] : (u16)0;
      Bs[tb + idx2] = (g < tail) ? B[(long)gcc * ldb + k0f + g] : (u16)0;
    }
    __syncthreads();
    compute(tb);
  }
}

// ---------------------------------------------------------------------------
// init: RoPE tables + patch gather + cls fill + zero sq-sum slots. One launch.
// grid 5115 x 256. Spatial table is INTERLEAVED (cos,sin) float2 in cosP.
__global__ void init_kernel(const float* __restrict__ img, const float* __restrict__ cls,
                            float* cosP, float* sinP, float* cosT, float* sinT,
                            u16* __restrict__ pimg, float* __restrict__ x,
                            float* __restrict__ ffs) {
  long idx = (long)blockIdx.x * 256 + threadIdx.x;
  if (idx < 197 * 256) {
    int p = (int)(idx / 256), i = (int)(idx % 256);
    float theta = powf(10000.f, -2.f * ((float)i - 1.f) / 512.f);
    float a = (float)p * theta;
    cosP[2 * idx] = cosf(a); cosP[2 * idx + 1] = sinf(a);
    return;
  }
  long j = idx - 197 * 256;
  if (j < 64 * 788) {
    int p = (int)(j / 788), i = (int)(j % 788);
    float theta = powf(10000.f, -2.f * ((float)i - 1.f) / 1576.f);
    float a = (float)p * theta;
    cosT[j] = cosf(a); sinT[j] = sinf(a);
    return;
  }
  long k2 = j - 64 * 788;
  if (k2 < 1568L * 768) {
    int r = (int)(k2 / 768), k = (int)(k2 % 768);
    int b = r / 196, p = r - b * 196;
    int pi = p / 14, pj = p - pi * 14;
    int cc = k % 3, pq = k / 3, pp = pq >> 4, qq = pq & 15;
    pimg[k2] = f2bf(img[((long)(b * 3 + cc) * 224 + pi * 16 + pp) * 224 + pj * 16 + qq]);
    return;
  }
  long c2 = k2 - 1568L * 768;
  if (c2 < 8 * 512) {
    int b = (int)(c2 >> 9), e = (int)(c2 & 511);
    x[((long)b * NM) * ND + e] = cls[e];
    return;
  }
  long c3 = c2 - 8 * 512;
  if (c3 < 64) ffs[c3] = 0.f;   // zero the fused sq-sum slots
}

// ---------------------------------------------------------------------------
// Two-stage per-batch RMS (used only for the first RMS after patch embed).
__global__ void rms_part_kernel(const float* __restrict__ x, float* __restrict__ part64) {
  int i = blockIdx.x, b = blockIdx.y;
  const float* p = x + (long)b * NM * ND + (long)i * 12608;
  float s = 0.f;
  for (int j = threadIdx.x; j < 12608; j += 256) { float v = p[j]; s += v * v; }
  __shared__ float red[256];
  red[threadIdx.x] = s; __syncthreads();
  for (int off = 128; off; off >>= 1) {
    if (threadIdx.x < off) red[threadIdx.x] += red[threadIdx.x + off];
    __syncthreads();
  }
  if (threadIdx.x == 0) part64[b * 8 + i] = red[0];
}

// np=8: sum 8 partials per batch; np=1: single pre-accumulated float.
__device__ __forceinline__ float rms_inv(const float* part, int b, int np) {
  float ssum = 0.f;
  if (np == 8) {
#pragma unroll
    for (int i = 0; i < 8; i++) ssum += part[b * 8 + i];
  } else {
    ssum = part[b];
  }
  return sqrtf((float)(NM * ND) / ssum);
}

__global__ void rms_apply_kernel(const float* __restrict__ x, const float* __restrict__ scale,
                                 const float* __restrict__ part, int np, float* __restrict__ xn,
                                 u16* __restrict__ xnb) {
  long idx = (long)blockIdx.x * 256 + threadIdx.x;
  if (idx >= XSZ) return;
  int b = (int)(idx / (NM * ND));
  long md = idx % (NM * ND);
  float v = x[idx] * scale[md] * rms_inv(part, b, np);
  xn[idx] = v;
  xnb[idx] = f2bf(v);
}

// Phase-B: writes xn and the permuted token matrix yb[(b*64+c)*1576 + f*197+mm].
__global__ void rms_apply_tok_kernel(const float* __restrict__ x, const float* __restrict__ scale,
                                     const float* __restrict__ part, int np, float* __restrict__ xn,
                                     u16* __restrict__ yb) {
  long idx = (long)blockIdx.x * 256 + threadIdx.x;
  if (idx >= XSZ) return;
  int b = (int)(idx / (NM * ND));
  long md = idx % (NM * ND);
  float v = x[idx] * scale[md] * rms_inv(part, b, np);
  xn[idx] = v;
  int mm = (int)(md / ND), d = (int)(md % ND);
  int c = d >> 3, f = d & 7;
  yb[((long)b * 64 + c) * NTD + f * 197 + mm] = f2bf(v);
}

// ---------------------------------------------------------------------------
// Spatial QKV, one launch. grid (4,13,24), z = w*8+h (after swizzle).
// w<2: q/k = xnb(1576x512) @ Wslab^T -> (h,b*m,e), RoPE fused in epilogue.
// w=2: v^T = Wv^T(512x512) @ xnb^T -> vt (h,b,e,m_pad).
__global__ __launch_bounds__(256) void qkv_kernel(const u16* __restrict__ xnb,
                                                  const u16* __restrict__ WtL,
                                                  u16* __restrict__ q,
                                                  const float* __restrict__ csP) {
  int wg = swz_flat();
  int bx = wg & 3, tmp = wg >> 2;
  int by = tmp % 13, bz = tmp / 13;
  int w = bz >> 3, h = bz & 7;
  __shared__ __align__(16) u16 As[3 * 4096];
  __shared__ __align__(16) u16 Bs[3 * 4096];
  const int tid = threadIdx.x;
  const int lane = tid & 63, wave = tid >> 6;
  const int wm = wave >> 1, wn = wave & 1;
  const int l15 = lane & 15, quad = lane >> 4;
  f32x4 acc[4][4] = {};

  if (w < 2) {
    int row0 = by * 128, col0 = bx * 128;
    const u16* B = WtL + ((long)(w * 8 + h)) * 262144;
    gemm_core(xnb, 512, 1576, row0, B, 512, 512, col0, 512, As, Bs, acc,
              tid, wm, wn, l15, quad);
    long base = (long)w * QSZ + (long)h * XSZ;
    const float2* cs2 = (const float2*)csP;
#pragma unroll
    for (int i = 0; i < 4; i++)
#pragma unroll
      for (int j = 0; j < 4; j++)
#pragma unroll
        for (int reg = 0; reg < 4; reg++) {
          int gr = row0 + wm * 64 + i * 16 + quad * 4 + reg;
          int gc = col0 + wn * 64 + j * 16 + l15;
          float v = acc[i][j][reg];
          float p = __shfl_xor(v, 1);            // all lanes execute (guard below)
          int t = gr % 197;                      // token index (bogus rows unused)
          float2 cs = cs2[t * 256 + (gc >> 1)];
          float outv = v * cs.x + ((gc & 1) ? -p * cs.y : p * cs.y);
          if (gr < 1576)
            q[base + (long)gr * 512 + gc] = f2bf(outv);
        }
  } else {
    int row0 = bx * 128, col0 = by * 128;
    const u16* A = WtL + ((long)(16 + h)) * 262144;
    gemm_core(A, 512, 512, row0, xnb, 512, 1576, col0, 512, As, Bs, acc,
              tid, wm, wn, l15, quad);
#pragma unroll
    for (int i = 0; i < 4; i++)
#pragma unroll
      for (int j = 0; j < 4; j++)
#pragma unroll
        for (int reg = 0; reg < 4; reg++) {
          int gr = row0 + wm * 64 + i * 16 + quad * 4 + reg;  // e
          int gc = col0 + wn * 64 + j * 16 + l15;             // b*197+mm
          if (gr < 512 && gc < 1576) {
            int b = gc / 197, mm = gc - b * 197;
            q[2 * QSZ + ((long)(h * 8 + b) * 512 + gr) * MP + mm] = f2bf(acc[i][j][reg]);
          }
        }
  }
}

// ---------------------------------------------------------------------------
// Token QKV, one launch. grid (4,13,6), XCD-chunked.
// z<4: tq/tk split-K partials (w=z>>1, seg=z&1): C = yb(512x1576) @ tW^T -> tprt[z].
// z>=4: tv^T split-K: C = tWv^T(1576x1576) @ yb^T -> tprt[4+seg] (1576x512).
__global__ __launch_bounds__(256) void tok_qkv_kernel(const u16* __restrict__ yb,
                                                      const u16* __restrict__ tWt, int l,
                                                      float* __restrict__ tprt) {
  int wg = swz_flat();
  int bx = wg & 3, tmp = wg >> 2;
  int by = tmp % 13, z = tmp / 13;
  __shared__ __align__(16) u16 As[3 * 4096];
  __shared__ __align__(16) u16 Bs[3 * 4096];
  const int tid = threadIdx.x;
  const int lane = tid & 63, wave = tid >> 6;
  const int wm = wave >> 1, wn = wave & 1;
  const int l15 = lane & 15, quad = lane >> 4;
  f32x4 acc[4][4] = {};

  if (z < 4) {
    int w = z >> 1, seg = z & 1;
    int kbeg = seg * 800, KL = seg ? 776 : 800;
    int row0 = bx * 128, col0 = by * 128;
    const u16* A = yb + kbeg;
    const u16* B = tWt + ((long)(w * 2 + l)) * 2483776 + kbeg;
    gemm_core(A, 1576, 512, row0, B, 1576, 1576, col0, KL, As, Bs, acc,
              tid, wm, wn, l15, quad);
    float* dst = tprt + (long)z * XSZ;
#pragma unroll
    for (int i = 0; i < 4; i++)
#pragma unroll
      for (int j = 0; j < 4; j++)
#pragma unroll
        for (int reg = 0; reg < 4; reg++) {
          int gr = row0 + wm * 64 + i * 16 + quad * 4 + reg;
          int gc = col0 + wn * 64 + j * 16 + l15;
          if (gr < 512 && gc < 1576) dst[(long)gr * 1576 + gc] = acc[i][j][reg];
        }
  } else {
    int seg = z - 4;
    int kbeg = seg * 800, KL = seg ? 776 : 800;
    int row0 = by * 128, col0 = bx * 128;
    const u16* A = tWt + ((long)(4 + l)) * 2483776 + kbeg;
    const u16* B = yb + kbeg;
    gemm_core(A, 1576, 1576, row0, B, 1576, 512, col0, KL, As, Bs, acc,
              tid, wm, wn, l15, quad);
    float* dst = tprt + (long)(4 + seg) * XSZ;
#pragma unroll
    for (int i = 0; i < 4; i++)
#pragma unroll
      for (int j = 0; j < 4; j++)
#pragma unroll
        for (int reg = 0; reg < 4; reg++) {
          int gr = row0 + wm * 64 + i * 16 + quad * 4 + reg;
          int gc = col0 + wn * 64 + j * 16 + l15;
          if (gr < 1576 && gc < 512) dst[(long)gr * 512 + gc] = acc[i][j][reg];
        }
  }
}

// Reduce token split-K partials: rope(tq), rope(tk), transpose(tv) -> bf16.
// tqb layout contract: tkb = tqb + XSZ, tvt = tqb + 2*XSZ.
__global__ void token_finish_kernel(const float* __restrict__ tp,
                                    const float* __restrict__ cosT,
                                    const float* __restrict__ sinT,
                                    u16* __restrict__ tqb) {
  long idx = (long)blockIdx.x * 256 + threadIdx.x;
  if (idx >= XSZ) return;
  int r = (int)(idx / NTD), g = (int)(idx - (long)r * NTD);
  int t = r & 63, ii = g >> 1;
  float cv = cosT[(long)t * 788 + ii];
  float sv = sinT[(long)t * 788 + ii];
  long re = (long)r * NTD + (g & ~1), ro = re + 1;
  float ve = tp[re] + tp[XSZ + re], vo = tp[ro] + tp[XSZ + ro];
  tqb[idx] = f2bf((g & 1) ? (-ve * sv + vo * cv) : (ve * cv + vo * sv));
  ve = tp[2 * XSZ + re] + tp[3 * XSZ + re];
  vo = tp[2 * XSZ + ro] + tp[3 * XSZ + ro];
  tqb[XSZ + idx] = f2bf((g & 1) ? (-ve * sv + vo * cv) : (ve * cv + vo * sv));
  // tv: idx = g2*512 + r2 in the (1576 x 512) partial layout
  int g2 = (int)(idx >> 9), r2 = (int)(idx & 511);
  float v = tp[4 * XSZ + idx] + tp[5 * XSZ + idx];
  tqb[2 * XSZ + ((long)(r2 >> 6) * NTD + g2) * 64 + (r2 & 63)] = f2bf(v);
}

// ---------------------------------------------------------------------------
// Generic MFMA GEMM for the remaining shapes. XCD-chunked work mapping.
// EPI_TOKPV additionally accumulates per-batch sum(x^2) into sqout[z2]
// (pre-zeroed) so the following RMS needs no separate reduction pass.
enum { EPI_BF16 = 0, EPI_F32 = 1, EPI_TOKPV = 3, EPI_PATCH = 4 };

template <int EPI>
__global__ __launch_bounds__(256) void mfma_gemm(
    const u16* __restrict__ A, const u16* __restrict__ B, void* __restrict__ Cv,
    const float* __restrict__ resid, float* __restrict__ sqout,
    int M, int N, int K, int lda, int ldb, int ldc, float alpha, int nz2,
    long aS2, long bS1, long bS2, long cS1, long cS2) {
  int wg = swz_flat();
  int bx = wg % gridDim.x; int tmp = wg / gridDim.x;
  int by = tmp % gridDim.y; int z = tmp / gridDim.y;
  int z1 = z / nz2, z2 = z - z1 * nz2;
  A += z2 * aS2;
  B += z1 * bS1 + z2 * bS2;
  __shared__ __align__(16) u16 As[3 * 4096];
  __shared__ __align__(16) u16 Bs[3 * 4096];
  const int tid = threadIdx.x;
  const int lane = tid & 63, wave = tid >> 6;
  const int wm = wave >> 1, wn = wave & 1;
  const int l15 = lane & 15, quad = lane >> 4;
  const int row0 = by * 128, col0 = bx * 128;
  f32x4 acc[4][4] = {};
  gemm_core(A, lda, M, row0, B, ldb, N, col0, K, As, Bs, acc, tid, wm, wn, l15, quad);

  float* Cf = (float*)Cv;
  u16* Ch = (u16*)Cv;
  const long cbase = z1 * cS1 + z2 * cS2;
  float ssq = 0.f;
#pragma unroll
  for (int i = 0; i < 4; i++)
#pragma unroll
    for (int j = 0; j < 4; j++)
#pragma unroll
      for (int reg = 0; reg < 4; reg++) {
        int gr = row0 + wm * 64 + i * 16 + quad * 4 + reg;
        int gc = col0 + wn * 64 + j * 16 + l15;
        if (gr >= M || gc >= N) continue;
        float vv = acc[i][j][reg] * alpha;
        if (EPI == EPI_BF16) {
          Ch[cbase + (long)gr * ldc + gc] = f2bf(vv);
        } else if (EPI == EPI_F32) {
          Cf[cbase + (long)gr * ldc + gc] = vv;
        } else if (EPI == EPI_TOKPV) {    // x[b][mm][c*8+f] = acc + xn
          int f = gc / 197, mm = gc - f * 197;
          long o = ((long)z2 * 197 + mm) * 512 + gr * 8 + f;
          float xv = vv + resid[o];
          Cf[o] = xv;
          ssq += xv * xv;
        } else {                          // PATCH: x[b][1+p][gc] = acc + bias
          int b = gr / 196, p = gr - b * 196;
          Cf[((long)b * 197 + 1 + p) * 512 + gc] = vv + resid[gc];
        }
      }
  if (EPI == EPI_TOKPV) {
    __syncthreads();                       // LDS no longer needed by gemm
    float* red = (float*)As;
    red[tid] = ssq; __syncthreads();
    for (int o2 = 128; o2; o2 >>= 1) {
      if (tid < o2) red[tid] += red[tid + o2];
      __syncthreads();
    }
    if (tid == 0) atomicAdd(&sqout[z2], red[0]);
  }
}

// ---------------------------------------------------------------------------
// Token scores, split-K: grid (split=8, b=8). tsp[(s*8+b)][64][64] partials.
// Same 3-slot ring + counted vmcnt as gemm_core (was depth-0 stall before).
__global__ __launch_bounds__(256) void token_scores_kernel(const u16* __restrict__ tq,
                                                           const u16* __restrict__ tk,
                                                           float* __restrict__ tsp) {
  int s = blockIdx.x, b = blockIdx.y;
  const u16* A = tq + (long)b * 64 * NTD;
  const u16* B = tk + (long)b * 64 * NTD;
  __shared__ __align__(16) u16 As[3 * 2048];
  __shared__ __align__(16) u16 Bs[3 * 2048];
  int tid = threadIdx.x, lane = tid & 63, w = tid >> 6;
  int l15 = lane & 15, quad = lane >> 4;
  f32x4 acc[4] = {};
  const int r = tid >> 2;
  const int cs = (((tid & 3) ^ ((r >> 1) & 3)) << 3);
  const u16* pa = A + (long)r * NTD + cs;
  const u16* pbp = B + (long)r * NTD + cs;
  const int lb = (tid & ~63) * 8;

  auto stage = [&](int ch, int bi) {
    async_cp16(pa + ch * 32, &As[bi + lb]);
    async_cp16(pbp + ch * 32, &Bs[bi + lb]);
  };
  auto compute = [&](int bi) {
    int row = w * 16 + l15;
    bf16x8 av = *(const bf16x8*)&As[bi + row * 32 + ((quad ^ ((row >> 1) & 3)) << 3)];
#pragma unroll
    for (int j = 0; j < 4; j++) {
      int rb = j * 16 + l15;
      bf16x8 bv = *(const bf16x8*)&Bs[bi + rb * 32 + ((quad ^ ((rb >> 1) & 3)) << 3)];
      acc[j] = __builtin_amdgcn_mfma_f32_16x16x32_bf16(av, bv, acc[j], 0, 0, 0);
    }
  };

  int ch0 = s * 6, nch = (s == 7) ? 7 : 6;
  stage(ch0, 0);
  stage(ch0 + 1, 2048);
  for (int c = 0; c < nch; c++) {
    if (c + 1 < nch) {
      asm volatile("s_waitcnt vmcnt(2)" ::: "memory");
    } else {
      asm volatile("s_waitcnt vmcnt(0)" ::: "memory");
    }
    __builtin_amdgcn_s_barrier();
    if (c + 2 < nch) stage(ch0 + c + 2, ((c + 2) % 3) * 2048);
    compute((c % 3) * 2048);
  }
  if (s == 7) {  // 8-element K tail at k=1568
    const int tb = (nch % 3) * 2048;
    __syncthreads();
    for (int idx = tid; idx < 2048; idx += 256) {
      int rr = idx >> 5, cc = idx & 31;
      int g = ((((cc >> 3) ^ ((rr >> 1) & 3)) << 3)) | (cc & 7);
      As[tb + idx] = (g < 8) ? A[(long)rr * NTD + 1568 + g] : (u16)0;
      Bs[tb + idx] = (g < 8) ? B[(long)rr * NTD + 1568 + g] : (u16)0;
    }
    __syncthreads();
    compute(tb);
  }
  const float sc = rsqrtf(1576.f);
  float* dst = tsp + ((long)(s * 8 + b)) * 4096;
#pragma unroll
  for (int j = 0; j < 4; j++)
#pragma unroll
    for (int reg = 0; reg < 4; reg++) {
      int row = w * 16 + quad * 4 + reg, col = j * 16 + l15;
      dst[row * 64 + col] = acc[j][reg] * sc;
    }
}

// ---------------------------------------------------------------------------
// Spatial softmax: s fp32 (64,197,197) -> pb bf16 (64,197,208). 4 rows/block.
__global__ void softmax_spatial_kernel(const float* __restrict__ s, u16* __restrict__ pb) {
  int row = blockIdx.x * 4 + (threadIdx.x >> 6);
  int lane = threadIdx.x & 63;
  const float* p = s + (long)row * 197;
  int hb = row / 197, mm = row - hb * 197;
  u16* q = pb + (long)hb * 197 * MP + (long)mm * MP;
  float mx = -INFINITY;
  for (int j = lane; j < 197; j += 64) mx = fmaxf(mx, p[j]);
#pragma unroll
  for (int off = 32; off; off >>= 1) mx = fmaxf(mx, __shfl_xor(mx, off));
  float sum = 0.f;
  float ev[4];
  int cnt = 0;
  for (int j = lane; j < 197; j += 64) { ev[cnt] = expf(p[j] - mx); sum += ev[cnt]; cnt++; }
#pragma unroll
  for (int off = 32; off; off >>= 1) sum += __shfl_xor(sum, off);
  float inv = 1.f / sum;
  cnt = 0;
  for (int j = lane; j < 197; j += 64) { q[j] = f2bf(ev[cnt] * inv); cnt++; }
}

// Token softmax: sums 8 split-K partials, softmaxes, writes Pb bf16.
__global__ void softmax_token_kernel(const float* __restrict__ tsp, u16* __restrict__ Pb) {
  int row = blockIdx.x * 4 + (threadIdx.x >> 6);  // 0..511 = b*64+r
  int lane = threadIdx.x & 63;
  int b = row >> 6, r = row & 63;
  float v = 0.f;
#pragma unroll
  for (int p = 0; p < 8; p++) v += tsp[((long)(p * 8 + b)) * 4096 + r * 64 + lane];
  float mx = v;
#pragma unroll
  for (int off = 32; off; off >>= 1) mx = fmaxf(mx, __shfl_xor(mx, off));
  float e = expf(v - mx);
  float sum = e;
#pragma unroll
  for (int off = 32; off; off >>= 1) sum += __shfl_xor(sum, off);
  Pb[(long)row * 64 + lane] = f2bf(e / sum);
}

// ---------------------------------------------------------------------------
// Attn output reduce + residual; fused per-batch sum(x^2) into sqslot[b].
// Each block (256 contiguous elems) lies within one batch (100864 % 256 == 0).
__global__ void attn_reduce_kernel(const float* __restrict__ part, const float* __restrict__ bias,
                                   const float* __restrict__ resid, float* __restrict__ x,
                                   float* __restrict__ sqslot) {
  long idx = (long)blockIdx.x * 256 + threadIdx.x;
  int col = (int)(idx % ND);
  float s = resid[idx] + bias[col];
#pragma unroll
  for (int h = 0; h < 8; h++) s += part[(long)h * XSZ + idx];
  x[idx] = s;
  __shared__ float red[256];
  red[threadIdx.x] = s * s; __syncthreads();
  for (int o = 128; o; o >>= 1) {
    if (threadIdx.x < o) red[threadIdx.x] += red[threadIdx.x + o];
    __syncthreads();
  }
  if (threadIdx.x == 0) atomicAdd(&sqslot[blockIdx.x / 394], red[0]);
}

// ---------------------------------------------------------------------------
// Merged Wqkv (48 slabs, z = l*24 + w*8 + h) + attn_W (16 slabs: l*8 + i).
// grid (16,16,64).
__global__ void transpose_wa_kernel(const float* __restrict__ Wq, const float* __restrict__ Wk,
                                    const float* __restrict__ Wv, const float* __restrict__ attn_W,
                                    u16* __restrict__ Wt16, u16* __restrict__ Wat16) {
  int z = blockIdx.z;
  const float* src;
  u16* dst;
  long dld;
  if (z < 48) {
    int l = z / 24, rem = z - l * 24, w = rem >> 3, h = rem & 7;
    src = (w == 0 ? Wq : w == 1 ? Wk : Wv) + (long)(l * 8 + h) * 262144;
    dst = Wt16 + (long)z * 262144;
    dld = 512;
  } else {
    int za = z - 48, l = za >> 3, i = za & 7;   // 8 row-blocks per layer
    src = attn_W + (long)l * 4096 * 512 + (long)i * 512 * 512;
    dst = Wat16 + (long)l * 512 * 4096 + (long)i * 512;
    dld = 4096;
  }
  __shared__ float t[32][33];
  int c0 = blockIdx.x * 32, r0 = blockIdx.y * 32;
  int tx = threadIdx.x, ty = threadIdx.y;
#pragma unroll
  for (int i = 0; i < 4; i++)
    t[ty + i * 8][tx] = src[(long)(r0 + ty + i * 8) * 512 + c0 + tx];
  __syncthreads();
#pragma unroll
  for (int i = 0; i < 4; i++)
    dst[(long)(c0 + ty + i * 8) * dld + r0 + tx] = f2bf(t[tx][ty + i * 8]);
}

// Generic transpose fp32 (RxC) -> bf16 (CxR) (used for patch_W).
__global__ void transpose_bf16_kernel(const float* __restrict__ src, u16* __restrict__ dst,
                                      int R, int C) {
  __shared__ float t[32][33];
  int c0 = blockIdx.x * 32, r0 = blockIdx.y * 32;
  int tx = threadIdx.x, ty = threadIdx.y;
#pragma unroll
  for (int i = 0; i < 4; i++) {
    int r = r0 + ty + i * 8;
    if (r < R && c0 + tx < C) t[ty + i * 8][tx] = src[(long)r * C + c0 + tx];
  }
  __syncthreads();
#pragma unroll
  for (int i = 0; i < 4; i++) {
    int c = c0 + ty + i * 8;
    if (c < C && r0 + tx < R) dst[(long)c * R + r0 + tx] = f2bf(t[tx][ty + i * 8]);
  }
}

// Merged tWq/tWk/tWv transpose: grid (50,50,6), z = w*2 + l.
__global__ void t_transpose3_kernel(const float* __restrict__ Wq, const float* __restrict__ Wk,
                                    const float* __restrict__ Wv, u16* __restrict__ dst0) {
  int z = blockIdx.z;
  int w = z >> 1, l = z & 1;
  const float* src = (w == 0 ? Wq : w == 1 ? Wk : Wv) + (long)l * NTD * NTD;
  u16* d = dst0 + (long)z * NTD * NTD;
  __shared__ float t[32][33];
  int c0 = blockIdx.x * 32, r0 = blockIdx.y * 32;
  int tx = threadIdx.x, ty = threadIdx.y;
#pragma unroll
  for (int i = 0; i < 4; i++) {
    int r = r0 + ty + i * 8;
    if (r < NTD && c0 + tx < NTD) t[ty + i * 8][tx] = src[(long)r * NTD + c0 + tx];
  }
  __syncthreads();
#pragma unroll
  for (int i = 0; i < 4; i++) {
    int c = c0 + ty + i * 8;
    if (c < NTD && r0 + tx < NTD) d[(long)c * NTD + r0 + tx] = f2bf(t[tx][ty + i * 8]);
  }
}

// ---------------------------------------------------------------------------
// Fused cls LayerNorm + head GEMM. grid (4,8), 256 thr (LN redone per block).
__global__ void ln_head_kernel(const float* __restrict__ x, const float* __restrict__ g,
                               const float* __restrict__ bb, const float* __restrict__ W,
                               const float* __restrict__ hb, float* __restrict__ out) {
  int b = blockIdx.y, t = threadIdx.x;
  __shared__ float xs[512];
  __shared__ float red[256];
  float v0 = x[(long)b * NM * ND + t];
  float v1 = x[(long)b * NM * ND + 256 + t];
  red[t] = v0 + v1; __syncthreads();
  for (int o = 128; o; o >>= 1) { if (t < o) red[t] += red[t + o]; __syncthreads(); }
  float mu = red[0] / 512.f; __syncthreads();
  float d0 = v0 - mu, d1 = v1 - mu;
  red[t] = d0 * d0 + d1 * d1; __syncthreads();
  for (int o = 128; o; o >>= 1) { if (t < o) red[t] += red[t + o]; __syncthreads(); }
  float inv = rsqrtf(red[0] / 512.f + 1e-5f); __syncthreads();
  xs[t] = d0 * inv * g[t] + bb[t];
  xs[256 + t] = d1 * inv * g[256 + t] + bb[256 + t];
  __syncthreads();
  int n = blockIdx.x * 250 + t;
  if (t < 250 && n < 1000) {
    float acc = hb[n];
    for (int dd = 0; dd < 512; dd++) acc += xs[dd] * W[(long)dd * 1000 + n];
    out[(long)b * 1000 + n] = acc;
  }
}

}  // namespace

extern "C" void kernel_launch(void* const* d_in, const int* in_sizes, int n_in,
                              void* d_out, int out_size, void* d_ws, size_t ws_size,
                              hipStream_t stream) {
  const float* img     = (const float*)d_in[0];
  const float* patch_W = (const float*)d_in[1];
  const float* patch_b = (const float*)d_in[2];
  const float* cls_tok = (const float*)d_in[3];
  const float* rms_s   = (const float*)d_in[4];
  const float* Wq      = (const float*)d_in[5];
  const float* Wk      = (const float*)d_in[6];
  const float* Wv      = (const float*)d_in[7];
  const float* attn_W  = (const float*)d_in[8];
  const float* attn_b  = (const float*)d_in[9];
  const float* tWq     = (const float*)d_in[10];
  const float* tWk     = (const float*)d_in[11];
  const float* tWv     = (const float*)d_in[12];
  const float* ln_g    = (const float*)d_in[13];
  const float* ln_b    = (const float*)d_in[14];
  const float* head_W  = (const float*)d_in[15];
  const float* head_b  = (const float*)d_in[16];
  float* out = (float*)d_out;

  // ---- workspace layout (floats) ----
  float* base = (float*)d_ws;
  long off = 0;
  auto alloc = [&](long n) { float* r = base + off; off += (n + 15) & ~15L; return r; };
  float* cosP = alloc(TABSZ);       // interleaved (cos,sin) float2 table spans
  float* sinP = alloc(TABSZ);       //   cosP..sinP (2*TABSZ floats contiguous)
  float* cosT = alloc(TABSZ);
  float* sinT = alloc(TABSZ);
  float* x    = alloc(XSZ);
  float* xn   = alloc(XSZ);
  float* Wt_f   = alloc(6291456);   // 48 slabs 512x512 bf16, z = l*24+w*8+h
  float* Wat_f  = alloc(2097152);   // (l) 512x4096 bf16
  float* tWt_f  = alloc(7451328);   // (w,l) 1576x1576 bf16
  float* xnb_f  = alloc(XSZ / 2);
  float* pimg_f = alloc(602112);    // 1568x768 bf16
  float* pWt_f  = alloc(196608);    // 512x768 bf16
  float* U      = alloc(16885824);  // union region
  float* ff     = alloc(64);        // 8x8 partials for the first RMS
  float* ffs    = alloc(64);        // fused sq-sum slots: [0]=attn l0, [8]=tok l0,
                                    //   [16]=attn l1, [24]=tok l1 (unused-read)

  u16* Wt16  = (u16*)Wt_f;
  u16* Wat16 = (u16*)Wat_f;
  u16* tWt16 = (u16*)tWt_f;
  u16* xnb   = (u16*)xnb_f;
  u16* pimg  = (u16*)pimg_f;
  u16* pWt   = (u16*)pWt_f;
  // phase A overlay (contract: kk = q + QSZ, vt = q + 2*QSZ)
  u16* q   = (u16*)U;                 // 6455296 (h, b*m, e)
  u16* kk  = q + QSZ;                 // 6455296
  u16* vt  = kk + QSZ;                // 6815744 (h,b,e,m_pad)
  float* s = (float*)(vt + 6815744);  // 2483776 f (hb,197,197)
  u16* pb  = (u16*)(s + 2483776);     // 2622464 (hb,197,208)
  u16* o   = pb + 2622464;            // 6455296 (h, b*m, e)
  float* part = (float*)q;            // 8*XSZ fp32 (aliases dead q,kk)
  // phase B overlay (contract: tkb = tqb + XSZ, tvt = tqb + 2*XSZ)
  u16* yb     = (u16*)U;              // 806912 (b*64+c, 1576)
  float* tprt = (float*)(yb + XSZ);   // 6*XSZ fp32 split partials
  u16* tqb    = (u16*)(tprt + 6 * XSZ);
  u16* tvt    = tqb + 2 * XSZ;        // (b, 1576, 64)
  float* tsp  = (float*)(tvt + XSZ);  // 8 x 8 x 64 x 64
  u16* Pb     = (u16*)(tsp + 262144); // 8*64*64

  const float rs512 = 1.f / sqrtf(512.f);
  const dim3 tt(32, 8);

  // ---- setup ----
  init_kernel<<<5115, 256, 0, stream>>>(img, cls_tok, cosP, sinP, cosT, sinT, pimg, x, ffs);
  transpose_bf16_kernel<<<dim3(16, 24), tt, 0, stream>>>(patch_W, pWt, 768, 512);
  transpose_wa_kernel<<<dim3(16, 16, 64), tt, 0, stream>>>(Wq, Wk, Wv, attn_W, Wt16, Wat16);
  t_transpose3_kernel<<<dim3(50, 50, 6), tt, 0, stream>>>(tWq, tWk, tWv, tWt16);
  mfma_gemm<EPI_PATCH><<<dim3(4, 13, 1), 256, 0, stream>>>(
      pimg, pWt, x, patch_b, nullptr, 1568, 512, 768, 768, 768, 512, 1.f, 1, 0, 0, 0, 0, 0);

  for (int l = 0; l < 2; l++) {
    const float* scale = rms_s + (long)l * NM * ND;
    float* slotA = ffs + l * 16;       // attn-phase sq-sums for this layer
    float* slotT = ffs + l * 16 + 8;   // token-phase sq-sums for this layer
    // ---- spatial attention ----
    if (l == 0) {
      rms_part_kernel<<<dim3(8, 8), 256, 0, stream>>>(x, ff);
      rms_apply_kernel<<<3152, 256, 0, stream>>>(x, scale, ff, 8, xn, xnb);
    } else {
      // sq-sums were accumulated by the previous layer's token-PV epilogue
      rms_apply_kernel<<<3152, 256, 0, stream>>>(x, scale, ffs + 8, 1, xn, xnb);
    }

    // qkv with fused RoPE on q,k
    qkv_kernel<<<dim3(4, 13, 24), 256, 0, stream>>>(xnb, Wt16 + (long)l * 24 * 262144, q, cosP);

    // scores (fp32, scaled)
    mfma_gemm<EPI_F32><<<dim3(2, 2, 64), 256, 0, stream>>>(
        q, kk, s, nullptr, nullptr, 197, 197, 512, 512, 512, 197, rs512, 64,
        197L * 512, 0, 197L * 512, 0, 197L * 197);
    softmax_spatial_kernel<<<3152, 256, 0, stream>>>(s, pb);
    // o = P @ v
    mfma_gemm<EPI_BF16><<<dim3(4, 2, 64), 256, 0, stream>>>(
        pb, vt, o, nullptr, nullptr, 197, 512, 197, MP, MP, 512, 1.f, 64,
        197L * MP, 0, 512L * MP, 0, 197L * 512);
    // attn-proj head partials
    mfma_gemm<EPI_F32><<<dim3(4, 13, 8), 256, 0, stream>>>(
        o, Wat16 + (long)l * 2097152, part, nullptr, nullptr, 1576, 512, 512, 512, 4096, 512, 1.f, 8,
        XSZ, 0, 512, 0, XSZ);
    // reduce + residual + fused sum(x^2) into slotA
    attn_reduce_kernel<<<3152, 256, 0, stream>>>(part, attn_b + (long)l * ND, xn, x, slotA);

    // ---- token mixing ----
    rms_apply_tok_kernel<<<3152, 256, 0, stream>>>(x, scale, slotA, 1, xn, yb);

    tok_qkv_kernel<<<dim3(4, 13, 6), 256, 0, stream>>>(yb, tWt16, l, tprt);
    token_finish_kernel<<<3152, 256, 0, stream>>>(tprt, cosT, sinT, tqb);

    token_scores_kernel<<<dim3(8, 8), 256, 0, stream>>>(tqb, tqb + XSZ, tsp);
    softmax_token_kernel<<<128, 256, 0, stream>>>(tsp, Pb);
    // token PV: scatter + residual into fp32 x; fused sum(x^2) into slotT
    mfma_gemm<EPI_TOKPV><<<dim3(13, 1, 8), 256, 0, stream>>>(
        Pb, tvt, x, xn, slotT, 64, 1576, 64, 64, 64, 0, 1.f, 8,
        4096, 0, 1576L * 64, 0, 0);
  }

  ln_head_kernel<<<dim3(4, 8), 256, 0, stream>>>(x, ln_g, ln_b, head_W, head_b, out);
}

// Round 5
// 682.260 us; speedup vs baseline: 1.1116x; 1.0933x over previous
//
#include <hip/hip_runtime.h>
#include <math.h>

// B=8, m=197, dim=512, heads=8, depth=2, F=8, tdim=1576, cdim=64, ncls=1000.
namespace {

typedef unsigned short u16;
typedef __attribute__((ext_vector_type(8))) short bf16x8;
typedef __attribute__((ext_vector_type(4))) float f32x4;
typedef __attribute__((ext_vector_type(4))) unsigned short u16x4;
typedef __attribute__((ext_vector_type(2))) unsigned short u16x2;

constexpr int NB = 8, NM = 197, ND = 512, NH = 8, NTD = 1576, NC = 64;
constexpr long XSZ = (long)NB * NM * ND;        // 806912
constexpr long QSZ = (long)NH * XSZ;            // 6455296 (h, b*m, e)
constexpr long TABSZ = 50432;                   // 197*256 == 64*788
constexpr int MP = 208;                         // padded 197 (16B-aligned bf16 rows)
constexpr int BMD = NM * ND;                    // 100864 per-batch elems

__device__ __forceinline__ u16 f2bf(float f) {
  union { float f; unsigned u; } v; v.f = f;
  unsigned r = v.u + 0x7FFF + ((v.u >> 16) & 1);
  return (u16)(r >> 16);
}
__device__ __forceinline__ void async_cp16(const void* g, void* l) {
  __builtin_amdgcn_global_load_lds((const __attribute__((address_space(1))) unsigned*)g,
                                   (__attribute__((address_space(3))) unsigned*)l, 16, 0, 0);
}

// Bijective XCD-chunk swizzle (m204).
__device__ __forceinline__ int xcd_swz(int orig, int nwg) {
  int q = nwg >> 3, r = nwg & 7, x = orig & 7, i = orig >> 3;
  return (x < r ? x * (q + 1) : r * (q + 1) + (x - r) * q) + i;
}
__device__ __forceinline__ int swz_flat() {
  int nwg = gridDim.x * gridDim.y * gridDim.z;
  int orig = blockIdx.x + gridDim.x * (blockIdx.y + gridDim.y * blockIdx.z);
  return xcd_swz(orig, nwg);
}

// ---------------------------------------------------------------------------
// Shared MFMA GEMM core: acc += A(M x KL) * B^T(N x KL), 128x128 tile, BK=32.
// Depth-2 prefetch: 3-slot LDS ring, raw s_barrier + counted vmcnt(4).
__device__ __forceinline__ void gemm_core(
    const u16* __restrict__ A, int lda, int M, int row0,
    const u16* __restrict__ B, int ldb, int N, int col0,
    int KL, u16* As, u16* Bs, f32x4 (&acc)[4][4],
    int tid, int wm, int wn, int l15, int quad) {
  const int nfull = KL >> 5, tail = KL & 31;
  const int r = tid >> 2;
  const int cs = (((tid & 3) ^ ((r >> 1) & 3)) << 3);
  int gr0 = row0 + r;      if (gr0 >= M) gr0 = M - 1;
  int gr1 = row0 + r + 64; if (gr1 >= M) gr1 = M - 1;
  int gc0 = col0 + r;      if (gc0 >= N) gc0 = N - 1;
  int gc1 = col0 + r + 64; if (gc1 >= N) gc1 = N - 1;
  const u16* pa0 = A + (long)gr0 * lda + cs;
  const u16* pa1 = A + (long)gr1 * lda + cs;
  const u16* pb0 = B + (long)gc0 * ldb + cs;
  const u16* pb1 = B + (long)gc1 * ldb + cs;
  const int lb0 = (tid & ~63) * 8;
  const int lb1 = lb0 + 2048;

  auto stage = [&](int k0, int bi) {
    async_cp16(pa0 + k0, &As[bi + lb0]);
    async_cp16(pa1 + k0, &As[bi + lb1]);
    async_cp16(pb0 + k0, &Bs[bi + lb0]);
    async_cp16(pb1 + k0, &Bs[bi + lb1]);
  };
  auto compute = [&](int bi) {
    bf16x8 af[4], bg[4];
#pragma unroll
    for (int i = 0; i < 4; i++) {
      int row = wm * 64 + i * 16 + l15;
      af[i] = *(const bf16x8*)&As[bi + row * 32 + ((quad ^ ((row >> 1) & 3)) << 3)];
    }
#pragma unroll
    for (int j = 0; j < 4; j++) {
      int row = wn * 64 + j * 16 + l15;
      bg[j] = *(const bf16x8*)&Bs[bi + row * 32 + ((quad ^ ((row >> 1) & 3)) << 3)];
    }
#pragma unroll
    for (int i = 0; i < 4; i++)
#pragma unroll
      for (int j = 0; j < 4; j++)
        acc[i][j] = __builtin_amdgcn_mfma_f32_16x16x32_bf16(af[i], bg[j], acc[i][j], 0, 0, 0);
  };

  if (nfull > 0) {
    stage(0, 0);
    if (nfull > 1) stage(32, 4096);
    for (int ch = 0; ch < nfull; ch++) {
      if (ch + 1 < nfull) {
        asm volatile("s_waitcnt vmcnt(4)" ::: "memory");
      } else {
        asm volatile("s_waitcnt vmcnt(0)" ::: "memory");
      }
      __builtin_amdgcn_s_barrier();
      if (ch + 2 < nfull) stage((ch + 2) << 5, ((ch + 2) % 3) * 4096);
      compute((ch % 3) * 4096);
    }
  }
  if (tail) {
    const int tb = (nfull % 3) * 4096;
    const int k0f = nfull << 5;
    if (nfull > 0) __syncthreads();
    for (int idx2 = tid; idx2 < 4096; idx2 += 256) {
      int rr = idx2 >> 5, cc = idx2 & 31;
      int g = ((((cc >> 3) ^ ((rr >> 1) & 3)) << 3)) | (cc & 7);
      int grr = row0 + rr; if (grr >= M) grr = M - 1;
      int gcc = col0 + rr; if (gcc >= N) gcc = N - 1;
      As[tb + idx2] = (g < tail) ? A[(long)grr * lda + k0f + g] : (u16)0;
      Bs[tb + idx2] = (g < tail) ? B[(long)gcc * ldb + k0f + g] : (u16)0;
    }
    __syncthreads();
    compute(tb);
  }
}

// ---------------------------------------------------------------------------
// init: RoPE tables + patch gather + cls fill + zero sq-sum slots. One launch.
// grid 5115 x 256. Spatial table is INTERLEAVED (cos,sin) float2 in cosP.
__global__ void init_kernel(const float* __restrict__ img, const float* __restrict__ cls,
                            float* cosP, float* sinP, float* cosT, float* sinT,
                            u16* __restrict__ pimg, float* __restrict__ x,
                            float* __restrict__ ffs) {
  long idx = (long)blockIdx.x * 256 + threadIdx.x;
  if (idx < 197 * 256) {
    int p = (int)(idx / 256), i = (int)(idx % 256);
    float theta = powf(10000.f, -2.f * ((float)i - 1.f) / 512.f);
    float a = (float)p * theta;
    cosP[2 * idx] = cosf(a); cosP[2 * idx + 1] = sinf(a);
    return;
  }
  long j = idx - 197 * 256;
  if (j < 64 * 788) {
    int p = (int)(j / 788), i = (int)(j % 788);
    float theta = powf(10000.f, -2.f * ((float)i - 1.f) / 1576.f);
    float a = (float)p * theta;
    cosT[j] = cosf(a); sinT[j] = sinf(a);
    return;
  }
  long k2 = j - 64 * 788;
  if (k2 < 1568L * 768) {
    int r = (int)(k2 / 768), k = (int)(k2 % 768);
    int b = r / 196, p = r - b * 196;
    int pi = p / 14, pj = p - pi * 14;
    int cc = k % 3, pq = k / 3, pp = pq >> 4, qq = pq & 15;
    pimg[k2] = f2bf(img[((long)(b * 3 + cc) * 224 + pi * 16 + pp) * 224 + pj * 16 + qq]);
    return;
  }
  long c2 = k2 - 1568L * 768;
  if (c2 < 8 * 512) {
    int b = (int)(c2 >> 9), e = (int)(c2 & 511);
    x[((long)b * NM) * ND + e] = cls[e];
    return;
  }
  long c3 = c2 - 8 * 512;
  if (c3 < 64) ffs[c3] = 0.f;   // zero the fused sq-sum slots
}

// ---------------------------------------------------------------------------
// Two-stage per-batch RMS (only for the first RMS after patch embed). float4.
__global__ void rms_part_kernel(const float* __restrict__ x, float* __restrict__ part64) {
  int i = blockIdx.x, b = blockIdx.y;
  const float4* p = (const float4*)(x + (long)b * BMD + (long)i * 12608);
  float s = 0.f;
  for (int j = threadIdx.x; j < 3152; j += 256) {
    float4 v = p[j];
    s += v.x * v.x + v.y * v.y + v.z * v.z + v.w * v.w;
  }
  __shared__ float red[256];
  red[threadIdx.x] = s; __syncthreads();
  for (int off = 128; off; off >>= 1) {
    if (threadIdx.x < off) red[threadIdx.x] += red[threadIdx.x + off];
    __syncthreads();
  }
  if (threadIdx.x == 0) part64[b * 8 + i] = red[0];
}

// np=8: sum 8 partials per batch; np=1: single pre-accumulated float.
__device__ __forceinline__ float rms_inv(const float* part, int b, int np) {
  float ssum = 0.f;
  if (np == 8) {
#pragma unroll
    for (int i = 0; i < 8; i++) ssum += part[b * 8 + i];
  } else {
    ssum = part[b];
  }
  return sqrtf((float)(NM * ND) / ssum);
}

// Vectorized x4: grid 788 x 256 (XSZ/4 = 201728 float4 threads).
__global__ void rms_apply_kernel(const float* __restrict__ x, const float* __restrict__ scale,
                                 const float* __restrict__ part, int np, float* __restrict__ xn,
                                 u16* __restrict__ xnb) {
  int idx4 = blockIdx.x * 256 + threadIdx.x;
  int b = idx4 / (BMD / 4);
  int md4 = idx4 - b * (BMD / 4);
  float ri = rms_inv(part, b, np);
  float4 xv = ((const float4*)x)[idx4];
  float4 sv = ((const float4*)(scale))[md4];
  float4 v;
  v.x = xv.x * sv.x * ri; v.y = xv.y * sv.y * ri;
  v.z = xv.z * sv.z * ri; v.w = xv.w * sv.w * ri;
  ((float4*)xn)[idx4] = v;
  u16x4 h = { f2bf(v.x), f2bf(v.y), f2bf(v.z), f2bf(v.w) };
  ((u16x4*)xnb)[idx4] = h;
}

// Phase-B vectorized: writes xn and permuted yb[(b*64+c)*1576 + f*197+mm].
__global__ void rms_apply_tok_kernel(const float* __restrict__ x, const float* __restrict__ scale,
                                     const float* __restrict__ part, int np, float* __restrict__ xn,
                                     u16* __restrict__ yb) {
  int idx4 = blockIdx.x * 256 + threadIdx.x;
  int b = idx4 / (BMD / 4);
  int md4 = idx4 - b * (BMD / 4);
  float ri = rms_inv(part, b, np);
  float4 xv = ((const float4*)x)[idx4];
  float4 sv = ((const float4*)(scale))[md4];
  float4 v;
  v.x = xv.x * sv.x * ri; v.y = xv.y * sv.y * ri;
  v.z = xv.z * sv.z * ri; v.w = xv.w * sv.w * ri;
  ((float4*)xn)[idx4] = v;
  int md = md4 * 4;
  int mm = md / ND, d0 = md - mm * ND;     // d0 % 4 == 0
  int c = d0 >> 3, f0 = d0 & 7;            // f0 in {0,4}; f = f0..f0+3
  u16* row = yb + ((long)b * 64 + c) * NTD + mm;
  row[(f0 + 0) * 197] = f2bf(v.x);
  row[(f0 + 1) * 197] = f2bf(v.y);
  row[(f0 + 2) * 197] = f2bf(v.z);
  row[(f0 + 3) * 197] = f2bf(v.w);
}

// ---------------------------------------------------------------------------
// Spatial QKV, one launch. grid (4,13,24), z = w*8+h (after swizzle).
// w<2: q/k = xnb(1576x512) @ Wslab^T -> (h,b*m,e), RoPE fused in epilogue.
// w=2: v^T = Wv^T(512x512) @ xnb^T -> vt (h,b,e,m_pad).
__global__ __launch_bounds__(256) void qkv_kernel(const u16* __restrict__ xnb,
                                                  const u16* __restrict__ WtL,
                                                  u16* __restrict__ q,
                                                  const float* __restrict__ csP) {
  int wg = swz_flat();
  int bx = wg & 3, tmp = wg >> 2;
  int by = tmp % 13, bz = tmp / 13;
  int w = bz >> 3, h = bz & 7;
  __shared__ __align__(16) u16 As[3 * 4096];
  __shared__ __align__(16) u16 Bs[3 * 4096];
  const int tid = threadIdx.x;
  const int lane = tid & 63, wave = tid >> 6;
  const int wm = wave >> 1, wn = wave & 1;
  const int l15 = lane & 15, quad = lane >> 4;
  f32x4 acc[4][4] = {};

  if (w < 2) {
    int row0 = by * 128, col0 = bx * 128;
    const u16* B = WtL + ((long)(w * 8 + h)) * 262144;
    gemm_core(xnb, 512, 1576, row0, B, 512, 512, col0, 512, As, Bs, acc,
              tid, wm, wn, l15, quad);
    long base = (long)w * QSZ + (long)h * XSZ;
    const float2* cs2 = (const float2*)csP;
#pragma unroll
    for (int i = 0; i < 4; i++)
#pragma unroll
      for (int j = 0; j < 4; j++)
#pragma unroll
        for (int reg = 0; reg < 4; reg++) {
          int gr = row0 + wm * 64 + i * 16 + quad * 4 + reg;
          int gc = col0 + wn * 64 + j * 16 + l15;
          float v = acc[i][j][reg];
          float p = __shfl_xor(v, 1);            // all lanes execute (guard below)
          int t = gr % 197;                      // token index (bogus rows unused)
          float2 cs = cs2[t * 256 + (gc >> 1)];
          float outv = v * cs.x + ((gc & 1) ? -p * cs.y : p * cs.y);
          if (gr < 1576)
            q[base + (long)gr * 512 + gc] = f2bf(outv);
        }
  } else {
    int row0 = bx * 128, col0 = by * 128;
    const u16* A = WtL + ((long)(16 + h)) * 262144;
    gemm_core(A, 512, 512, row0, xnb, 512, 1576, col0, 512, As, Bs, acc,
              tid, wm, wn, l15, quad);
#pragma unroll
    for (int i = 0; i < 4; i++)
#pragma unroll
      for (int j = 0; j < 4; j++)
#pragma unroll
        for (int reg = 0; reg < 4; reg++) {
          int gr = row0 + wm * 64 + i * 16 + quad * 4 + reg;  // e
          int gc = col0 + wn * 64 + j * 16 + l15;             // b*197+mm
          if (gr < 512 && gc < 1576) {
            int b = gc / 197, mm = gc - b * 197;
            q[2 * QSZ + ((long)(h * 8 + b) * 512 + gr) * MP + mm] = f2bf(acc[i][j][reg]);
          }
        }
  }
}

// ---------------------------------------------------------------------------
// Token QKV, one launch. grid (4,13,6), XCD-chunked.
__global__ __launch_bounds__(256) void tok_qkv_kernel(const u16* __restrict__ yb,
                                                      const u16* __restrict__ tWt, int l,
                                                      float* __restrict__ tprt) {
  int wg = swz_flat();
  int bx = wg & 3, tmp = wg >> 2;
  int by = tmp % 13, z = tmp / 13;
  __shared__ __align__(16) u16 As[3 * 4096];
  __shared__ __align__(16) u16 Bs[3 * 4096];
  const int tid = threadIdx.x;
  const int lane = tid & 63, wave = tid >> 6;
  const int wm = wave >> 1, wn = wave & 1;
  const int l15 = lane & 15, quad = lane >> 4;
  f32x4 acc[4][4] = {};

  if (z < 4) {
    int w = z >> 1, seg = z & 1;
    int kbeg = seg * 800, KL = seg ? 776 : 800;
    int row0 = bx * 128, col0 = by * 128;
    const u16* A = yb + kbeg;
    const u16* B = tWt + ((long)(w * 2 + l)) * 2483776 + kbeg;
    gemm_core(A, 1576, 512, row0, B, 1576, 1576, col0, KL, As, Bs, acc,
              tid, wm, wn, l15, quad);
    float* dst = tprt + (long)z * XSZ;
#pragma unroll
    for (int i = 0; i < 4; i++)
#pragma unroll
      for (int j = 0; j < 4; j++)
#pragma unroll
        for (int reg = 0; reg < 4; reg++) {
          int gr = row0 + wm * 64 + i * 16 + quad * 4 + reg;
          int gc = col0 + wn * 64 + j * 16 + l15;
          if (gr < 512 && gc < 1576) dst[(long)gr * 1576 + gc] = acc[i][j][reg];
        }
  } else {
    int seg = z - 4;
    int kbeg = seg * 800, KL = seg ? 776 : 800;
    int row0 = by * 128, col0 = bx * 128;
    const u16* A = tWt + ((long)(4 + l)) * 2483776 + kbeg;
    const u16* B = yb + kbeg;
    gemm_core(A, 1576, 1576, row0, B, 1576, 512, col0, KL, As, Bs, acc,
              tid, wm, wn, l15, quad);
    float* dst = tprt + (long)(4 + seg) * XSZ;
#pragma unroll
    for (int i = 0; i < 4; i++)
#pragma unroll
      for (int j = 0; j < 4; j++)
#pragma unroll
        for (int reg = 0; reg < 4; reg++) {
          int gr = row0 + wm * 64 + i * 16 + quad * 4 + reg;
          int gc = col0 + wn * 64 + j * 16 + l15;
          if (gr < 1576 && gc < 512) dst[(long)gr * 512 + gc] = acc[i][j][reg];
        }
  }
}

// Reduce token split-K partials: rope(tq), rope(tk), transpose(tv) -> bf16.
// Pair-vectorized: one thread handles the (even,odd) RoPE pair for tq AND tk,
// plus two tv elements. grid 1576 x 256 (= XSZ/2 threads).
// tqb layout contract: tkb = tqb + XSZ, tvt = tqb + 2*XSZ.
__global__ void token_finish_kernel(const float* __restrict__ tp,
                                    const float* __restrict__ cosT,
                                    const float* __restrict__ sinT,
                                    u16* __restrict__ tqb) {
  int p2 = blockIdx.x * 256 + threadIdx.x;   // pair index, < XSZ/2
  int r = p2 / 788, gp = p2 - r * 788;       // row, pair-in-row (NTD/2=788)
  int t = r & 63;
  float cv = cosT[(long)t * 788 + gp];
  float sv = sinT[(long)t * 788 + gp];
  const float2* tp2 = (const float2*)tp;
  long pr = (long)r * 788 + gp;              // float2 index of the pair
  // tq = seg0 + seg1 partials
  float2 a0 = tp2[pr], a1 = tp2[(XSZ >> 1) + pr];
  float ve = a0.x + a1.x, vo = a0.y + a1.y;
  u16x2 hq = { f2bf(ve * cv + vo * sv), f2bf(-ve * sv + vo * cv) };
  ((u16x2*)tqb)[pr] = hq;
  // tk
  float2 b0 = tp2[2 * (XSZ >> 1) + pr], b1 = tp2[3 * (XSZ >> 1) + pr];
  ve = b0.x + b1.x; vo = b0.y + b1.y;
  u16x2 hk = { f2bf(ve * cv + vo * sv), f2bf(-ve * sv + vo * cv) };
  ((u16x2*)(tqb + XSZ))[pr] = hk;
  // tv: two consecutive idx = 2*p2, 2*p2+1 in the (1576 x 512) partial layout
  long i0 = (long)p2 * 2;
  int g2 = (int)(i0 >> 9), r2 = (int)(i0 & 511);    // r2 even
  float2 c0 = tp2[4 * (XSZ >> 1) + p2], c1 = tp2[5 * (XSZ >> 1) + p2];
  u16x2 hv = { f2bf(c0.x + c1.x), f2bf(c0.y + c1.y) };
  long vo2 = 2 * XSZ + ((long)(r2 >> 6) * NTD + g2) * 64 + (r2 & 63);
  *(u16x2*)(tqb + vo2) = hv;
}

// ---------------------------------------------------------------------------
// Generic MFMA GEMM for the remaining shapes. XCD-chunked work mapping.
// EPI_TOKPV additionally accumulates per-batch sum(x^2) into sqout[z2].
enum { EPI_BF16 = 0, EPI_F32 = 1, EPI_TOKPV = 3, EPI_PATCH = 4 };

template <int EPI>
__global__ __launch_bounds__(256) void mfma_gemm(
    const u16* __restrict__ A, const u16* __restrict__ B, void* __restrict__ Cv,
    const float* __restrict__ resid, float* __restrict__ sqout,
    int M, int N, int K, int lda, int ldb, int ldc, float alpha, int nz2,
    long aS2, long bS1, long bS2, long cS1, long cS2) {
  int wg = swz_flat();
  int bx = wg % gridDim.x; int tmp = wg / gridDim.x;
  int by = tmp % gridDim.y; int z = tmp / gridDim.y;
  int z1 = z / nz2, z2 = z - z1 * nz2;
  A += z2 * aS2;
  B += z1 * bS1 + z2 * bS2;
  __shared__ __align__(16) u16 As[3 * 4096];
  __shared__ __align__(16) u16 Bs[3 * 4096];
  const int tid = threadIdx.x;
  const int lane = tid & 63, wave = tid >> 6;
  const int wm = wave >> 1, wn = wave & 1;
  const int l15 = lane & 15, quad = lane >> 4;
  const int row0 = by * 128, col0 = bx * 128;
  f32x4 acc[4][4] = {};
  gemm_core(A, lda, M, row0, B, ldb, N, col0, K, As, Bs, acc, tid, wm, wn, l15, quad);

  float* Cf = (float*)Cv;
  u16* Ch = (u16*)Cv;
  const long cbase = z1 * cS1 + z2 * cS2;
  float ssq = 0.f;
#pragma unroll
  for (int i = 0; i < 4; i++)
#pragma unroll
    for (int j = 0; j < 4; j++)
#pragma unroll
      for (int reg = 0; reg < 4; reg++) {
        int gr = row0 + wm * 64 + i * 16 + quad * 4 + reg;
        int gc = col0 + wn * 64 + j * 16 + l15;
        if (gr >= M || gc >= N) continue;
        float vv = acc[i][j][reg] * alpha;
        if (EPI == EPI_BF16) {
          Ch[cbase + (long)gr * ldc + gc] = f2bf(vv);
        } else if (EPI == EPI_F32) {
          Cf[cbase + (long)gr * ldc + gc] = vv;
        } else if (EPI == EPI_TOKPV) {    // x[b][mm][c*8+f] = acc + xn
          int f = gc / 197, mm = gc - f * 197;
          long o = ((long)z2 * 197 + mm) * 512 + gr * 8 + f;
          float xv = vv + resid[o];
          Cf[o] = xv;
          ssq += xv * xv;
        } else {                          // PATCH: x[b][1+p][gc] = acc + bias
          int b = gr / 196, p = gr - b * 196;
          Cf[((long)b * 197 + 1 + p) * 512 + gc] = vv + resid[gc];
        }
      }
  if (EPI == EPI_TOKPV) {
    __syncthreads();                       // LDS no longer needed by gemm
    float* red = (float*)As;
    red[tid] = ssq; __syncthreads();
    for (int o2 = 128; o2; o2 >>= 1) {
      if (tid < o2) red[tid] += red[tid + o2];
      __syncthreads();
    }
    if (tid == 0) atomicAdd(&sqout[z2], red[0]);
  }
}

// ---------------------------------------------------------------------------
// Token scores, split-K: grid (split=8, b=8). tsp[(s*8+b)][64][64] partials.
// 3-slot ring + counted vmcnt (same discipline as gemm_core).
__global__ __launch_bounds__(256) void token_scores_kernel(const u16* __restrict__ tq,
                                                           const u16* __restrict__ tk,
                                                           float* __restrict__ tsp) {
  int s = blockIdx.x, b = blockIdx.y;
  const u16* A = tq + (long)b * 64 * NTD;
  const u16* B = tk + (long)b * 64 * NTD;
  __shared__ __align__(16) u16 As[3 * 2048];
  __shared__ __align__(16) u16 Bs[3 * 2048];
  int tid = threadIdx.x, lane = tid & 63, w = tid >> 6;
  int l15 = lane & 15, quad = lane >> 4;
  f32x4 acc[4] = {};
  const int r = tid >> 2;
  const int cs = (((tid & 3) ^ ((r >> 1) & 3)) << 3);
  const u16* pa = A + (long)r * NTD + cs;
  const u16* pbp = B + (long)r * NTD + cs;
  const int lb = (tid & ~63) * 8;

  auto stage = [&](int ch, int bi) {
    async_cp16(pa + ch * 32, &As[bi + lb]);
    async_cp16(pbp + ch * 32, &Bs[bi + lb]);
  };
  auto compute = [&](int bi) {
    int row = w * 16 + l15;
    bf16x8 av = *(const bf16x8*)&As[bi + row * 32 + ((quad ^ ((row >> 1) & 3)) << 3)];
#pragma unroll
    for (int j = 0; j < 4; j++) {
      int rb = j * 16 + l15;
      bf16x8 bv = *(const bf16x8*)&Bs[bi + rb * 32 + ((quad ^ ((rb >> 1) & 3)) << 3)];
      acc[j] = __builtin_amdgcn_mfma_f32_16x16x32_bf16(av, bv, acc[j], 0, 0, 0);
    }
  };

  int ch0 = s * 6, nch = (s == 7) ? 7 : 6;
  stage(ch0, 0);
  stage(ch0 + 1, 2048);
  for (int c = 0; c < nch; c++) {
    if (c + 1 < nch) {
      asm volatile("s_waitcnt vmcnt(2)" ::: "memory");
    } else {
      asm volatile("s_waitcnt vmcnt(0)" ::: "memory");
    }
    __builtin_amdgcn_s_barrier();
    if (c + 2 < nch) stage(ch0 + c + 2, ((c + 2) % 3) * 2048);
    compute((c % 3) * 2048);
  }
  if (s == 7) {  // 8-element K tail at k=1568
    const int tb = (nch % 3) * 2048;
    __syncthreads();
    for (int idx = tid; idx < 2048; idx += 256) {
      int rr = idx >> 5, cc = idx & 31;
      int g = ((((cc >> 3) ^ ((rr >> 1) & 3)) << 3)) | (cc & 7);
      As[tb + idx] = (g < 8) ? A[(long)rr * NTD + 1568 + g] : (u16)0;
      Bs[tb + idx] = (g < 8) ? B[(long)rr * NTD + 1568 + g] : (u16)0;
    }
    __syncthreads();
    compute(tb);
  }
  const float sc = rsqrtf(1576.f);
  float* dst = tsp + ((long)(s * 8 + b)) * 4096;
#pragma unroll
  for (int j = 0; j < 4; j++)
#pragma unroll
    for (int reg = 0; reg < 4; reg++) {
      int row = w * 16 + quad * 4 + reg, col = j * 16 + l15;
      dst[row * 64 + col] = acc[j][reg] * sc;
    }
}

// ---------------------------------------------------------------------------
// Spatial softmax: s fp32 (64,197,197) -> pb bf16 (64,197,208). 4 rows/block.
__global__ void softmax_spatial_kernel(const float* __restrict__ s, u16* __restrict__ pb) {
  int row = blockIdx.x * 4 + (threadIdx.x >> 6);
  int lane = threadIdx.x & 63;
  const float* p = s + (long)row * 197;
  int hb = row / 197, mm = row - hb * 197;
  u16* q = pb + (long)hb * 197 * MP + (long)mm * MP;
  float mx = -INFINITY;
  for (int j = lane; j < 197; j += 64) mx = fmaxf(mx, p[j]);
#pragma unroll
  for (int off = 32; off; off >>= 1) mx = fmaxf(mx, __shfl_xor(mx, off));
  float sum = 0.f;
  float ev[4];
  int cnt = 0;
  for (int j = lane; j < 197; j += 64) { ev[cnt] = expf(p[j] - mx); sum += ev[cnt]; cnt++; }
#pragma unroll
  for (int off = 32; off; off >>= 1) sum += __shfl_xor(sum, off);
  float inv = 1.f / sum;
  cnt = 0;
  for (int j = lane; j < 197; j += 64) { q[j] = f2bf(ev[cnt] * inv); cnt++; }
}

// Token softmax: sums 8 split-K partials, softmaxes, writes Pb bf16.
__global__ void softmax_token_kernel(const float* __restrict__ tsp, u16* __restrict__ Pb) {
  int row = blockIdx.x * 4 + (threadIdx.x >> 6);  // 0..511 = b*64+r
  int lane = threadIdx.x & 63;
  int b = row >> 6, r = row & 63;
  float v = 0.f;
#pragma unroll
  for (int p = 0; p < 8; p++) v += tsp[((long)(p * 8 + b)) * 4096 + r * 64 + lane];
  float mx = v;
#pragma unroll
  for (int off = 32; off; off >>= 1) mx = fmaxf(mx, __shfl_xor(mx, off));
  float e = expf(v - mx);
  float sum = e;
#pragma unroll
  for (int off = 32; off; off >>= 1) sum += __shfl_xor(sum, off);
  Pb[(long)row * 64 + lane] = f2bf(e / sum);
}

// ---------------------------------------------------------------------------
// Attn output reduce + residual, vectorized x4; fused per-batch sum(x^2).
// grid 788 x 256. A block (1024 elems) may straddle ONE batch boundary ->
// segmented 2-slot reduce.
__global__ void attn_reduce_kernel(const float* __restrict__ part, const float* __restrict__ bias,
                                   const float* __restrict__ resid, float* __restrict__ x,
                                   float* __restrict__ sqslot) {
  int idx4 = blockIdx.x * 256 + threadIdx.x;
  long base = (long)idx4 * 4;
  int col = (int)(base % ND);
  float4 sv = *(const float4*)(bias + col);
  float4 rv = ((const float4*)resid)[idx4];
  sv.x += rv.x; sv.y += rv.y; sv.z += rv.z; sv.w += rv.w;
#pragma unroll
  for (int h = 0; h < 8; h++) {
    float4 pv = ((const float4*)part)[(h * (XSZ >> 2)) + idx4];
    sv.x += pv.x; sv.y += pv.y; sv.z += pv.z; sv.w += pv.w;
  }
  ((float4*)x)[idx4] = sv;
  float ssq = sv.x * sv.x + sv.y * sv.y + sv.z * sv.z + sv.w * sv.w;
  int b = (int)(base / BMD);
  int bfirst = (int)(((long)blockIdx.x * 1024) / BMD);
  float s0 = (b == bfirst) ? ssq : 0.f;
  float s1 = ssq - s0;
  __shared__ float red0[256], red1[256];
  red0[threadIdx.x] = s0; red1[threadIdx.x] = s1; __syncthreads();
  for (int o = 128; o; o >>= 1) {
    if (threadIdx.x < o) {
      red0[threadIdx.x] += red0[threadIdx.x + o];
      red1[threadIdx.x] += red1[threadIdx.x + o];
    }
    __syncthreads();
  }
  if (threadIdx.x == 0) {
    atomicAdd(&sqslot[bfirst], red0[0]);
    if (red1[0] != 0.f) atomicAdd(&sqslot[bfirst + 1], red1[0]);
  }
}

// ---------------------------------------------------------------------------
// Merged Wqkv (48 slabs, z = l*24 + w*8 + h) + attn_W (16 slabs: l*8 + i).
// grid (16,16,64).
__global__ void transpose_wa_kernel(const float* __restrict__ Wq, const float* __restrict__ Wk,
                                    const float* __restrict__ Wv, const float* __restrict__ attn_W,
                                    u16* __restrict__ Wt16, u16* __restrict__ Wat16) {
  int z = blockIdx.z;
  const float* src;
  u16* dst;
  long dld;
  if (z < 48) {
    int l = z / 24, rem = z - l * 24, w = rem >> 3, h = rem & 7;
    src = (w == 0 ? Wq : w == 1 ? Wk : Wv) + (long)(l * 8 + h) * 262144;
    dst = Wt16 + (long)z * 262144;
    dld = 512;
  } else {
    int za = z - 48, l = za >> 3, i = za & 7;   // 8 row-blocks per layer
    src = attn_W + (long)l * 4096 * 512 + (long)i * 512 * 512;
    dst = Wat16 + (long)l * 512 * 4096 + (long)i * 512;
    dld = 4096;
  }
  __shared__ float t[32][33];
  int c0 = blockIdx.x * 32, r0 = blockIdx.y * 32;
  int tx = threadIdx.x, ty = threadIdx.y;
#pragma unroll
  for (int i = 0; i < 4; i++)
    t[ty + i * 8][tx] = src[(long)(r0 + ty + i * 8) * 512 + c0 + tx];
  __syncthreads();
#pragma unroll
  for (int i = 0; i < 4; i++)
    dst[(long)(c0 + ty + i * 8) * dld + r0 + tx] = f2bf(t[tx][ty + i * 8]);
}

// Generic transpose fp32 (RxC) -> bf16 (CxR) (used for patch_W).
__global__ void transpose_bf16_kernel(const float* __restrict__ src, u16* __restrict__ dst,
                                      int R, int C) {
  __shared__ float t[32][33];
  int c0 = blockIdx.x * 32, r0 = blockIdx.y * 32;
  int tx = threadIdx.x, ty = threadIdx.y;
#pragma unroll
  for (int i = 0; i < 4; i++) {
    int r = r0 + ty + i * 8;
    if (r < R && c0 + tx < C) t[ty + i * 8][tx] = src[(long)r * C + c0 + tx];
  }
  __syncthreads();
#pragma unroll
  for (int i = 0; i < 4; i++) {
    int c = c0 + ty + i * 8;
    if (c < C && r0 + tx < R) dst[(long)c * R + r0 + tx] = f2bf(t[tx][ty + i * 8]);
  }
}

// Merged tWq/tWk/tWv transpose: grid (50,50,6), z = w*2 + l.
__global__ void t_transpose3_kernel(const float* __restrict__ Wq, const float* __restrict__ Wk,
                                    const float* __restrict__ Wv, u16* __restrict__ dst0) {
  int z = blockIdx.z;
  int w = z >> 1, l = z & 1;
  const float* src = (w == 0 ? Wq : w == 1 ? Wk : Wv) + (long)l * NTD * NTD;
  u16* d = dst0 + (long)z * NTD * NTD;
  __shared__ float t[32][33];
  int c0 = blockIdx.x * 32, r0 = blockIdx.y * 32;
  int tx = threadIdx.x, ty = threadIdx.y;
#pragma unroll
  for (int i = 0; i < 4; i++) {
    int r = r0 + ty + i * 8;
    if (r < NTD && c0 + tx < NTD) t[ty + i * 8][tx] = src[(long)r * NTD + c0 + tx];
  }
  __syncthreads();
#pragma unroll
  for (int i = 0; i < 4; i++) {
    int c = c0 + ty + i * 8;
    if (c < NTD && r0 + tx < NTD) d[(long)c * NTD + r0 + tx] = f2bf(t[tx][ty + i * 8]);
  }
}

// ---------------------------------------------------------------------------
// Fused cls LayerNorm + head GEMM. grid (4,8), 256 thr (LN redone per block).
__global__ void ln_head_kernel(const float* __restrict__ x, const float* __restrict__ g,
                               const float* __restrict__ bb, const float* __restrict__ W,
                               const float* __restrict__ hb, float* __restrict__ out) {
  int b = blockIdx.y, t = threadIdx.x;
  __shared__ float xs[512];
  __shared__ float red[256];
  float v0 = x[(long)b * NM * ND + t];
  float v1 = x[(long)b * NM * ND + 256 + t];
  red[t] = v0 + v1; __syncthreads();
  for (int o = 128; o; o >>= 1) { if (t < o) red[t] += red[t + o]; __syncthreads(); }
  float mu = red[0] / 512.f; __syncthreads();
  float d0 = v0 - mu, d1 = v1 - mu;
  red[t] = d0 * d0 + d1 * d1; __syncthreads();
  for (int o = 128; o; o >>= 1) { if (t < o) red[t] += red[t + o]; __syncthreads(); }
  float inv = rsqrtf(red[0] / 512.f + 1e-5f); __syncthreads();
  xs[t] = d0 * inv * g[t] + bb[t];
  xs[256 + t] = d1 * inv * g[256 + t] + bb[256 + t];
  __syncthreads();
  int n = blockIdx.x * 250 + t;
  if (t < 250 && n < 1000) {
    float acc = hb[n];
    for (int dd = 0; dd < 512; dd++) acc += xs[dd] * W[(long)dd * 1000 + n];
    out[(long)b * 1000 + n] = acc;
  }
}

}  // namespace

extern "C" void kernel_launch(void* const* d_in, const int* in_sizes, int n_in,
                              void* d_out, int out_size, void* d_ws, size_t ws_size,
                              hipStream_t stream) {
  const float* img     = (const float*)d_in[0];
  const float* patch_W = (const float*)d_in[1];
  const float* patch_b = (const float*)d_in[2];
  const float* cls_tok = (const float*)d_in[3];
  const float* rms_s   = (const float*)d_in[4];
  const float* Wq      = (const float*)d_in[5];
  const float* Wk      = (const float*)d_in[6];
  const float* Wv      = (const float*)d_in[7];
  const float* attn_W  = (const float*)d_in[8];
  const float* attn_b  = (const float*)d_in[9];
  const float* tWq     = (const float*)d_in[10];
  const float* tWk     = (const float*)d_in[11];
  const float* tWv     = (const float*)d_in[12];
  const float* ln_g    = (const float*)d_in[13];
  const float* ln_b    = (const float*)d_in[14];
  const float* head_W  = (const float*)d_in[15];
  const float* head_b  = (const float*)d_in[16];
  float* out = (float*)d_out;

  // ---- workspace layout (floats) ----
  float* base = (float*)d_ws;
  long off = 0;
  auto alloc = [&](long n) { float* r = base + off; off += (n + 15) & ~15L; return r; };
  float* cosP = alloc(TABSZ);       // interleaved (cos,sin) float2 table spans
  float* sinP = alloc(TABSZ);       //   cosP..sinP (2*TABSZ floats contiguous)
  float* cosT = alloc(TABSZ);
  float* sinT = alloc(TABSZ);
  float* x    = alloc(XSZ);
  float* xn   = alloc(XSZ);
  float* Wt_f   = alloc(6291456);   // 48 slabs 512x512 bf16, z = l*24+w*8+h
  float* Wat_f  = alloc(2097152);   // (l) 512x4096 bf16
  float* tWt_f  = alloc(7451328);   // (w,l) 1576x1576 bf16
  float* xnb_f  = alloc(XSZ / 2);
  float* pimg_f = alloc(602112);    // 1568x768 bf16
  float* pWt_f  = alloc(196608);    // 512x768 bf16
  float* U      = alloc(16885824);  // union region
  float* ff     = alloc(64);        // 8x8 partials for the first RMS
  float* ffs    = alloc(64);        // fused sq-sum slots: [0]=attn l0, [8]=tok l0,
                                    //   [16]=attn l1, [24]=tok l1 (unused-read)

  u16* Wt16  = (u16*)Wt_f;
  u16* Wat16 = (u16*)Wat_f;
  u16* tWt16 = (u16*)tWt_f;
  u16* xnb   = (u16*)xnb_f;
  u16* pimg  = (u16*)pimg_f;
  u16* pWt   = (u16*)pWt_f;
  // phase A overlay (contract: kk = q + QSZ, vt = q + 2*QSZ)
  u16* q   = (u16*)U;                 // 6455296 (h, b*m, e)
  u16* kk  = q + QSZ;                 // 6455296
  u16* vt  = kk + QSZ;                // 6815744 (h,b,e,m_pad)
  float* s = (float*)(vt + 6815744);  // 2483776 f (hb,197,197)
  u16* pb  = (u16*)(s + 2483776);     // 2622464 (hb,197,208)
  u16* o   = pb + 2622464;            // 6455296 (h, b*m, e)
  float* part = (float*)q;            // 8*XSZ fp32 (aliases dead q,kk)
  // phase B overlay (contract: tkb = tqb + XSZ, tvt = tqb + 2*XSZ)
  u16* yb     = (u16*)U;              // 806912 (b*64+c, 1576)
  float* tprt = (float*)(yb + XSZ);   // 6*XSZ fp32 split partials
  u16* tqb    = (u16*)(tprt + 6 * XSZ);
  u16* tvt    = tqb + 2 * XSZ;        // (b, 1576, 64)
  float* tsp  = (float*)(tvt + XSZ);  // 8 x 8 x 64 x 64
  u16* Pb     = (u16*)(tsp + 262144); // 8*64*64

  const float rs512 = 1.f / sqrtf(512.f);
  const dim3 tt(32, 8);

  // ---- setup ----
  init_kernel<<<5115, 256, 0, stream>>>(img, cls_tok, cosP, sinP, cosT, sinT, pimg, x, ffs);
  transpose_bf16_kernel<<<dim3(16, 24), tt, 0, stream>>>(patch_W, pWt, 768, 512);
  transpose_wa_kernel<<<dim3(16, 16, 64), tt, 0, stream>>>(Wq, Wk, Wv, attn_W, Wt16, Wat16);
  t_transpose3_kernel<<<dim3(50, 50, 6), tt, 0, stream>>>(tWq, tWk, tWv, tWt16);
  mfma_gemm<EPI_PATCH><<<dim3(4, 13, 1), 256, 0, stream>>>(
      pimg, pWt, x, patch_b, nullptr, 1568, 512, 768, 768, 768, 512, 1.f, 1, 0, 0, 0, 0, 0);

  for (int l = 0; l < 2; l++) {
    const float* scale = rms_s + (long)l * NM * ND;
    float* slotA = ffs + l * 16;       // attn-phase sq-sums for this layer
    float* slotT = ffs + l * 16 + 8;   // token-phase sq-sums for this layer
    // ---- spatial attention ----
    if (l == 0) {
      rms_part_kernel<<<dim3(8, 8), 256, 0, stream>>>(x, ff);
      rms_apply_kernel<<<788, 256, 0, stream>>>(x, scale, ff, 8, xn, xnb);
    } else {
      // sq-sums were accumulated by the previous layer's token-PV epilogue
      rms_apply_kernel<<<788, 256, 0, stream>>>(x, scale, ffs + 8, 1, xn, xnb);
    }

    // qkv with fused RoPE on q,k
    qkv_kernel<<<dim3(4, 13, 24), 256, 0, stream>>>(xnb, Wt16 + (long)l * 24 * 262144, q, cosP);

    // scores (fp32, scaled)
    mfma_gemm<EPI_F32><<<dim3(2, 2, 64), 256, 0, stream>>>(
        q, kk, s, nullptr, nullptr, 197, 197, 512, 512, 512, 197, rs512, 64,
        197L * 512, 0, 197L * 512, 0, 197L * 197);
    softmax_spatial_kernel<<<3152, 256, 0, stream>>>(s, pb);
    // o = P @ v
    mfma_gemm<EPI_BF16><<<dim3(4, 2, 64), 256, 0, stream>>>(
        pb, vt, o, nullptr, nullptr, 197, 512, 197, MP, MP, 512, 1.f, 64,
        197L * MP, 0, 512L * MP, 0, 197L * 512);
    // attn-proj head partials
    mfma_gemm<EPI_F32><<<dim3(4, 13, 8), 256, 0, stream>>>(
        o, Wat16 + (long)l * 2097152, part, nullptr, nullptr, 1576, 512, 512, 512, 4096, 512, 1.f, 8,
        XSZ, 0, 512, 0, XSZ);
    // reduce + residual + fused sum(x^2) into slotA
    attn_reduce_kernel<<<788, 256, 0, stream>>>(part, attn_b + (long)l * ND, xn, x, slotA);

    // ---- token mixing ----
    rms_apply_tok_kernel<<<788, 256, 0, stream>>>(x, scale, slotA, 1, xn, yb);

    tok_qkv_kernel<<<dim3(4, 13, 6), 256, 0, stream>>>(yb, tWt16, l, tprt);
    token_finish_kernel<<<1576, 256, 0, stream>>>(tprt, cosT, sinT, tqb);

    token_scores_kernel<<<dim3(8, 8), 256, 0, stream>>>(tqb, tqb + XSZ, tsp);
    softmax_token_kernel<<<128, 256, 0, stream>>>(tsp, Pb);
    // token PV: scatter + residual into fp32 x; fused sum(x^2) into slotT
    mfma_gemm<EPI_TOKPV><<<dim3(13, 1, 8), 256, 0, stream>>>(
        Pb, tvt, x, xn, slotT, 64, 1576, 64, 64, 64, 0, 1.f, 8,
        4096, 0, 1576L * 64, 0, 0);
  }

  ln_head_kernel<<<dim3(4, 8), 256, 0, stream>>>(x, ln_g, ln_b, head_W, head_b, out);
}

// Round 6
// 670.156 us; speedup vs baseline: 1.1317x; 1.0181x over previous
//
#include <hip/hip_runtime.h>
#include <math.h>

// B=8, m=197, dim=512, heads=8, depth=2, F=8, tdim=1576, cdim=64, ncls=1000.
namespace {

typedef unsigned short u16;
typedef __attribute__((ext_vector_type(8))) short bf16x8;
typedef __attribute__((ext_vector_type(4))) float f32x4;
typedef __attribute__((ext_vector_type(4))) unsigned short u16x4;
typedef __attribute__((ext_vector_type(2))) unsigned short u16x2;

constexpr int NB = 8, NM = 197, ND = 512, NH = 8, NTD = 1576, NC = 64;
constexpr long XSZ = (long)NB * NM * ND;        // 806912
constexpr long QSZ = (long)NH * XSZ;            // 6455296 (h, b*m, e)
constexpr long TABSZ = 50432;                   // 197*256 == 64*788
constexpr int MP = 208;                         // padded 197 (16B-aligned bf16 rows)
constexpr int BMD = NM * ND;                    // 100864 per-batch elems

__device__ __forceinline__ u16 f2bf(float f) {
  union { float f; unsigned u; } v; v.f = f;
  unsigned r = v.u + 0x7FFF + ((v.u >> 16) & 1);
  return (u16)(r >> 16);
}
__device__ __forceinline__ void async_cp16(const void* g, void* l) {
  __builtin_amdgcn_global_load_lds((const __attribute__((address_space(1))) unsigned*)g,
                                   (__attribute__((address_space(3))) unsigned*)l, 16, 0, 0);
}

// Bijective XCD-chunk swizzle (m204).
__device__ __forceinline__ int xcd_swz(int orig, int nwg) {
  int q = nwg >> 3, r = nwg & 7, x = orig & 7, i = orig >> 3;
  return (x < r ? x * (q + 1) : r * (q + 1) + (x - r) * q) + i;
}
__device__ __forceinline__ int swz_flat() {
  int nwg = gridDim.x * gridDim.y * gridDim.z;
  int orig = blockIdx.x + gridDim.x * (blockIdx.y + gridDim.y * blockIdx.z);
  return xcd_swz(orig, nwg);
}

// ---------------------------------------------------------------------------
// Shared MFMA GEMM core: acc += A(M x KL) * B^T(N x KL), 128x128 tile, BK=32.
// Depth-2 prefetch: 3-slot LDS ring, raw s_barrier + counted vmcnt(4).
__device__ __forceinline__ void gemm_core(
    const u16* __restrict__ A, int lda, int M, int row0,
    const u16* __restrict__ B, int ldb, int N, int col0,
    int KL, u16* As, u16* Bs, f32x4 (&acc)[4][4],
    int tid, int wm, int wn, int l15, int quad) {
  const int nfull = KL >> 5, tail = KL & 31;
  const int r = tid >> 2;
  const int cs = (((tid & 3) ^ ((r >> 1) & 3)) << 3);
  int gr0 = row0 + r;      if (gr0 >= M) gr0 = M - 1;
  int gr1 = row0 + r + 64; if (gr1 >= M) gr1 = M - 1;
  int gc0 = col0 + r;      if (gc0 >= N) gc0 = N - 1;
  int gc1 = col0 + r + 64; if (gc1 >= N) gc1 = N - 1;
  const u16* pa0 = A + (long)gr0 * lda + cs;
  const u16* pa1 = A + (long)gr1 * lda + cs;
  const u16* pb0 = B + (long)gc0 * ldb + cs;
  const u16* pb1 = B + (long)gc1 * ldb + cs;
  const int lb0 = (tid & ~63) * 8;
  const int lb1 = lb0 + 2048;

  auto stage = [&](int k0, int bi) {
    async_cp16(pa0 + k0, &As[bi + lb0]);
    async_cp16(pa1 + k0, &As[bi + lb1]);
    async_cp16(pb0 + k0, &Bs[bi + lb0]);
    async_cp16(pb1 + k0, &Bs[bi + lb1]);
  };
  auto compute = [&](int bi) {
    bf16x8 af[4], bg[4];
#pragma unroll
    for (int i = 0; i < 4; i++) {
      int row = wm * 64 + i * 16 + l15;
      af[i] = *(const bf16x8*)&As[bi + row * 32 + ((quad ^ ((row >> 1) & 3)) << 3)];
    }
#pragma unroll
    for (int j = 0; j < 4; j++) {
      int row = wn * 64 + j * 16 + l15;
      bg[j] = *(const bf16x8*)&Bs[bi + row * 32 + ((quad ^ ((row >> 1) & 3)) << 3)];
    }
#pragma unroll
    for (int i = 0; i < 4; i++)
#pragma unroll
      for (int j = 0; j < 4; j++)
        acc[i][j] = __builtin_amdgcn_mfma_f32_16x16x32_bf16(af[i], bg[j], acc[i][j], 0, 0, 0);
  };

  if (nfull > 0) {
    stage(0, 0);
    if (nfull > 1) stage(32, 4096);
    for (int ch = 0; ch < nfull; ch++) {
      if (ch + 1 < nfull) {
        asm volatile("s_waitcnt vmcnt(4)" ::: "memory");
      } else {
        asm volatile("s_waitcnt vmcnt(0)" ::: "memory");
      }
      __builtin_amdgcn_s_barrier();
      if (ch + 2 < nfull) stage((ch + 2) << 5, ((ch + 2) % 3) * 4096);
      compute((ch % 3) * 4096);
    }
  }
  if (tail) {
    const int tb = (nfull % 3) * 4096;
    const int k0f = nfull << 5;
    if (nfull > 0) __syncthreads();
    for (int idx2 = tid; idx2 < 4096; idx2 += 256) {
      int rr = idx2 >> 5, cc = idx2 & 31;
      int g = ((((cc >> 3) ^ ((rr >> 1) & 3)) << 3)) | (cc & 7);
      int grr = row0 + rr; if (grr >= M) grr = M - 1;
      int gcc = col0 + rr; if (gcc >= N) gcc = N - 1;
      As[tb + idx2] = (g < tail) ? A[(long)grr * lda + k0f + g] : (u16)0;
      Bs[tb + idx2] = (g < tail) ? B[(long)gcc * ldb + k0f + g] : (u16)0;
    }
    __syncthreads();
    compute(tb);
  }
}

// ---------------------------------------------------------------------------
// init: RoPE tables + patch gather + cls fill + zero sq-sum slots. One launch.
// grid 5115 x 256. Spatial table is INTERLEAVED (cos,sin) float2 in cosP.
__global__ void init_kernel(const float* __restrict__ img, const float* __restrict__ cls,
                            float* cosP, float* sinP, float* cosT, float* sinT,
                            u16* __restrict__ pimg, float* __restrict__ x,
                            float* __restrict__ ffs) {
  long idx = (long)blockIdx.x * 256 + threadIdx.x;
  if (idx < 197 * 256) {
    int p = (int)(idx / 256), i = (int)(idx % 256);
    float theta = powf(10000.f, -2.f * ((float)i - 1.f) / 512.f);
    float a = (float)p * theta;
    cosP[2 * idx] = cosf(a); cosP[2 * idx + 1] = sinf(a);
    return;
  }
  long j = idx - 197 * 256;
  if (j < 64 * 788) {
    int p = (int)(j / 788), i = (int)(j % 788);
    float theta = powf(10000.f, -2.f * ((float)i - 1.f) / 1576.f);
    float a = (float)p * theta;
    cosT[j] = cosf(a); sinT[j] = sinf(a);
    return;
  }
  long k2 = j - 64 * 788;
  if (k2 < 1568L * 768) {
    int r = (int)(k2 / 768), k = (int)(k2 % 768);
    int b = r / 196, p = r - b * 196;
    int pi = p / 14, pj = p - pi * 14;
    int cc = k % 3, pq = k / 3, pp = pq >> 4, qq = pq & 15;
    pimg[k2] = f2bf(img[((long)(b * 3 + cc) * 224 + pi * 16 + pp) * 224 + pj * 16 + qq]);
    return;
  }
  long c2 = k2 - 1568L * 768;
  if (c2 < 8 * 512) {
    int b = (int)(c2 >> 9), e = (int)(c2 & 511);
    x[((long)b * NM) * ND + e] = cls[e];
    return;
  }
  long c3 = c2 - 8 * 512;
  if (c3 < 64) ffs[c3] = 0.f;   // zero the fused sq-sum slots
}

// ---------------------------------------------------------------------------
// Two-stage per-batch RMS (only for the first RMS after patch embed). float4.
__global__ void rms_part_kernel(const float* __restrict__ x, float* __restrict__ part64) {
  int i = blockIdx.x, b = blockIdx.y;
  const float4* p = (const float4*)(x + (long)b * BMD + (long)i * 12608);
  float s = 0.f;
  for (int j = threadIdx.x; j < 3152; j += 256) {
    float4 v = p[j];
    s += v.x * v.x + v.y * v.y + v.z * v.z + v.w * v.w;
  }
  __shared__ float red[256];
  red[threadIdx.x] = s; __syncthreads();
  for (int off = 128; off; off >>= 1) {
    if (threadIdx.x < off) red[threadIdx.x] += red[threadIdx.x + off];
    __syncthreads();
  }
  if (threadIdx.x == 0) part64[b * 8 + i] = red[0];
}

// np=8: sum 8 partials per batch; np=1: single pre-accumulated float.
__device__ __forceinline__ float rms_inv(const float* part, int b, int np) {
  float ssum = 0.f;
  if (np == 8) {
#pragma unroll
    for (int i = 0; i < 8; i++) ssum += part[b * 8 + i];
  } else {
    ssum = part[b];
  }
  return sqrtf((float)(NM * ND) / ssum);
}

// Vectorized x4: grid 788 x 256 (XSZ/4 = 201728 float4 threads).
__global__ void rms_apply_kernel(const float* __restrict__ x, const float* __restrict__ scale,
                                 const float* __restrict__ part, int np, float* __restrict__ xn,
                                 u16* __restrict__ xnb) {
  int idx4 = blockIdx.x * 256 + threadIdx.x;
  int b = idx4 / (BMD / 4);
  int md4 = idx4 - b * (BMD / 4);
  float ri = rms_inv(part, b, np);
  float4 xv = ((const float4*)x)[idx4];
  float4 sv = ((const float4*)(scale))[md4];
  float4 v;
  v.x = xv.x * sv.x * ri; v.y = xv.y * sv.y * ri;
  v.z = xv.z * sv.z * ri; v.w = xv.w * sv.w * ri;
  ((float4*)xn)[idx4] = v;
  u16x4 h = { f2bf(v.x), f2bf(v.y), f2bf(v.z), f2bf(v.w) };
  ((u16x4*)xnb)[idx4] = h;
}

// Phase-B vectorized: writes xn and permuted yb[(b*64+c)*1576 + f*197+mm].
__global__ void rms_apply_tok_kernel(const float* __restrict__ x, const float* __restrict__ scale,
                                     const float* __restrict__ part, int np, float* __restrict__ xn,
                                     u16* __restrict__ yb) {
  int idx4 = blockIdx.x * 256 + threadIdx.x;
  int b = idx4 / (BMD / 4);
  int md4 = idx4 - b * (BMD / 4);
  float ri = rms_inv(part, b, np);
  float4 xv = ((const float4*)x)[idx4];
  float4 sv = ((const float4*)(scale))[md4];
  float4 v;
  v.x = xv.x * sv.x * ri; v.y = xv.y * sv.y * ri;
  v.z = xv.z * sv.z * ri; v.w = xv.w * sv.w * ri;
  ((float4*)xn)[idx4] = v;
  int md = md4 * 4;
  int mm = md / ND, d0 = md - mm * ND;     // d0 % 4 == 0
  int c = d0 >> 3, f0 = d0 & 7;            // f0 in {0,4}; f = f0..f0+3
  u16* row = yb + ((long)b * 64 + c) * NTD + mm;
  row[(f0 + 0) * 197] = f2bf(v.x);
  row[(f0 + 1) * 197] = f2bf(v.y);
  row[(f0 + 2) * 197] = f2bf(v.z);
  row[(f0 + 3) * 197] = f2bf(v.w);
}

// ---------------------------------------------------------------------------
// Spatial QKV, one launch. grid (4,13,24), z = w*8+h (after swizzle).
// w<2: q/k = xnb(1576x512) @ Wslab^T -> (h,b*m,e), RoPE fused in epilogue.
// w=2: v^T = Wv^T(512x512) @ xnb^T -> vt (h,b,e,m_pad).
__global__ __launch_bounds__(256) void qkv_kernel(const u16* __restrict__ xnb,
                                                  const u16* __restrict__ WtL,
                                                  u16* __restrict__ q,
                                                  const float* __restrict__ csP) {
  int wg = swz_flat();
  int bx = wg & 3, tmp = wg >> 2;
  int by = tmp % 13, bz = tmp / 13;
  int w = bz >> 3, h = bz & 7;
  __shared__ __align__(16) u16 As[3 * 4096];
  __shared__ __align__(16) u16 Bs[3 * 4096];
  const int tid = threadIdx.x;
  const int lane = tid & 63, wave = tid >> 6;
  const int wm = wave >> 1, wn = wave & 1;
  const int l15 = lane & 15, quad = lane >> 4;
  f32x4 acc[4][4] = {};

  if (w < 2) {
    int row0 = by * 128, col0 = bx * 128;
    const u16* B = WtL + ((long)(w * 8 + h)) * 262144;
    gemm_core(xnb, 512, 1576, row0, B, 512, 512, col0, 512, As, Bs, acc,
              tid, wm, wn, l15, quad);
    long base = (long)w * QSZ + (long)h * XSZ;
    const float2* cs2 = (const float2*)csP;
#pragma unroll
    for (int i = 0; i < 4; i++)
#pragma unroll
      for (int j = 0; j < 4; j++)
#pragma unroll
        for (int reg = 0; reg < 4; reg++) {
          int gr = row0 + wm * 64 + i * 16 + quad * 4 + reg;
          int gc = col0 + wn * 64 + j * 16 + l15;
          float v = acc[i][j][reg];
          float p = __shfl_xor(v, 1);            // all lanes execute (guard below)
          int t = gr % 197;                      // token index (bogus rows unused)
          float2 cs = cs2[t * 256 + (gc >> 1)];
          float outv = v * cs.x + ((gc & 1) ? -p * cs.y : p * cs.y);
          if (gr < 1576)
            q[base + (long)gr * 512 + gc] = f2bf(outv);
        }
  } else {
    int row0 = bx * 128, col0 = by * 128;
    const u16* A = WtL + ((long)(16 + h)) * 262144;
    gemm_core(A, 512, 512, row0, xnb, 512, 1576, col0, 512, As, Bs, acc,
              tid, wm, wn, l15, quad);
#pragma unroll
    for (int i = 0; i < 4; i++)
#pragma unroll
      for (int j = 0; j < 4; j++)
#pragma unroll
        for (int reg = 0; reg < 4; reg++) {
          int gr = row0 + wm * 64 + i * 16 + quad * 4 + reg;  // e
          int gc = col0 + wn * 64 + j * 16 + l15;             // b*197+mm
          if (gr < 512 && gc < 1576) {
            int b = gc / 197, mm = gc - b * 197;
            q[2 * QSZ + ((long)(h * 8 + b) * 512 + gr) * MP + mm] = f2bf(acc[i][j][reg]);
          }
        }
  }
}

// ---------------------------------------------------------------------------
// Token QKV, one launch. grid (4,13,12), XCD-chunked. 4-way K split:
// segs 416/416/416/328 (only last has a BK tail).
// z<8 : tq/tk partials (w=z>>2, seg=z&3): C = yb(512x1576) @ tW^T -> tprt[z].
// z>=8: tv^T partials (seg=z-8): C = tWv^T(1576x1576) @ yb^T -> tprt[8+seg].
__global__ __launch_bounds__(256) void tok_qkv_kernel(const u16* __restrict__ yb,
                                                      const u16* __restrict__ tWt, int l,
                                                      float* __restrict__ tprt) {
  int wg = swz_flat();
  int bx = wg & 3, tmp = wg >> 2;
  int by = tmp % 13, z = tmp / 13;
  __shared__ __align__(16) u16 As[3 * 4096];
  __shared__ __align__(16) u16 Bs[3 * 4096];
  const int tid = threadIdx.x;
  const int lane = tid & 63, wave = tid >> 6;
  const int wm = wave >> 1, wn = wave & 1;
  const int l15 = lane & 15, quad = lane >> 4;
  f32x4 acc[4][4] = {};

  if (z < 8) {
    int w = z >> 2, seg = z & 3;
    int kbeg = seg * 416, KL = (seg < 3) ? 416 : 328;
    int row0 = bx * 128, col0 = by * 128;
    const u16* A = yb + kbeg;
    const u16* B = tWt + ((long)(w * 2 + l)) * 2483776 + kbeg;
    gemm_core(A, 1576, 512, row0, B, 1576, 1576, col0, KL, As, Bs, acc,
              tid, wm, wn, l15, quad);
    float* dst = tprt + (long)z * XSZ;
#pragma unroll
    for (int i = 0; i < 4; i++)
#pragma unroll
      for (int j = 0; j < 4; j++)
#pragma unroll
        for (int reg = 0; reg < 4; reg++) {
          int gr = row0 + wm * 64 + i * 16 + quad * 4 + reg;
          int gc = col0 + wn * 64 + j * 16 + l15;
          if (gr < 512 && gc < 1576) dst[(long)gr * 1576 + gc] = acc[i][j][reg];
        }
  } else {
    int seg = z - 8;
    int kbeg = seg * 416, KL = (seg < 3) ? 416 : 328;
    int row0 = by * 128, col0 = bx * 128;
    const u16* A = tWt + ((long)(4 + l)) * 2483776 + kbeg;
    const u16* B = yb + kbeg;
    gemm_core(A, 1576, 1576, row0, B, 1576, 512, col0, KL, As, Bs, acc,
              tid, wm, wn, l15, quad);
    float* dst = tprt + (long)(8 + seg) * XSZ;
#pragma unroll
    for (int i = 0; i < 4; i++)
#pragma unroll
      for (int j = 0; j < 4; j++)
#pragma unroll
        for (int reg = 0; reg < 4; reg++) {
          int gr = row0 + wm * 64 + i * 16 + quad * 4 + reg;
          int gc = col0 + wn * 64 + j * 16 + l15;
          if (gr < 1576 && gc < 512) dst[(long)gr * 512 + gc] = acc[i][j][reg];
        }
  }
}

// Reduce token split-K partials: rope(tq), rope(tk), transpose(tv) -> bf16.
// tq = slabs 0..3, tk = 4..7, tv = 8..11. Pair-vectorized, grid 1576 x 256.
// tqb layout contract: tkb = tqb + XSZ, tvt = tqb + 2*XSZ.
__global__ void token_finish_kernel(const float* __restrict__ tp,
                                    const float* __restrict__ cosT,
                                    const float* __restrict__ sinT,
                                    u16* __restrict__ tqb) {
  int p2 = blockIdx.x * 256 + threadIdx.x;   // pair index, < XSZ/2
  int r = p2 / 788, gp = p2 - r * 788;       // row, pair-in-row (NTD/2=788)
  int t = r & 63;
  float cv = cosT[(long)t * 788 + gp];
  float sv = sinT[(long)t * 788 + gp];
  const float2* tp2 = (const float2*)tp;
  const long H = XSZ >> 1;                   // float2 elems per slab
  long pr = (long)r * 788 + gp;              // float2 index of the pair
  // tq = sum of 4 seg partials
  float2 a0 = tp2[pr], a1 = tp2[H + pr], a2 = tp2[2 * H + pr], a3 = tp2[3 * H + pr];
  float ve = a0.x + a1.x + a2.x + a3.x, vo = a0.y + a1.y + a2.y + a3.y;
  u16x2 hq = { f2bf(ve * cv + vo * sv), f2bf(-ve * sv + vo * cv) };
  ((u16x2*)tqb)[pr] = hq;
  // tk
  float2 b0 = tp2[4 * H + pr], b1 = tp2[5 * H + pr], b2 = tp2[6 * H + pr], b3 = tp2[7 * H + pr];
  ve = b0.x + b1.x + b2.x + b3.x; vo = b0.y + b1.y + b2.y + b3.y;
  u16x2 hk = { f2bf(ve * cv + vo * sv), f2bf(-ve * sv + vo * cv) };
  ((u16x2*)(tqb + XSZ))[pr] = hk;
  // tv: two consecutive idx = 2*p2, 2*p2+1 in the (1576 x 512) partial layout
  long i0 = (long)p2 * 2;
  int g2 = (int)(i0 >> 9), r2 = (int)(i0 & 511);    // r2 even
  float2 c0 = tp2[8 * H + p2], c1 = tp2[9 * H + p2];
  float2 c2 = tp2[10 * H + p2], c3 = tp2[11 * H + p2];
  u16x2 hv = { f2bf(c0.x + c1.x + c2.x + c3.x), f2bf(c0.y + c1.y + c2.y + c3.y) };
  long vo2 = 2 * XSZ + ((long)(r2 >> 6) * NTD + g2) * 64 + (r2 & 63);
  *(u16x2*)(tqb + vo2) = hv;
}

// ---------------------------------------------------------------------------
// Generic MFMA GEMM for the remaining shapes. XCD-chunked work mapping.
// z = z1*nz2 + z2; A += z1*aS1 + z2*aS2 (aS1 enables K-segment split-K).
// EPI_TOKPV additionally accumulates per-batch sum(x^2) into sqout[z2].
enum { EPI_BF16 = 0, EPI_F32 = 1, EPI_TOKPV = 3, EPI_PATCH = 4 };

template <int EPI>
__global__ __launch_bounds__(256) void mfma_gemm(
    const u16* __restrict__ A, const u16* __restrict__ B, void* __restrict__ Cv,
    const float* __restrict__ resid, float* __restrict__ sqout,
    int M, int N, int K, int lda, int ldb, int ldc, float alpha, int nz2,
    long aS1, long aS2, long bS1, long bS2, long cS1, long cS2) {
  int wg = swz_flat();
  int bx = wg % gridDim.x; int tmp = wg / gridDim.x;
  int by = tmp % gridDim.y; int z = tmp / gridDim.y;
  int z1 = z / nz2, z2 = z - z1 * nz2;
  A += z1 * aS1 + z2 * aS2;
  B += z1 * bS1 + z2 * bS2;
  __shared__ __align__(16) u16 As[3 * 4096];
  __shared__ __align__(16) u16 Bs[3 * 4096];
  const int tid = threadIdx.x;
  const int lane = tid & 63, wave = tid >> 6;
  const int wm = wave >> 1, wn = wave & 1;
  const int l15 = lane & 15, quad = lane >> 4;
  const int row0 = by * 128, col0 = bx * 128;
  f32x4 acc[4][4] = {};
  gemm_core(A, lda, M, row0, B, ldb, N, col0, K, As, Bs, acc, tid, wm, wn, l15, quad);

  float* Cf = (float*)Cv;
  u16* Ch = (u16*)Cv;
  const long cbase = z1 * cS1 + z2 * cS2;
  float ssq = 0.f;
#pragma unroll
  for (int i = 0; i < 4; i++)
#pragma unroll
    for (int j = 0; j < 4; j++)
#pragma unroll
      for (int reg = 0; reg < 4; reg++) {
        int gr = row0 + wm * 64 + i * 16 + quad * 4 + reg;
        int gc = col0 + wn * 64 + j * 16 + l15;
        if (gr >= M || gc >= N) continue;
        float vv = acc[i][j][reg] * alpha;
        if (EPI == EPI_BF16) {
          Ch[cbase + (long)gr * ldc + gc] = f2bf(vv);
        } else if (EPI == EPI_F32) {
          Cf[cbase + (long)gr * ldc + gc] = vv;
        } else if (EPI == EPI_TOKPV) {    // x[b][mm][c*8+f] = acc + xn
          int f = gc / 197, mm = gc - f * 197;
          long o = ((long)z2 * 197 + mm) * 512 + gr * 8 + f;
          float xv = vv + resid[o];
          Cf[o] = xv;
          ssq += xv * xv;
        } else {                          // PATCH: x[b][1+p][gc] = acc + bias
          int b = gr / 196, p = gr - b * 196;
          Cf[((long)b * 197 + 1 + p) * 512 + gc] = vv + resid[gc];
        }
      }
  if (EPI == EPI_TOKPV) {
    __syncthreads();                       // LDS no longer needed by gemm
    float* red = (float*)As;
    red[tid] = ssq; __syncthreads();
    for (int o2 = 128; o2; o2 >>= 1) {
      if (tid < o2) red[tid] += red[tid + o2];
      __syncthreads();
    }
    if (tid == 0) atomicAdd(&sqout[z2], red[0]);
  }
}

// ---------------------------------------------------------------------------
// Token scores, split-K: grid (split=8, b=8). tsp[(s*8+b)][64][64] partials.
// 3-slot ring + counted vmcnt (same discipline as gemm_core).
__global__ __launch_bounds__(256) void token_scores_kernel(const u16* __restrict__ tq,
                                                           const u16* __restrict__ tk,
                                                           float* __restrict__ tsp) {
  int s = blockIdx.x, b = blockIdx.y;
  const u16* A = tq + (long)b * 64 * NTD;
  const u16* B = tk + (long)b * 64 * NTD;
  __shared__ __align__(16) u16 As[3 * 2048];
  __shared__ __align__(16) u16 Bs[3 * 2048];
  int tid = threadIdx.x, lane = tid & 63, w = tid >> 6;
  int l15 = lane & 15, quad = lane >> 4;
  f32x4 acc[4] = {};
  const int r = tid >> 2;
  const int cs = (((tid & 3) ^ ((r >> 1) & 3)) << 3);
  const u16* pa = A + (long)r * NTD + cs;
  const u16* pbp = B + (long)r * NTD + cs;
  const int lb = (tid & ~63) * 8;

  auto stage = [&](int ch, int bi) {
    async_cp16(pa + ch * 32, &As[bi + lb]);
    async_cp16(pbp + ch * 32, &Bs[bi + lb]);
  };
  auto compute = [&](int bi) {
    int row = w * 16 + l15;
    bf16x8 av = *(const bf16x8*)&As[bi + row * 32 + ((quad ^ ((row >> 1) & 3)) << 3)];
#pragma unroll
    for (int j = 0; j < 4; j++) {
      int rb = j * 16 + l15;
      bf16x8 bv = *(const bf16x8*)&Bs[bi + rb * 32 + ((quad ^ ((rb >> 1) & 3)) << 3)];
      acc[j] = __builtin_amdgcn_mfma_f32_16x16x32_bf16(av, bv, acc[j], 0, 0, 0);
    }
  };

  int ch0 = s * 6, nch = (s == 7) ? 7 : 6;
  stage(ch0, 0);
  stage(ch0 + 1, 2048);
  for (int c = 0; c < nch; c++) {
    if (c + 1 < nch) {
      asm volatile("s_waitcnt vmcnt(2)" ::: "memory");
    } else {
      asm volatile("s_waitcnt vmcnt(0)" ::: "memory");
    }
    __builtin_amdgcn_s_barrier();
    if (c + 2 < nch) stage(ch0 + c + 2, ((c + 2) % 3) * 2048);
    compute((c % 3) * 2048);
  }
  if (s == 7) {  // 8-element K tail at k=1568
    const int tb = (nch % 3) * 2048;
    __syncthreads();
    for (int idx = tid; idx < 2048; idx += 256) {
      int rr = idx >> 5, cc = idx & 31;
      int g = ((((cc >> 3) ^ ((rr >> 1) & 3)) << 3)) | (cc & 7);
      As[tb + idx] = (g < 8) ? A[(long)rr * NTD + 1568 + g] : (u16)0;
      Bs[tb + idx] = (g < 8) ? B[(long)rr * NTD + 1568 + g] : (u16)0;
    }
    __syncthreads();
    compute(tb);
  }
  const float sc = rsqrtf(1576.f);
  float* dst = tsp + ((long)(s * 8 + b)) * 4096;
#pragma unroll
  for (int j = 0; j < 4; j++)
#pragma unroll
    for (int reg = 0; reg < 4; reg++) {
      int row = w * 16 + quad * 4 + reg, col = j * 16 + l15;
      dst[row * 64 + col] = acc[j][reg] * sc;
    }
}

// ---------------------------------------------------------------------------
// Spatial softmax: sums 2 split-K partials s[0],s[1] (each 64x197x197 fp32)
// -> pb bf16 (64,197,208). 4 rows/block; row cached in registers.
__global__ void softmax_spatial_kernel(const float* __restrict__ s, u16* __restrict__ pb) {
  int row = blockIdx.x * 4 + (threadIdx.x >> 6);
  int lane = threadIdx.x & 63;
  const float* p0 = s + (long)row * 197;
  const float* p1 = p0 + 2483776;
  int hb = row / 197, mm = row - hb * 197;
  u16* q = pb + (long)hb * 197 * MP + (long)mm * MP;
  float vv[4];
  float mx = -INFINITY;
  int cnt = 0;
  for (int j = lane; j < 197; j += 64) {
    vv[cnt] = p0[j] + p1[j];
    mx = fmaxf(mx, vv[cnt]);
    cnt++;
  }
#pragma unroll
  for (int off = 32; off; off >>= 1) mx = fmaxf(mx, __shfl_xor(mx, off));
  float sum = 0.f;
  for (int i = 0; i < cnt; i++) { vv[i] = expf(vv[i] - mx); sum += vv[i]; }
#pragma unroll
  for (int off = 32; off; off >>= 1) sum += __shfl_xor(sum, off);
  float inv = 1.f / sum;
  cnt = 0;
  for (int j = lane; j < 197; j += 64) { q[j] = f2bf(vv[cnt] * inv); cnt++; }
}

// Token softmax: sums 8 split-K partials, softmaxes, writes Pb bf16.
__global__ void softmax_token_kernel(const float* __restrict__ tsp, u16* __restrict__ Pb) {
  int row = blockIdx.x * 4 + (threadIdx.x >> 6);  // 0..511 = b*64+r
  int lane = threadIdx.x & 63;
  int b = row >> 6, r = row & 63;
  float v = 0.f;
#pragma unroll
  for (int p = 0; p < 8; p++) v += tsp[((long)(p * 8 + b)) * 4096 + r * 64 + lane];
  float mx = v;
#pragma unroll
  for (int off = 32; off; off >>= 1) mx = fmaxf(mx, __shfl_xor(mx, off));
  float e = expf(v - mx);
  float sum = e;
#pragma unroll
  for (int off = 32; off; off >>= 1) sum += __shfl_xor(sum, off);
  Pb[(long)row * 64 + lane] = f2bf(e / sum);
}

// ---------------------------------------------------------------------------
// Attn output reduce + residual, vectorized x4; fused per-batch sum(x^2).
// grid 788 x 256. A block (1024 elems) may straddle ONE batch boundary ->
// segmented 2-slot reduce.
__global__ void attn_reduce_kernel(const float* __restrict__ part, const float* __restrict__ bias,
                                   const float* __restrict__ resid, float* __restrict__ x,
                                   float* __restrict__ sqslot) {
  int idx4 = blockIdx.x * 256 + threadIdx.x;
  long base = (long)idx4 * 4;
  int col = (int)(base % ND);
  float4 sv = *(const float4*)(bias + col);
  float4 rv = ((const float4*)resid)[idx4];
  sv.x += rv.x; sv.y += rv.y; sv.z += rv.z; sv.w += rv.w;
#pragma unroll
  for (int h = 0; h < 8; h++) {
    float4 pv = ((const float4*)part)[(h * (XSZ >> 2)) + idx4];
    sv.x += pv.x; sv.y += pv.y; sv.z += pv.z; sv.w += pv.w;
  }
  ((float4*)x)[idx4] = sv;
  float ssq = sv.x * sv.x + sv.y * sv.y + sv.z * sv.z + sv.w * sv.w;
  int b = (int)(base / BMD);
  int bfirst = (int)(((long)blockIdx.x * 1024) / BMD);
  float s0 = (b == bfirst) ? ssq : 0.f;
  float s1 = ssq - s0;
  __shared__ float red0[256], red1[256];
  red0[threadIdx.x] = s0; red1[threadIdx.x] = s1; __syncthreads();
  for (int o = 128; o; o >>= 1) {
    if (threadIdx.x < o) {
      red0[threadIdx.x] += red0[threadIdx.x + o];
      red1[threadIdx.x] += red1[threadIdx.x + o];
    }
    __syncthreads();
  }
  if (threadIdx.x == 0) {
    atomicAdd(&sqslot[bfirst], red0[0]);
    if (red1[0] != 0.f) atomicAdd(&sqslot[bfirst + 1], red1[0]);
  }
}

// ---------------------------------------------------------------------------
// Merged Wqkv (48 slabs, z = l*24 + w*8 + h) + attn_W (16 slabs: l*8 + i).
// grid (16,16,64).
__global__ void transpose_wa_kernel(const float* __restrict__ Wq, const float* __restrict__ Wk,
                                    const float* __restrict__ Wv, const float* __restrict__ attn_W,
                                    u16* __restrict__ Wt16, u16* __restrict__ Wat16) {
  int z = blockIdx.z;
  const float* src;
  u16* dst;
  long dld;
  if (z < 48) {
    int l = z / 24, rem = z - l * 24, w = rem >> 3, h = rem & 7;
    src = (w == 0 ? Wq : w == 1 ? Wk : Wv) + (long)(l * 8 + h) * 262144;
    dst = Wt16 + (long)z * 262144;
    dld = 512;
  } else {
    int za = z - 48, l = za >> 3, i = za & 7;   // 8 row-blocks per layer
    src = attn_W + (long)l * 4096 * 512 + (long)i * 512 * 512;
    dst = Wat16 + (long)l * 512 * 4096 + (long)i * 512;
    dld = 4096;
  }
  __shared__ float t[32][33];
  int c0 = blockIdx.x * 32, r0 = blockIdx.y * 32;
  int tx = threadIdx.x, ty = threadIdx.y;
#pragma unroll
  for (int i = 0; i < 4; i++)
    t[ty + i * 8][tx] = src[(long)(r0 + ty + i * 8) * 512 + c0 + tx];
  __syncthreads();
#pragma unroll
  for (int i = 0; i < 4; i++)
    dst[(long)(c0 + ty + i * 8) * dld + r0 + tx] = f2bf(t[tx][ty + i * 8]);
}

// Generic transpose fp32 (RxC) -> bf16 (CxR) (used for patch_W).
__global__ void transpose_bf16_kernel(const float* __restrict__ src, u16* __restrict__ dst,
                                      int R, int C) {
  __shared__ float t[32][33];
  int c0 = blockIdx.x * 32, r0 = blockIdx.y * 32;
  int tx = threadIdx.x, ty = threadIdx.y;
#pragma unroll
  for (int i = 0; i < 4; i++) {
    int r = r0 + ty + i * 8;
    if (r < R && c0 + tx < C) t[ty + i * 8][tx] = src[(long)r * C + c0 + tx];
  }
  __syncthreads();
#pragma unroll
  for (int i = 0; i < 4; i++) {
    int c = c0 + ty + i * 8;
    if (c < C && r0 + tx < R) dst[(long)c * R + r0 + tx] = f2bf(t[tx][ty + i * 8]);
  }
}

// Merged tWq/tWk/tWv transpose: grid (50,50,6), z = w*2 + l.
__global__ void t_transpose3_kernel(const float* __restrict__ Wq, const float* __restrict__ Wk,
                                    const float* __restrict__ Wv, u16* __restrict__ dst0) {
  int z = blockIdx.z;
  int w = z >> 1, l = z & 1;
  const float* src = (w == 0 ? Wq : w == 1 ? Wk : Wv) + (long)l * NTD * NTD;
  u16* d = dst0 + (long)z * NTD * NTD;
  __shared__ float t[32][33];
  int c0 = blockIdx.x * 32, r0 = blockIdx.y * 32;
  int tx = threadIdx.x, ty = threadIdx.y;
#pragma unroll
  for (int i = 0; i < 4; i++) {
    int r = r0 + ty + i * 8;
    if (r < NTD && c0 + tx < NTD) t[ty + i * 8][tx] = src[(long)r * NTD + c0 + tx];
  }
  __syncthreads();
#pragma unroll
  for (int i = 0; i < 4; i++) {
    int c = c0 + ty + i * 8;
    if (c < NTD && r0 + tx < NTD) d[(long)c * NTD + r0 + tx] = f2bf(t[tx][ty + i * 8]);
  }
}

// ---------------------------------------------------------------------------
// Fused cls LayerNorm + head GEMM. grid (4,8), 256 thr (LN redone per block).
__global__ void ln_head_kernel(const float* __restrict__ x, const float* __restrict__ g,
                               const float* __restrict__ bb, const float* __restrict__ W,
                               const float* __restrict__ hb, float* __restrict__ out) {
  int b = blockIdx.y, t = threadIdx.x;
  __shared__ float xs[512];
  __shared__ float red[256];
  float v0 = x[(long)b * NM * ND + t];
  float v1 = x[(long)b * NM * ND + 256 + t];
  red[t] = v0 + v1; __syncthreads();
  for (int o = 128; o; o >>= 1) { if (t < o) red[t] += red[t + o]; __syncthreads(); }
  float mu = red[0] / 512.f; __syncthreads();
  float d0 = v0 - mu, d1 = v1 - mu;
  red[t] = d0 * d0 + d1 * d1; __syncthreads();
  for (int o = 128; o; o >>= 1) { if (t < o) red[t] += red[t + o]; __syncthreads(); }
  float inv = rsqrtf(red[0] / 512.f + 1e-5f); __syncthreads();
  xs[t] = d0 * inv * g[t] + bb[t];
  xs[256 + t] = d1 * inv * g[256 + t] + bb[256 + t];
  __syncthreads();
  int n = blockIdx.x * 250 + t;
  if (t < 250 && n < 1000) {
    float acc = hb[n];
    for (int dd = 0; dd < 512; dd++) acc += xs[dd] * W[(long)dd * 1000 + n];
    out[(long)b * 1000 + n] = acc;
  }
}

}  // namespace

extern "C" void kernel_launch(void* const* d_in, const int* in_sizes, int n_in,
                              void* d_out, int out_size, void* d_ws, size_t ws_size,
                              hipStream_t stream) {
  const float* img     = (const float*)d_in[0];
  const float* patch_W = (const float*)d_in[1];
  const float* patch_b = (const float*)d_in[2];
  const float* cls_tok = (const float*)d_in[3];
  const float* rms_s   = (const float*)d_in[4];
  const float* Wq      = (const float*)d_in[5];
  const float* Wk      = (const float*)d_in[6];
  const float* Wv      = (const float*)d_in[7];
  const float* attn_W  = (const float*)d_in[8];
  const float* attn_b  = (const float*)d_in[9];
  const float* tWq     = (const float*)d_in[10];
  const float* tWk     = (const float*)d_in[11];
  const float* tWv     = (const float*)d_in[12];
  const float* ln_g    = (const float*)d_in[13];
  const float* ln_b    = (const float*)d_in[14];
  const float* head_W  = (const float*)d_in[15];
  const float* head_b  = (const float*)d_in[16];
  float* out = (float*)d_out;

  // ---- workspace layout (floats) ----
  float* base = (float*)d_ws;
  long off = 0;
  auto alloc = [&](long n) { float* r = base + off; off += (n + 15) & ~15L; return r; };
  float* cosP = alloc(TABSZ);       // interleaved (cos,sin) float2 table spans
  float* sinP = alloc(TABSZ);       //   cosP..sinP (2*TABSZ floats contiguous)
  float* cosT = alloc(TABSZ);
  float* sinT = alloc(TABSZ);
  float* x    = alloc(XSZ);
  float* xn   = alloc(XSZ);
  float* Wt_f   = alloc(6291456);   // 48 slabs 512x512 bf16, z = l*24+w*8+h
  float* Wat_f  = alloc(2097152);   // (l) 512x4096 bf16
  float* tWt_f  = alloc(7451328);   // (w,l) 1576x1576 bf16
  float* xnb_f  = alloc(XSZ / 2);
  float* pimg_f = alloc(602112);    // 1568x768 bf16
  float* pWt_f  = alloc(196608);    // 512x768 bf16
  float* U      = alloc(16885824);  // union region
  float* ff     = alloc(64);        // 8x8 partials for the first RMS
  float* ffs    = alloc(64);        // fused sq-sum slots

  u16* Wt16  = (u16*)Wt_f;
  u16* Wat16 = (u16*)Wat_f;
  u16* tWt16 = (u16*)tWt_f;
  u16* xnb   = (u16*)xnb_f;
  u16* pimg  = (u16*)pimg_f;
  u16* pWt   = (u16*)pWt_f;
  // phase A overlay (contract: kk = q + QSZ, vt = q + 2*QSZ)
  u16* q   = (u16*)U;                 // 6455296 (h, b*m, e)
  u16* kk  = q + QSZ;                 // 6455296
  u16* vt  = kk + QSZ;                // 6815744 (h,b,e,m_pad)
  float* s = (float*)(vt + 6815744);  // 2x 2483776 f split-K score partials
  u16* pb  = (u16*)(s + 2 * 2483776); // 2622464 (hb,197,208)
  u16* o   = (u16*)s;                 // 6455296 (aliases dead s after softmax)
  float* part = (float*)q;            // 8*XSZ fp32 (aliases dead q,kk)
  // phase B overlay (contract: tkb = tqb + XSZ, tvt = tqb + 2*XSZ)
  u16* yb     = (u16*)U;              // 806912 (b*64+c, 1576)
  float* tprt = (float*)(yb + XSZ);   // 12*XSZ fp32 split partials
  u16* tqb    = (u16*)(tprt + 12 * XSZ);
  u16* tvt    = tqb + 2 * XSZ;        // (b, 1576, 64)
  float* tsp  = (float*)(tvt + XSZ);  // 8 x 8 x 64 x 64
  u16* Pb     = (u16*)(tsp + 262144); // 8*64*64

  const float rs512 = 1.f / sqrtf(512.f);
  const dim3 tt(32, 8);

  // ---- setup ----
  init_kernel<<<5115, 256, 0, stream>>>(img, cls_tok, cosP, sinP, cosT, sinT, pimg, x, ffs);
  transpose_bf16_kernel<<<dim3(16, 24), tt, 0, stream>>>(patch_W, pWt, 768, 512);
  transpose_wa_kernel<<<dim3(16, 16, 64), tt, 0, stream>>>(Wq, Wk, Wv, attn_W, Wt16, Wat16);
  t_transpose3_kernel<<<dim3(50, 50, 6), tt, 0, stream>>>(tWq, tWk, tWv, tWt16);
  mfma_gemm<EPI_PATCH><<<dim3(4, 13, 1), 256, 0, stream>>>(
      pimg, pWt, x, patch_b, nullptr, 1568, 512, 768, 768, 768, 512, 1.f, 1,
      0, 0, 0, 0, 0, 0);

  for (int l = 0; l < 2; l++) {
    const float* scale = rms_s + (long)l * NM * ND;
    float* slotA = ffs + l * 16;       // attn-phase sq-sums for this layer
    float* slotT = ffs + l * 16 + 8;   // token-phase sq-sums for this layer
    // ---- spatial attention ----
    if (l == 0) {
      rms_part_kernel<<<dim3(8, 8), 256, 0, stream>>>(x, ff);
      rms_apply_kernel<<<788, 256, 0, stream>>>(x, scale, ff, 8, xn, xnb);
    } else {
      // sq-sums were accumulated by the previous layer's token-PV epilogue
      rms_apply_kernel<<<788, 256, 0, stream>>>(x, scale, ffs + 8, 1, xn, xnb);
    }

    // qkv with fused RoPE on q,k
    qkv_kernel<<<dim3(4, 13, 24), 256, 0, stream>>>(xnb, Wt16 + (long)l * 24 * 262144, q, cosP);

    // scores, 2-way split-K (fp32 partials, scaled)
    mfma_gemm<EPI_F32><<<dim3(2, 2, 128), 256, 0, stream>>>(
        q, kk, s, nullptr, nullptr, 197, 197, 256, 512, 512, 197, rs512, 64,
        256, 197L * 512, 256, 197L * 512, 2483776, 197L * 197);
    softmax_spatial_kernel<<<3152, 256, 0, stream>>>(s, pb);
    // o = P @ v   (o aliases the now-dead s region)
    mfma_gemm<EPI_BF16><<<dim3(4, 2, 64), 256, 0, stream>>>(
        pb, vt, o, nullptr, nullptr, 197, 512, 197, MP, MP, 512, 1.f, 64,
        0, 197L * MP, 0, 512L * MP, 0, 197L * 512);
    // attn-proj head partials
    mfma_gemm<EPI_F32><<<dim3(4, 13, 8), 256, 0, stream>>>(
        o, Wat16 + (long)l * 2097152, part, nullptr, nullptr, 1576, 512, 512, 512, 4096, 512,
        1.f, 8, 0, XSZ, 0, 512, 0, XSZ);
    // reduce + residual + fused sum(x^2) into slotA
    attn_reduce_kernel<<<788, 256, 0, stream>>>(part, attn_b + (long)l * ND, xn, x, slotA);

    // ---- token mixing ----
    rms_apply_tok_kernel<<<788, 256, 0, stream>>>(x, scale, slotA, 1, xn, yb);

    // 4-way K split (624 blocks)
    tok_qkv_kernel<<<dim3(4, 13, 12), 256, 0, stream>>>(yb, tWt16, l, tprt);
    token_finish_kernel<<<1576, 256, 0, stream>>>(tprt, cosT, sinT, tqb);

    token_scores_kernel<<<dim3(8, 8), 256, 0, stream>>>(tqb, tqb + XSZ, tsp);
    softmax_token_kernel<<<128, 256, 0, stream>>>(tsp, Pb);
    // token PV: scatter + residual into fp32 x; fused sum(x^2) into slotT
    mfma_gemm<EPI_TOKPV><<<dim3(13, 1, 8), 256, 0, stream>>>(
        Pb, tvt, x, xn, slotT, 64, 1576, 64, 64, 64, 0, 1.f, 8,
        0, 4096, 0, 1576L * 64, 0, 0);
  }

  ln_head_kernel<<<dim3(4, 8), 256, 0, stream>>>(x, ln_g, ln_b, head_W, head_b, out);
}

// Round 7
// 656.714 us; speedup vs baseline: 1.1549x; 1.0205x over previous
//
#include <hip/hip_runtime.h>
#include <math.h>

// B=8, m=197, dim=512, heads=8, depth=2, F=8, tdim=1576, cdim=64, ncls=1000.
namespace {

typedef unsigned short u16;
typedef __attribute__((ext_vector_type(8))) short bf16x8;
typedef __attribute__((ext_vector_type(4))) float f32x4;
typedef __attribute__((ext_vector_type(4))) unsigned short u16x4;
typedef __attribute__((ext_vector_type(2))) unsigned short u16x2;

constexpr int NB = 8, NM = 197, ND = 512, NH = 8, NTD = 1576, NC = 64;
constexpr long XSZ = (long)NB * NM * ND;        // 806912
constexpr long QSZ = (long)NH * XSZ;            // 6455296 (h, b*m, e)
constexpr long TABSZ = 50432;                   // 197*256 == 64*788
constexpr int MP = 208;                         // padded 197 (16B-aligned bf16 rows)
constexpr int BMD = NM * ND;                    // 100864 per-batch elems

__device__ __forceinline__ u16 f2bf(float f) {
  union { float f; unsigned u; } v; v.f = f;
  unsigned r = v.u + 0x7FFF + ((v.u >> 16) & 1);
  return (u16)(r >> 16);
}
__device__ __forceinline__ void async_cp16(const void* g, void* l) {
  __builtin_amdgcn_global_load_lds((const __attribute__((address_space(1))) unsigned*)g,
                                   (__attribute__((address_space(3))) unsigned*)l, 16, 0, 0);
}

// Bijective XCD-chunk swizzle (m204).
__device__ __forceinline__ int xcd_swz(int orig, int nwg) {
  int q = nwg >> 3, r = nwg & 7, x = orig & 7, i = orig >> 3;
  return (x < r ? x * (q + 1) : r * (q + 1) + (x - r) * q) + i;
}
__device__ __forceinline__ int swz_flat() {
  int nwg = gridDim.x * gridDim.y * gridDim.z;
  int orig = blockIdx.x + gridDim.x * (blockIdx.y + gridDim.y * blockIdx.z);
  return xcd_swz(orig, nwg);
}

// ---------------------------------------------------------------------------
// Shared MFMA GEMM core: acc += A(M x KL) * B^T(N x KL), 128x128 tile, BK=32.
// Depth-2 prefetch: 3-slot LDS ring, raw s_barrier + counted vmcnt(4).
__device__ __forceinline__ void gemm_core(
    const u16* __restrict__ A, int lda, int M, int row0,
    const u16* __restrict__ B, int ldb, int N, int col0,
    int KL, u16* As, u16* Bs, f32x4 (&acc)[4][4],
    int tid, int wm, int wn, int l15, int quad) {
  const int nfull = KL >> 5, tail = KL & 31;
  const int r = tid >> 2;
  const int cs = (((tid & 3) ^ ((r >> 1) & 3)) << 3);
  int gr0 = row0 + r;      if (gr0 >= M) gr0 = M - 1;
  int gr1 = row0 + r + 64; if (gr1 >= M) gr1 = M - 1;
  int gc0 = col0 + r;      if (gc0 >= N) gc0 = N - 1;
  int gc1 = col0 + r + 64; if (gc1 >= N) gc1 = N - 1;
  const u16* pa0 = A + (long)gr0 * lda + cs;
  const u16* pa1 = A + (long)gr1 * lda + cs;
  const u16* pb0 = B + (long)gc0 * ldb + cs;
  const u16* pb1 = B + (long)gc1 * ldb + cs;
  const int lb0 = (tid & ~63) * 8;
  const int lb1 = lb0 + 2048;

  auto stage = [&](int k0, int bi) {
    async_cp16(pa0 + k0, &As[bi + lb0]);
    async_cp16(pa1 + k0, &As[bi + lb1]);
    async_cp16(pb0 + k0, &Bs[bi + lb0]);
    async_cp16(pb1 + k0, &Bs[bi + lb1]);
  };
  auto compute = [&](int bi) {
    bf16x8 af[4], bg[4];
#pragma unroll
    for (int i = 0; i < 4; i++) {
      int row = wm * 64 + i * 16 + l15;
      af[i] = *(const bf16x8*)&As[bi + row * 32 + ((quad ^ ((row >> 1) & 3)) << 3)];
    }
#pragma unroll
    for (int j = 0; j < 4; j++) {
      int row = wn * 64 + j * 16 + l15;
      bg[j] = *(const bf16x8*)&Bs[bi + row * 32 + ((quad ^ ((row >> 1) & 3)) << 3)];
    }
#pragma unroll
    for (int i = 0; i < 4; i++)
#pragma unroll
      for (int j = 0; j < 4; j++)
        acc[i][j] = __builtin_amdgcn_mfma_f32_16x16x32_bf16(af[i], bg[j], acc[i][j], 0, 0, 0);
  };

  if (nfull > 0) {
    stage(0, 0);
    if (nfull > 1) stage(32, 4096);
    for (int ch = 0; ch < nfull; ch++) {
      if (ch + 1 < nfull) {
        asm volatile("s_waitcnt vmcnt(4)" ::: "memory");
      } else {
        asm volatile("s_waitcnt vmcnt(0)" ::: "memory");
      }
      __builtin_amdgcn_s_barrier();
      if (ch + 2 < nfull) stage((ch + 2) << 5, ((ch + 2) % 3) * 4096);
      compute((ch % 3) * 4096);
    }
  }
  if (tail) {
    const int tb = (nfull % 3) * 4096;
    const int k0f = nfull << 5;
    if (nfull > 0) __syncthreads();
    for (int idx2 = tid; idx2 < 4096; idx2 += 256) {
      int rr = idx2 >> 5, cc = idx2 & 31;
      int g = ((((cc >> 3) ^ ((rr >> 1) & 3)) << 3)) | (cc & 7);
      int grr = row0 + rr; if (grr >= M) grr = M - 1;
      int gcc = col0 + rr; if (gcc >= N) gcc = N - 1;
      As[tb + idx2] = (g < tail) ? A[(long)grr * lda + k0f + g] : (u16)0;
      Bs[tb + idx2] = (g < tail) ? B[(long)gcc * ldb + k0f + g] : (u16)0;
    }
    __syncthreads();
    compute(tb);
  }
}

// ---------------------------------------------------------------------------
// init: RoPE tables + patch gather + cls fill + zero sq-sum slots. One launch.
// grid 5115 x 256. Spatial table is INTERLEAVED (cos,sin) float2 in cosP.
__global__ void init_kernel(const float* __restrict__ img, const float* __restrict__ cls,
                            float* cosP, float* sinP, float* cosT, float* sinT,
                            u16* __restrict__ pimg, float* __restrict__ x,
                            float* __restrict__ ffs) {
  long idx = (long)blockIdx.x * 256 + threadIdx.x;
  if (idx < 197 * 256) {
    int p = (int)(idx / 256), i = (int)(idx % 256);
    float theta = powf(10000.f, -2.f * ((float)i - 1.f) / 512.f);
    float a = (float)p * theta;
    cosP[2 * idx] = cosf(a); cosP[2 * idx + 1] = sinf(a);
    return;
  }
  long j = idx - 197 * 256;
  if (j < 64 * 788) {
    int p = (int)(j / 788), i = (int)(j % 788);
    float theta = powf(10000.f, -2.f * ((float)i - 1.f) / 1576.f);
    float a = (float)p * theta;
    cosT[j] = cosf(a); sinT[j] = sinf(a);
    return;
  }
  long k2 = j - 64 * 788;
  if (k2 < 1568L * 768) {
    int r = (int)(k2 / 768), k = (int)(k2 % 768);
    int b = r / 196, p = r - b * 196;
    int pi = p / 14, pj = p - pi * 14;
    int cc = k % 3, pq = k / 3, pp = pq >> 4, qq = pq & 15;
    pimg[k2] = f2bf(img[((long)(b * 3 + cc) * 224 + pi * 16 + pp) * 224 + pj * 16 + qq]);
    return;
  }
  long c2 = k2 - 1568L * 768;
  if (c2 < 8 * 512) {
    int b = (int)(c2 >> 9), e = (int)(c2 & 511);
    x[((long)b * NM) * ND + e] = cls[e];
    return;
  }
  long c3 = c2 - 8 * 512;
  if (c3 < 64) ffs[c3] = 0.f;   // zero all fused sq-sum slots (incl. patch @32)
}

// np=8: sum 8 partials per batch; np=1: single pre-accumulated float.
__device__ __forceinline__ float rms_inv(const float* part, int b, int np) {
  float ssum = 0.f;
  if (np == 8) {
#pragma unroll
    for (int i = 0; i < 8; i++) ssum += part[b * 8 + i];
  } else {
    ssum = part[b];
  }
  return sqrtf((float)(NM * ND) / ssum);
}

// Vectorized x4: grid 788 x 256 (XSZ/4 = 201728 float4 threads).
__global__ void rms_apply_kernel(const float* __restrict__ x, const float* __restrict__ scale,
                                 const float* __restrict__ part, int np, float* __restrict__ xn,
                                 u16* __restrict__ xnb) {
  int idx4 = blockIdx.x * 256 + threadIdx.x;
  int b = idx4 / (BMD / 4);
  int md4 = idx4 - b * (BMD / 4);
  float ri = rms_inv(part, b, np);
  float4 xv = ((const float4*)x)[idx4];
  float4 sv = ((const float4*)(scale))[md4];
  float4 v;
  v.x = xv.x * sv.x * ri; v.y = xv.y * sv.y * ri;
  v.z = xv.z * sv.z * ri; v.w = xv.w * sv.w * ri;
  ((float4*)xn)[idx4] = v;
  u16x4 h = { f2bf(v.x), f2bf(v.y), f2bf(v.z), f2bf(v.w) };
  ((u16x4*)xnb)[idx4] = h;
}

// Phase-B vectorized: writes xn and permuted yb[(b*64+c)*1576 + f*197+mm].
__global__ void rms_apply_tok_kernel(const float* __restrict__ x, const float* __restrict__ scale,
                                     const float* __restrict__ part, int np, float* __restrict__ xn,
                                     u16* __restrict__ yb) {
  int idx4 = blockIdx.x * 256 + threadIdx.x;
  int b = idx4 / (BMD / 4);
  int md4 = idx4 - b * (BMD / 4);
  float ri = rms_inv(part, b, np);
  float4 xv = ((const float4*)x)[idx4];
  float4 sv = ((const float4*)(scale))[md4];
  float4 v;
  v.x = xv.x * sv.x * ri; v.y = xv.y * sv.y * ri;
  v.z = xv.z * sv.z * ri; v.w = xv.w * sv.w * ri;
  ((float4*)xn)[idx4] = v;
  int md = md4 * 4;
  int mm = md / ND, d0 = md - mm * ND;     // d0 % 4 == 0
  int c = d0 >> 3, f0 = d0 & 7;            // f0 in {0,4}; f = f0..f0+3
  u16* row = yb + ((long)b * 64 + c) * NTD + mm;
  row[(f0 + 0) * 197] = f2bf(v.x);
  row[(f0 + 1) * 197] = f2bf(v.y);
  row[(f0 + 2) * 197] = f2bf(v.z);
  row[(f0 + 3) * 197] = f2bf(v.w);
}

// ---------------------------------------------------------------------------
// Patch split-K reduce: x[b][1+p][col] = sum of 3 partials + bias; fused
// per-batch sum(x^2) into sq[b] (plus cls-row ssq via the extra block 784).
// grid 785 x 256. 98 blocks per batch exactly (196*512/1024) -> no straddle.
__global__ void patch_reduce_kernel(const float* __restrict__ pp, const float* __restrict__ bias,
                                    const float* __restrict__ cls, float* __restrict__ x,
                                    float* __restrict__ sq) {
  __shared__ float red[256];
  int t = threadIdx.x;
  if (blockIdx.x == 784) {   // cls ssq, identical for all batches
    float v0 = cls[t], v1 = cls[256 + t];
    red[t] = v0 * v0 + v1 * v1; __syncthreads();
    for (int o = 128; o; o >>= 1) {
      if (t < o) red[t] += red[t + o];
      __syncthreads();
    }
    if (t < 8) atomicAdd(&sq[t], red[0]);
    return;
  }
  int idx4 = blockIdx.x * 256 + t;
  long e0 = (long)idx4 * 4;
  int prow = (int)(e0 >> 9), col = (int)(e0 & 511);
  int b = prow / 196, p = prow - b * 196;
  float4 s0 = ((const float4*)pp)[idx4];
  float4 s1 = ((const float4*)pp)[200704 + idx4];
  float4 s2 = ((const float4*)pp)[401408 + idx4];
  float4 bv = *(const float4*)(bias + col);
  float4 r;
  r.x = s0.x + s1.x + s2.x + bv.x;
  r.y = s0.y + s1.y + s2.y + bv.y;
  r.z = s0.z + s1.z + s2.z + bv.z;
  r.w = s0.w + s1.w + s2.w + bv.w;
  *(float4*)(x + ((long)(b * 197 + 1 + p) * 512 + col)) = r;
  red[t] = r.x * r.x + r.y * r.y + r.z * r.z + r.w * r.w;
  __syncthreads();
  for (int o = 128; o; o >>= 1) {
    if (t < o) red[t] += red[t + o];
    __syncthreads();
  }
  if (t == 0) atomicAdd(&sq[blockIdx.x / 98], red[0]);
}

// ---------------------------------------------------------------------------
// Spatial QKV, one launch. grid (4,13,24), z = w*8+h (after swizzle).
// w<2: q/k = xnb(1576x512) @ Wslab^T -> (h,b*m,e), RoPE fused in epilogue.
// w=2: v^T = Wv^T(512x512) @ xnb^T -> vt (h,b,e,m_pad).
__global__ __launch_bounds__(256) void qkv_kernel(const u16* __restrict__ xnb,
                                                  const u16* __restrict__ WtL,
                                                  u16* __restrict__ q,
                                                  const float* __restrict__ csP) {
  int wg = swz_flat();
  int bx = wg & 3, tmp = wg >> 2;
  int by = tmp % 13, bz = tmp / 13;
  int w = bz >> 3, h = bz & 7;
  __shared__ __align__(16) u16 As[3 * 4096];
  __shared__ __align__(16) u16 Bs[3 * 4096];
  const int tid = threadIdx.x;
  const int lane = tid & 63, wave = tid >> 6;
  const int wm = wave >> 1, wn = wave & 1;
  const int l15 = lane & 15, quad = lane >> 4;
  f32x4 acc[4][4] = {};

  if (w < 2) {
    int row0 = by * 128, col0 = bx * 128;
    const u16* B = WtL + ((long)(w * 8 + h)) * 262144;
    gemm_core(xnb, 512, 1576, row0, B, 512, 512, col0, 512, As, Bs, acc,
              tid, wm, wn, l15, quad);
    long base = (long)w * QSZ + (long)h * XSZ;
    const float2* cs2 = (const float2*)csP;
#pragma unroll
    for (int i = 0; i < 4; i++)
#pragma unroll
      for (int j = 0; j < 4; j++)
#pragma unroll
        for (int reg = 0; reg < 4; reg++) {
          int gr = row0 + wm * 64 + i * 16 + quad * 4 + reg;
          int gc = col0 + wn * 64 + j * 16 + l15;
          float v = acc[i][j][reg];
          float p = __shfl_xor(v, 1);            // all lanes execute (guard below)
          int t = gr % 197;                      // token index (bogus rows unused)
          float2 cs = cs2[t * 256 + (gc >> 1)];
          float outv = v * cs.x + ((gc & 1) ? -p * cs.y : p * cs.y);
          if (gr < 1576)
            q[base + (long)gr * 512 + gc] = f2bf(outv);
        }
  } else {
    int row0 = bx * 128, col0 = by * 128;
    const u16* A = WtL + ((long)(16 + h)) * 262144;
    gemm_core(A, 512, 512, row0, xnb, 512, 1576, col0, 512, As, Bs, acc,
              tid, wm, wn, l15, quad);
#pragma unroll
    for (int i = 0; i < 4; i++)
#pragma unroll
      for (int j = 0; j < 4; j++)
#pragma unroll
        for (int reg = 0; reg < 4; reg++) {
          int gr = row0 + wm * 64 + i * 16 + quad * 4 + reg;  // e
          int gc = col0 + wn * 64 + j * 16 + l15;             // b*197+mm
          if (gr < 512 && gc < 1576) {
            int b = gc / 197, mm = gc - b * 197;
            q[2 * QSZ + ((long)(h * 8 + b) * 512 + gr) * MP + mm] = f2bf(acc[i][j][reg]);
          }
        }
  }
}

// ---------------------------------------------------------------------------
// Token QKV, one launch. grid (4,13,12), XCD-chunked. 4-way K split:
// segs 416/416/416/328 (only last has a BK tail).
// z<8 : tq/tk partials (w=z>>2, seg=z&3): C = yb(512x1576) @ tW^T -> tprt[z].
// z>=8: tv^T partials (seg=z-8): C = tWv^T(1576x1576) @ yb^T -> tprt[8+seg].
__global__ __launch_bounds__(256) void tok_qkv_kernel(const u16* __restrict__ yb,
                                                      const u16* __restrict__ tWt, int l,
                                                      float* __restrict__ tprt) {
  int wg = swz_flat();
  int bx = wg & 3, tmp = wg >> 2;
  int by = tmp % 13, z = tmp / 13;
  __shared__ __align__(16) u16 As[3 * 4096];
  __shared__ __align__(16) u16 Bs[3 * 4096];
  const int tid = threadIdx.x;
  const int lane = tid & 63, wave = tid >> 6;
  const int wm = wave >> 1, wn = wave & 1;
  const int l15 = lane & 15, quad = lane >> 4;
  f32x4 acc[4][4] = {};

  if (z < 8) {
    int w = z >> 2, seg = z & 3;
    int kbeg = seg * 416, KL = (seg < 3) ? 416 : 328;
    int row0 = bx * 128, col0 = by * 128;
    const u16* A = yb + kbeg;
    const u16* B = tWt + ((long)(w * 2 + l)) * 2483776 + kbeg;
    gemm_core(A, 1576, 512, row0, B, 1576, 1576, col0, KL, As, Bs, acc,
              tid, wm, wn, l15, quad);
    float* dst = tprt + (long)z * XSZ;
#pragma unroll
    for (int i = 0; i < 4; i++)
#pragma unroll
      for (int j = 0; j < 4; j++)
#pragma unroll
        for (int reg = 0; reg < 4; reg++) {
          int gr = row0 + wm * 64 + i * 16 + quad * 4 + reg;
          int gc = col0 + wn * 64 + j * 16 + l15;
          if (gr < 512 && gc < 1576) dst[(long)gr * 1576 + gc] = acc[i][j][reg];
        }
  } else {
    int seg = z - 8;
    int kbeg = seg * 416, KL = (seg < 3) ? 416 : 328;
    int row0 = by * 128, col0 = bx * 128;
    const u16* A = tWt + ((long)(4 + l)) * 2483776 + kbeg;
    const u16* B = yb + kbeg;
    gemm_core(A, 1576, 1576, row0, B, 1576, 512, col0, KL, As, Bs, acc,
              tid, wm, wn, l15, quad);
    float* dst = tprt + (long)(8 + seg) * XSZ;
#pragma unroll
    for (int i = 0; i < 4; i++)
#pragma unroll
      for (int j = 0; j < 4; j++)
#pragma unroll
        for (int reg = 0; reg < 4; reg++) {
          int gr = row0 + wm * 64 + i * 16 + quad * 4 + reg;
          int gc = col0 + wn * 64 + j * 16 + l15;
          if (gr < 1576 && gc < 512) dst[(long)gr * 512 + gc] = acc[i][j][reg];
        }
  }
}

// Reduce token split-K partials: rope(tq), rope(tk), transpose(tv) -> bf16.
// tq = slabs 0..3, tk = 4..7, tv = 8..11. Pair-vectorized, grid 1576 x 256.
// tqb layout contract: tkb = tqb + XSZ, tvt = tqb + 2*XSZ.
__global__ void token_finish_kernel(const float* __restrict__ tp,
                                    const float* __restrict__ cosT,
                                    const float* __restrict__ sinT,
                                    u16* __restrict__ tqb) {
  int p2 = blockIdx.x * 256 + threadIdx.x;   // pair index, < XSZ/2
  int r = p2 / 788, gp = p2 - r * 788;       // row, pair-in-row (NTD/2=788)
  int t = r & 63;
  float cv = cosT[(long)t * 788 + gp];
  float sv = sinT[(long)t * 788 + gp];
  const float2* tp2 = (const float2*)tp;
  const long H = XSZ >> 1;                   // float2 elems per slab
  long pr = (long)r * 788 + gp;              // float2 index of the pair
  // tq = sum of 4 seg partials
  float2 a0 = tp2[pr], a1 = tp2[H + pr], a2 = tp2[2 * H + pr], a3 = tp2[3 * H + pr];
  float ve = a0.x + a1.x + a2.x + a3.x, vo = a0.y + a1.y + a2.y + a3.y;
  u16x2 hq = { f2bf(ve * cv + vo * sv), f2bf(-ve * sv + vo * cv) };
  ((u16x2*)tqb)[pr] = hq;
  // tk
  float2 b0 = tp2[4 * H + pr], b1 = tp2[5 * H + pr], b2 = tp2[6 * H + pr], b3 = tp2[7 * H + pr];
  ve = b0.x + b1.x + b2.x + b3.x; vo = b0.y + b1.y + b2.y + b3.y;
  u16x2 hk = { f2bf(ve * cv + vo * sv), f2bf(-ve * sv + vo * cv) };
  ((u16x2*)(tqb + XSZ))[pr] = hk;
  // tv: two consecutive idx = 2*p2, 2*p2+1 in the (1576 x 512) partial layout
  long i0 = (long)p2 * 2;
  int g2 = (int)(i0 >> 9), r2 = (int)(i0 & 511);    // r2 even
  float2 c0 = tp2[8 * H + p2], c1 = tp2[9 * H + p2];
  float2 c2 = tp2[10 * H + p2], c3 = tp2[11 * H + p2];
  u16x2 hv = { f2bf(c0.x + c1.x + c2.x + c3.x), f2bf(c0.y + c1.y + c2.y + c3.y) };
  long vo2 = 2 * XSZ + ((long)(r2 >> 6) * NTD + g2) * 64 + (r2 & 63);
  *(u16x2*)(tqb + vo2) = hv;
}

// ---------------------------------------------------------------------------
// Generic MFMA GEMM for the remaining shapes. XCD-chunked work mapping.
// z = z1*nz2 + z2; A += z1*aS1 + z2*aS2 (aS1 enables K-segment split-K).
// EPI_TOKPV additionally accumulates per-batch sum(x^2) into sqout[z2].
enum { EPI_BF16 = 0, EPI_F32 = 1, EPI_TOKPV = 3, EPI_PATCH = 4 };

template <int EPI>
__global__ __launch_bounds__(256) void mfma_gemm(
    const u16* __restrict__ A, const u16* __restrict__ B, void* __restrict__ Cv,
    const float* __restrict__ resid, float* __restrict__ sqout,
    int M, int N, int K, int lda, int ldb, int ldc, float alpha, int nz2,
    long aS1, long aS2, long bS1, long bS2, long cS1, long cS2) {
  int wg = swz_flat();
  int bx = wg % gridDim.x; int tmp = wg / gridDim.x;
  int by = tmp % gridDim.y; int z = tmp / gridDim.y;
  int z1 = z / nz2, z2 = z - z1 * nz2;
  A += z1 * aS1 + z2 * aS2;
  B += z1 * bS1 + z2 * bS2;
  __shared__ __align__(16) u16 As[3 * 4096];
  __shared__ __align__(16) u16 Bs[3 * 4096];
  const int tid = threadIdx.x;
  const int lane = tid & 63, wave = tid >> 6;
  const int wm = wave >> 1, wn = wave & 1;
  const int l15 = lane & 15, quad = lane >> 4;
  const int row0 = by * 128, col0 = bx * 128;
  f32x4 acc[4][4] = {};
  gemm_core(A, lda, M, row0, B, ldb, N, col0, K, As, Bs, acc, tid, wm, wn, l15, quad);

  float* Cf = (float*)Cv;
  u16* Ch = (u16*)Cv;
  const long cbase = z1 * cS1 + z2 * cS2;
  float ssq = 0.f;
#pragma unroll
  for (int i = 0; i < 4; i++)
#pragma unroll
    for (int j = 0; j < 4; j++)
#pragma unroll
      for (int reg = 0; reg < 4; reg++) {
        int gr = row0 + wm * 64 + i * 16 + quad * 4 + reg;
        int gc = col0 + wn * 64 + j * 16 + l15;
        if (gr >= M || gc >= N) continue;
        float vv = acc[i][j][reg] * alpha;
        if (EPI == EPI_BF16) {
          Ch[cbase + (long)gr * ldc + gc] = f2bf(vv);
        } else if (EPI == EPI_F32) {
          Cf[cbase + (long)gr * ldc + gc] = vv;
        } else if (EPI == EPI_TOKPV) {    // x[b][mm][c*8+f] = acc + xn
          int f = gc / 197, mm = gc - f * 197;
          long o = ((long)z2 * 197 + mm) * 512 + gr * 8 + f;
          float xv = vv + resid[o];
          Cf[o] = xv;
          ssq += xv * xv;
        } else {                          // PATCH: x[b][1+p][gc] = acc + bias
          int b = gr / 196, p = gr - b * 196;
          Cf[((long)b * 197 + 1 + p) * 512 + gc] = vv + resid[gc];
        }
      }
  if (EPI == EPI_TOKPV) {
    __syncthreads();                       // LDS no longer needed by gemm
    float* red = (float*)As;
    red[tid] = ssq; __syncthreads();
    for (int o2 = 128; o2; o2 >>= 1) {
      if (tid < o2) red[tid] += red[tid + o2];
      __syncthreads();
    }
    if (tid == 0) atomicAdd(&sqout[z2], red[0]);
  }
}

// ---------------------------------------------------------------------------
// Token scores, split-K: grid (split=8, b=8). tsp[(s*8+b)][64][64] partials.
// 3-slot ring + counted vmcnt (same discipline as gemm_core).
__global__ __launch_bounds__(256) void token_scores_kernel(const u16* __restrict__ tq,
                                                           const u16* __restrict__ tk,
                                                           float* __restrict__ tsp) {
  int s = blockIdx.x, b = blockIdx.y;
  const u16* A = tq + (long)b * 64 * NTD;
  const u16* B = tk + (long)b * 64 * NTD;
  __shared__ __align__(16) u16 As[3 * 2048];
  __shared__ __align__(16) u16 Bs[3 * 2048];
  int tid = threadIdx.x, lane = tid & 63, w = tid >> 6;
  int l15 = lane & 15, quad = lane >> 4;
  f32x4 acc[4] = {};
  const int r = tid >> 2;
  const int cs = (((tid & 3) ^ ((r >> 1) & 3)) << 3);
  const u16* pa = A + (long)r * NTD + cs;
  const u16* pbp = B + (long)r * NTD + cs;
  const int lb = (tid & ~63) * 8;

  auto stage = [&](int ch, int bi) {
    async_cp16(pa + ch * 32, &As[bi + lb]);
    async_cp16(pbp + ch * 32, &Bs[bi + lb]);
  };
  auto compute = [&](int bi) {
    int row = w * 16 + l15;
    bf16x8 av = *(const bf16x8*)&As[bi + row * 32 + ((quad ^ ((row >> 1) & 3)) << 3)];
#pragma unroll
    for (int j = 0; j < 4; j++) {
      int rb = j * 16 + l15;
      bf16x8 bv = *(const bf16x8*)&Bs[bi + rb * 32 + ((quad ^ ((rb >> 1) & 3)) << 3)];
      acc[j] = __builtin_amdgcn_mfma_f32_16x16x32_bf16(av, bv, acc[j], 0, 0, 0);
    }
  };

  int ch0 = s * 6, nch = (s == 7) ? 7 : 6;
  stage(ch0, 0);
  stage(ch0 + 1, 2048);
  for (int c = 0; c < nch; c++) {
    if (c + 1 < nch) {
      asm volatile("s_waitcnt vmcnt(2)" ::: "memory");
    } else {
      asm volatile("s_waitcnt vmcnt(0)" ::: "memory");
    }
    __builtin_amdgcn_s_barrier();
    if (c + 2 < nch) stage(ch0 + c + 2, ((c + 2) % 3) * 2048);
    compute((c % 3) * 2048);
  }
  if (s == 7) {  // 8-element K tail at k=1568
    const int tb = (nch % 3) * 2048;
    __syncthreads();
    for (int idx = tid; idx < 2048; idx += 256) {
      int rr = idx >> 5, cc = idx & 31;
      int g = ((((cc >> 3) ^ ((rr >> 1) & 3)) << 3)) | (cc & 7);
      As[tb + idx] = (g < 8) ? A[(long)rr * NTD + 1568 + g] : (u16)0;
      Bs[tb + idx] = (g < 8) ? B[(long)rr * NTD + 1568 + g] : (u16)0;
    }
    __syncthreads();
    compute(tb);
  }
  const float sc = rsqrtf(1576.f);
  float* dst = tsp + ((long)(s * 8 + b)) * 4096;
#pragma unroll
  for (int j = 0; j < 4; j++)
#pragma unroll
    for (int reg = 0; reg < 4; reg++) {
      int row = w * 16 + quad * 4 + reg, col = j * 16 + l15;
      dst[row * 64 + col] = acc[j][reg] * sc;
    }
}

// ---------------------------------------------------------------------------
// Spatial softmax: sums 2 split-K partials s[0],s[1] (each 64x197x197 fp32)
// -> pb bf16 (64,197,208). 4 rows/block; row cached in registers.
__global__ void softmax_spatial_kernel(const float* __restrict__ s, u16* __restrict__ pb) {
  int row = blockIdx.x * 4 + (threadIdx.x >> 6);
  int lane = threadIdx.x & 63;
  const float* p0 = s + (long)row * 197;
  const float* p1 = p0 + 2483776;
  int hb = row / 197, mm = row - hb * 197;
  u16* q = pb + (long)hb * 197 * MP + (long)mm * MP;
  float vv[4];
  float mx = -INFINITY;
  int cnt = 0;
  for (int j = lane; j < 197; j += 64) {
    vv[cnt] = p0[j] + p1[j];
    mx = fmaxf(mx, vv[cnt]);
    cnt++;
  }
#pragma unroll
  for (int off = 32; off; off >>= 1) mx = fmaxf(mx, __shfl_xor(mx, off));
  float sum = 0.f;
  for (int i = 0; i < cnt; i++) { vv[i] = expf(vv[i] - mx); sum += vv[i]; }
#pragma unroll
  for (int off = 32; off; off >>= 1) sum += __shfl_xor(sum, off);
  float inv = 1.f / sum;
  cnt = 0;
  for (int j = lane; j < 197; j += 64) { q[j] = f2bf(vv[cnt] * inv); cnt++; }
}

// Token softmax: sums 8 split-K partials, softmaxes, writes Pb bf16.
__global__ void softmax_token_kernel(const float* __restrict__ tsp, u16* __restrict__ Pb) {
  int row = blockIdx.x * 4 + (threadIdx.x >> 6);  // 0..511 = b*64+r
  int lane = threadIdx.x & 63;
  int b = row >> 6, r = row & 63;
  float v = 0.f;
#pragma unroll
  for (int p = 0; p < 8; p++) v += tsp[((long)(p * 8 + b)) * 4096 + r * 64 + lane];
  float mx = v;
#pragma unroll
  for (int off = 32; off; off >>= 1) mx = fmaxf(mx, __shfl_xor(mx, off));
  float e = expf(v - mx);
  float sum = e;
#pragma unroll
  for (int off = 32; off; off >>= 1) sum += __shfl_xor(sum, off);
  Pb[(long)row * 64 + lane] = f2bf(e / sum);
}

// ---------------------------------------------------------------------------
// Attn output reduce + residual, vectorized x4; fused per-batch sum(x^2).
// grid 788 x 256. A block (1024 elems) may straddle ONE batch boundary ->
// segmented 2-slot reduce.
__global__ void attn_reduce_kernel(const float* __restrict__ part, const float* __restrict__ bias,
                                   const float* __restrict__ resid, float* __restrict__ x,
                                   float* __restrict__ sqslot) {
  int idx4 = blockIdx.x * 256 + threadIdx.x;
  long base = (long)idx4 * 4;
  int col = (int)(base % ND);
  float4 sv = *(const float4*)(bias + col);
  float4 rv = ((const float4*)resid)[idx4];
  sv.x += rv.x; sv.y += rv.y; sv.z += rv.z; sv.w += rv.w;
#pragma unroll
  for (int h = 0; h < 8; h++) {
    float4 pv = ((const float4*)part)[(h * (XSZ >> 2)) + idx4];
    sv.x += pv.x; sv.y += pv.y; sv.z += pv.z; sv.w += pv.w;
  }
  ((float4*)x)[idx4] = sv;
  float ssq = sv.x * sv.x + sv.y * sv.y + sv.z * sv.z + sv.w * sv.w;
  int b = (int)(base / BMD);
  int bfirst = (int)(((long)blockIdx.x * 1024) / BMD);
  float s0 = (b == bfirst) ? ssq : 0.f;
  float s1 = ssq - s0;
  __shared__ float red0[256], red1[256];
  red0[threadIdx.x] = s0; red1[threadIdx.x] = s1; __syncthreads();
  for (int o = 128; o; o >>= 1) {
    if (threadIdx.x < o) {
      red0[threadIdx.x] += red0[threadIdx.x + o];
      red1[threadIdx.x] += red1[threadIdx.x + o];
    }
    __syncthreads();
  }
  if (threadIdx.x == 0) {
    atomicAdd(&sqslot[bfirst], red0[0]);
    if (red1[0] != 0.f) atomicAdd(&sqslot[bfirst + 1], red1[0]);
  }
}

// ---------------------------------------------------------------------------
// Merged transposes: Wqkv (48 slabs, z = l*24 + w*8 + h) + attn_W (16 slabs:
// z-48 = l*8 + i) + patch_W (z=64). grid (16,24,65); z<64 uses by<16 only.
__global__ void transpose_wa_kernel(const float* __restrict__ Wq, const float* __restrict__ Wk,
                                    const float* __restrict__ Wv, const float* __restrict__ attn_W,
                                    const float* __restrict__ patch_W,
                                    u16* __restrict__ Wt16, u16* __restrict__ Wat16,
                                    u16* __restrict__ pWt) {
  int z = blockIdx.z;
  __shared__ float t[32][33];
  int c0 = blockIdx.x * 32, r0 = blockIdx.y * 32;
  int tx = threadIdx.x, ty = threadIdx.y;
  if (z == 64) {
    // patch_W fp32 (768x512) -> pWt bf16 (512x768); r0<768, c0<512, exact tiles
#pragma unroll
    for (int i = 0; i < 4; i++)
      t[ty + i * 8][tx] = patch_W[(long)(r0 + ty + i * 8) * 512 + c0 + tx];
    __syncthreads();
#pragma unroll
    for (int i = 0; i < 4; i++)
      pWt[(long)(c0 + ty + i * 8) * 768 + r0 + tx] = f2bf(t[tx][ty + i * 8]);
    return;
  }
  if (blockIdx.y >= 16) return;
  const float* src;
  u16* dst;
  long dld;
  if (z < 48) {
    int l = z / 24, rem = z - l * 24, w = rem >> 3, h = rem & 7;
    src = (w == 0 ? Wq : w == 1 ? Wk : Wv) + (long)(l * 8 + h) * 262144;
    dst = Wt16 + (long)z * 262144;
    dld = 512;
  } else {
    int za = z - 48, l = za >> 3, i = za & 7;   // 8 row-blocks per layer
    src = attn_W + (long)l * 4096 * 512 + (long)i * 512 * 512;
    dst = Wat16 + (long)l * 512 * 4096 + (long)i * 512;
    dld = 4096;
  }
#pragma unroll
  for (int i = 0; i < 4; i++)
    t[ty + i * 8][tx] = src[(long)(r0 + ty + i * 8) * 512 + c0 + tx];
  __syncthreads();
#pragma unroll
  for (int i = 0; i < 4; i++)
    dst[(long)(c0 + ty + i * 8) * dld + r0 + tx] = f2bf(t[tx][ty + i * 8]);
}

// Merged tWq/tWk/tWv transpose: grid (50,50,6), z = w*2 + l.
__global__ void t_transpose3_kernel(const float* __restrict__ Wq, const float* __restrict__ Wk,
                                    const float* __restrict__ Wv, u16* __restrict__ dst0) {
  int z = blockIdx.z;
  int w = z >> 1, l = z & 1;
  const float* src = (w == 0 ? Wq : w == 1 ? Wk : Wv) + (long)l * NTD * NTD;
  u16* d = dst0 + (long)z * NTD * NTD;
  __shared__ float t[32][33];
  int c0 = blockIdx.x * 32, r0 = blockIdx.y * 32;
  int tx = threadIdx.x, ty = threadIdx.y;
#pragma unroll
  for (int i = 0; i < 4; i++) {
    int r = r0 + ty + i * 8;
    if (r < NTD && c0 + tx < NTD) t[ty + i * 8][tx] = src[(long)r * NTD + c0 + tx];
  }
  __syncthreads();
#pragma unroll
  for (int i = 0; i < 4; i++) {
    int c = c0 + ty + i * 8;
    if (c < NTD && r0 + tx < NTD) d[(long)c * NTD + r0 + tx] = f2bf(t[tx][ty + i * 8]);
  }
}

// ---------------------------------------------------------------------------
// Fused cls LayerNorm + head GEMM. grid (4,8), 256 thr (LN redone per block).
__global__ void ln_head_kernel(const float* __restrict__ x, const float* __restrict__ g,
                               const float* __restrict__ bb, const float* __restrict__ W,
                               const float* __restrict__ hb, float* __restrict__ out) {
  int b = blockIdx.y, t = threadIdx.x;
  __shared__ float xs[512];
  __shared__ float red[256];
  float v0 = x[(long)b * NM * ND + t];
  float v1 = x[(long)b * NM * ND + 256 + t];
  red[t] = v0 + v1; __syncthreads();
  for (int o = 128; o; o >>= 1) { if (t < o) red[t] += red[t + o]; __syncthreads(); }
  float mu = red[0] / 512.f; __syncthreads();
  float d0 = v0 - mu, d1 = v1 - mu;
  red[t] = d0 * d0 + d1 * d1; __syncthreads();
  for (int o = 128; o; o >>= 1) { if (t < o) red[t] += red[t + o]; __syncthreads(); }
  float inv = rsqrtf(red[0] / 512.f + 1e-5f); __syncthreads();
  xs[t] = d0 * inv * g[t] + bb[t];
  xs[256 + t] = d1 * inv * g[256 + t] + bb[256 + t];
  __syncthreads();
  int n = blockIdx.x * 250 + t;
  if (t < 250 && n < 1000) {
    float acc = hb[n];
    for (int dd = 0; dd < 512; dd++) acc += xs[dd] * W[(long)dd * 1000 + n];
    out[(long)b * 1000 + n] = acc;
  }
}

}  // namespace

extern "C" void kernel_launch(void* const* d_in, const int* in_sizes, int n_in,
                              void* d_out, int out_size, void* d_ws, size_t ws_size,
                              hipStream_t stream) {
  const float* img     = (const float*)d_in[0];
  const float* patch_W = (const float*)d_in[1];
  const float* patch_b = (const float*)d_in[2];
  const float* cls_tok = (const float*)d_in[3];
  const float* rms_s   = (const float*)d_in[4];
  const float* Wq      = (const float*)d_in[5];
  const float* Wk      = (const float*)d_in[6];
  const float* Wv      = (const float*)d_in[7];
  const float* attn_W  = (const float*)d_in[8];
  const float* attn_b  = (const float*)d_in[9];
  const float* tWq     = (const float*)d_in[10];
  const float* tWk     = (const float*)d_in[11];
  const float* tWv     = (const float*)d_in[12];
  const float* ln_g    = (const float*)d_in[13];
  const float* ln_b    = (const float*)d_in[14];
  const float* head_W  = (const float*)d_in[15];
  const float* head_b  = (const float*)d_in[16];
  float* out = (float*)d_out;

  // ---- workspace layout (floats) ----
  float* base = (float*)d_ws;
  long off = 0;
  auto alloc = [&](long n) { float* r = base + off; off += (n + 15) & ~15L; return r; };
  float* cosP = alloc(TABSZ);       // interleaved (cos,sin) float2 table spans
  float* sinP = alloc(TABSZ);       //   cosP..sinP (2*TABSZ floats contiguous)
  float* cosT = alloc(TABSZ);
  float* sinT = alloc(TABSZ);
  float* x    = alloc(XSZ);
  float* xn   = alloc(XSZ);
  float* Wt_f   = alloc(6291456);   // 48 slabs 512x512 bf16, z = l*24+w*8+h
  float* Wat_f  = alloc(2097152);   // (l) 512x4096 bf16
  float* tWt_f  = alloc(7451328);   // (w,l) 1576x1576 bf16
  float* xnb_f  = alloc(XSZ / 2);
  float* pimg_f = alloc(602112);    // 1568x768 bf16
  float* pWt_f  = alloc(196608);    // 512x768 bf16
  float* U      = alloc(16885824);  // union region
  float* ffs    = alloc(64);        // fused sq-sum slots:
                                    //   [0..7]=attn l0, [8..15]=tok l0,
                                    //   [16..23]=attn l1, [24..31]=tok l1 (dead),
                                    //   [32..39]=patch embed (layer-0 RMS)

  u16* Wt16  = (u16*)Wt_f;
  u16* Wat16 = (u16*)Wat_f;
  u16* tWt16 = (u16*)tWt_f;
  u16* xnb   = (u16*)xnb_f;
  u16* pimg  = (u16*)pimg_f;
  u16* pWt   = (u16*)pWt_f;
  // patch split-K partials: 3 x 1568*512 fp32 in U (dead until qkv writes q)
  float* patchp = (float*)U;
  // phase A overlay (contract: kk = q + QSZ, vt = q + 2*QSZ)
  u16* q   = (u16*)U;                 // 6455296 (h, b*m, e)
  u16* kk  = q + QSZ;                 // 6455296
  u16* vt  = kk + QSZ;                // 6815744 (h,b,e,m_pad)
  float* s = (float*)(vt + 6815744);  // 2x 2483776 f split-K score partials
  u16* pb  = (u16*)(s + 2 * 2483776); // 2622464 (hb,197,208)
  u16* o   = (u16*)s;                 // 6455296 (aliases dead s after softmax)
  float* part = (float*)q;            // 8*XSZ fp32 (aliases dead q,kk)
  // phase B overlay (contract: tkb = tqb + XSZ, tvt = tqb + 2*XSZ)
  u16* yb     = (u16*)U;              // 806912 (b*64+c, 1576)
  float* tprt = (float*)(yb + XSZ);   // 12*XSZ fp32 split partials
  u16* tqb    = (u16*)(tprt + 12 * XSZ);
  u16* tvt    = tqb + 2 * XSZ;        // (b, 1576, 64)
  float* tsp  = (float*)(tvt + XSZ);  // 8 x 8 x 64 x 64
  u16* Pb     = (u16*)(tsp + 262144); // 8*64*64

  const float rs512 = 1.f / sqrtf(512.f);
  const dim3 tt(32, 8);

  // ---- setup ----
  init_kernel<<<5115, 256, 0, stream>>>(img, cls_tok, cosP, sinP, cosT, sinT, pimg, x, ffs);
  transpose_wa_kernel<<<dim3(16, 24, 65), tt, 0, stream>>>(
      Wq, Wk, Wv, attn_W, patch_W, Wt16, Wat16, pWt);
  t_transpose3_kernel<<<dim3(50, 50, 6), tt, 0, stream>>>(tWq, tWk, tWv, tWt16);
  // patch embed, 3-way split-K (K=256 each), fp32 partials -> patchp
  mfma_gemm<EPI_F32><<<dim3(4, 13, 3), 256, 0, stream>>>(
      pimg, pWt, patchp, nullptr, nullptr, 1568, 512, 256, 768, 768, 512, 1.f, 1,
      256, 0, 256, 0, 802816L, 0);
  // reduce partials + bias -> x; fused per-batch ssq (+cls row) -> ffs[32..39]
  patch_reduce_kernel<<<785, 256, 0, stream>>>(patchp, patch_b, cls_tok, x, ffs + 32);

  for (int l = 0; l < 2; l++) {
    const float* scale = rms_s + (long)l * NM * ND;
    float* slotA = ffs + l * 16;       // attn-phase sq-sums for this layer
    float* slotT = ffs + l * 16 + 8;   // token-phase sq-sums for this layer
    // ---- spatial attention ----
    // sq-sums pre-accumulated: patch_reduce (l=0) / previous token-PV (l=1)
    rms_apply_kernel<<<788, 256, 0, stream>>>(
        x, scale, (l == 0) ? ffs + 32 : ffs + 8, 1, xn, xnb);

    // qkv with fused RoPE on q,k
    qkv_kernel<<<dim3(4, 13, 24), 256, 0, stream>>>(xnb, Wt16 + (long)l * 24 * 262144, q, cosP);

    // scores, 2-way split-K (fp32 partials, scaled)
    mfma_gemm<EPI_F32><<<dim3(2, 2, 128), 256, 0, stream>>>(
        q, kk, s, nullptr, nullptr, 197, 197, 256, 512, 512, 197, rs512, 64,
        256, 197L * 512, 256, 197L * 512, 2483776, 197L * 197);
    softmax_spatial_kernel<<<3152, 256, 0, stream>>>(s, pb);
    // o = P @ v   (o aliases the now-dead s region)
    mfma_gemm<EPI_BF16><<<dim3(4, 2, 64), 256, 0, stream>>>(
        pb, vt, o, nullptr, nullptr, 197, 512, 197, MP, MP, 512, 1.f, 64,
        0, 197L * MP, 0, 512L * MP, 0, 197L * 512);
    // attn-proj head partials
    mfma_gemm<EPI_F32><<<dim3(4, 13, 8), 256, 0, stream>>>(
        o, Wat16 + (long)l * 2097152, part, nullptr, nullptr, 1576, 512, 512, 512, 4096, 512,
        1.f, 8, 0, XSZ, 0, 512, 0, XSZ);
    // reduce + residual + fused sum(x^2) into slotA
    attn_reduce_kernel<<<788, 256, 0, stream>>>(part, attn_b + (long)l * ND, xn, x, slotA);

    // ---- token mixing ----
    rms_apply_tok_kernel<<<788, 256, 0, stream>>>(x, scale, slotA, 1, xn, yb);

    // 4-way K split (624 blocks)
    tok_qkv_kernel<<<dim3(4, 13, 12), 256, 0, stream>>>(yb, tWt16, l, tprt);
    token_finish_kernel<<<1576, 256, 0, stream>>>(tprt, cosT, sinT, tqb);

    token_scores_kernel<<<dim3(8, 8), 256, 0, stream>>>(tqb, tqb + XSZ, tsp);
    softmax_token_kernel<<<128, 256, 0, stream>>>(tsp, Pb);
    // token PV: scatter + residual into fp32 x; fused sum(x^2) into slotT
    mfma_gemm<EPI_TOKPV><<<dim3(13, 1, 8), 256, 0, stream>>>(
        Pb, tvt, x, xn, slotT, 64, 1576, 64, 64, 64, 0, 1.f, 8,
        0, 4096, 0, 1576L * 64, 0, 0);
  }

  ln_head_kernel<<<dim3(4, 8), 256, 0, stream>>>(x, ln_g, ln_b, head_W, head_b, out);
}

// Round 8
// 614.253 us; speedup vs baseline: 1.2347x; 1.0691x over previous
//
#include <hip/hip_runtime.h>
#include <math.h>

// B=8, m=197, dim=512, heads=8, depth=2, F=8, tdim=1576, cdim=64, ncls=1000.
namespace {

typedef unsigned short u16;
typedef __attribute__((ext_vector_type(8))) short bf16x8;
typedef __attribute__((ext_vector_type(4))) float f32x4;
typedef __attribute__((ext_vector_type(4))) unsigned short u16x4;
typedef __attribute__((ext_vector_type(2))) unsigned short u16x2;

constexpr int NB = 8, NM = 197, ND = 512, NH = 8, NTD = 1576, NC = 64;
constexpr long XSZ = (long)NB * NM * ND;        // 806912
constexpr long QSZ = (long)NH * XSZ;            // 6455296 (h, b*m, e)
constexpr long TABSZ = 50432;                   // 197*256 == 64*788
constexpr int MP = 208;                         // padded 197 (16B-aligned bf16 rows)
constexpr int BMD = NM * ND;                    // 100864 per-batch elems

__device__ __forceinline__ u16 f2bf(float f) {
  union { float f; unsigned u; } v; v.f = f;
  unsigned r = v.u + 0x7FFF + ((v.u >> 16) & 1);
  return (u16)(r >> 16);
}
__device__ __forceinline__ void async_cp16(const void* g, void* l) {
  __builtin_amdgcn_global_load_lds((const __attribute__((address_space(1))) unsigned*)g,
                                   (__attribute__((address_space(3))) unsigned*)l, 16, 0, 0);
}

// Bijective XCD-chunk swizzle (m204).
__device__ __forceinline__ int xcd_swz(int orig, int nwg) {
  int q = nwg >> 3, r = nwg & 7, x = orig & 7, i = orig >> 3;
  return (x < r ? x * (q + 1) : r * (q + 1) + (x - r) * q) + i;
}
__device__ __forceinline__ int swz_flat() {
  int nwg = gridDim.x * gridDim.y * gridDim.z;
  int orig = blockIdx.x + gridDim.x * (blockIdx.y + gridDim.y * blockIdx.z);
  return xcd_swz(orig, nwg);
}

// ---------------------------------------------------------------------------
// Shared MFMA GEMM core: acc += A(M x KL) * B^T(N x KL), 128x128 tile, BK=32.
// 512 threads / 8 waves (2 M-tiles x 4 N-tiles), acc[4][2] per wave.
// Depth-2 prefetch: 3-slot LDS ring, raw s_barrier + counted vmcnt(2)
// (2 global_load_lds per stage; one stage kept in flight across the barrier).
// LDS fill invariant: thread tid loads A-row r=tid>>2 at k-offset
// cs=((tid&3)^((r>>1)&3))<<3; global_load_lds lands it at
// As[bi + row*32 + slot*8] with slot=(tid&3) -> k-group g = slot^((row>>1)&3),
// matching compute()'s swizzled fragment read (unchanged from 256-thr core).
__device__ __forceinline__ void gemm_core(
    const u16* __restrict__ A, int lda, int M, int row0,
    const u16* __restrict__ B, int ldb, int N, int col0,
    int KL, u16* As, u16* Bs, f32x4 (&acc)[4][2],
    int tid, int wm, int wn, int l15, int quad) {
  const int nfull = KL >> 5, tail = KL & 31;
  const int r = tid >> 2;                      // 0..127 (512 threads)
  const int cs = (((tid & 3) ^ ((r >> 1) & 3)) << 3);
  int gr0 = row0 + r; if (gr0 >= M) gr0 = M - 1;
  int gc0 = col0 + r; if (gc0 >= N) gc0 = N - 1;
  const u16* pa0 = A + (long)gr0 * lda + cs;
  const u16* pb0 = B + (long)gc0 * ldb + cs;
  const int lb0 = (tid & ~63) * 8;             // wave wv -> wv*512 u16

  auto stage = [&](int k0, int bi) {
    async_cp16(pa0 + k0, &As[bi + lb0]);
    async_cp16(pb0 + k0, &Bs[bi + lb0]);
  };
  auto compute = [&](int bi) {
    bf16x8 af[4], bg[2];
#pragma unroll
    for (int i = 0; i < 4; i++) {
      int row = wm * 64 + i * 16 + l15;
      af[i] = *(const bf16x8*)&As[bi + row * 32 + ((quad ^ ((row >> 1) & 3)) << 3)];
    }
#pragma unroll
    for (int j = 0; j < 2; j++) {
      int row = wn * 32 + j * 16 + l15;
      bg[j] = *(const bf16x8*)&Bs[bi + row * 32 + ((quad ^ ((row >> 1) & 3)) << 3)];
    }
#pragma unroll
    for (int i = 0; i < 4; i++)
#pragma unroll
      for (int j = 0; j < 2; j++)
        acc[i][j] = __builtin_amdgcn_mfma_f32_16x16x32_bf16(af[i], bg[j], acc[i][j], 0, 0, 0);
  };

  if (nfull > 0) {
    stage(0, 0);
    if (nfull > 1) stage(32, 4096);
    for (int ch = 0; ch < nfull; ch++) {
      if (ch + 1 < nfull) {
        asm volatile("s_waitcnt vmcnt(2)" ::: "memory");
      } else {
        asm volatile("s_waitcnt vmcnt(0)" ::: "memory");
      }
      __builtin_amdgcn_s_barrier();
      if (ch + 2 < nfull) stage((ch + 2) << 5, ((ch + 2) % 3) * 4096);
      compute((ch % 3) * 4096);
    }
  }
  if (tail) {
    const int tb = (nfull % 3) * 4096;
    const int k0f = nfull << 5;
    if (nfull > 0) __syncthreads();
    for (int idx2 = tid; idx2 < 4096; idx2 += 512) {
      int rr = idx2 >> 5, cc = idx2 & 31;
      int g = ((((cc >> 3) ^ ((rr >> 1) & 3)) << 3)) | (cc & 7);
      int grr = row0 + rr; if (grr >= M) grr = M - 1;
      int gcc = col0 + rr; if (gcc >= N) gcc = N - 1;
      As[tb + idx2] = (g < tail) ? A[(long)grr * lda + k0f + g] : (u16)0;
      Bs[tb + idx2] = (g < tail) ? B[(long)gcc * ldb + k0f + g] : (u16)0;
    }
    __syncthreads();
    compute(tb);
  }
}

// ---------------------------------------------------------------------------
// init: RoPE tables + patch gather + cls fill + zero sq-sum slots. One launch.
// grid 5115 x 256. Spatial table is INTERLEAVED (cos,sin) float2 in cosP.
__global__ void init_kernel(const float* __restrict__ img, const float* __restrict__ cls,
                            float* cosP, float* sinP, float* cosT, float* sinT,
                            u16* __restrict__ pimg, float* __restrict__ x,
                            float* __restrict__ ffs) {
  long idx = (long)blockIdx.x * 256 + threadIdx.x;
  if (idx < 197 * 256) {
    int p = (int)(idx / 256), i = (int)(idx % 256);
    float theta = powf(10000.f, -2.f * ((float)i - 1.f) / 512.f);
    float a = (float)p * theta;
    cosP[2 * idx] = cosf(a); cosP[2 * idx + 1] = sinf(a);
    return;
  }
  long j = idx - 197 * 256;
  if (j < 64 * 788) {
    int p = (int)(j / 788), i = (int)(j % 788);
    float theta = powf(10000.f, -2.f * ((float)i - 1.f) / 1576.f);
    float a = (float)p * theta;
    cosT[j] = cosf(a); sinT[j] = sinf(a);
    return;
  }
  long k2 = j - 64 * 788;
  if (k2 < 1568L * 768) {
    int r = (int)(k2 / 768), k = (int)(k2 % 768);
    int b = r / 196, p = r - b * 196;
    int pi = p / 14, pj = p - pi * 14;
    int cc = k % 3, pq = k / 3, pp = pq >> 4, qq = pq & 15;
    pimg[k2] = f2bf(img[((long)(b * 3 + cc) * 224 + pi * 16 + pp) * 224 + pj * 16 + qq]);
    return;
  }
  long c2 = k2 - 1568L * 768;
  if (c2 < 8 * 512) {
    int b = (int)(c2 >> 9), e = (int)(c2 & 511);
    x[((long)b * NM) * ND + e] = cls[e];
    return;
  }
  long c3 = c2 - 8 * 512;
  if (c3 < 64) ffs[c3] = 0.f;   // zero all fused sq-sum slots (incl. patch @32)
}

// np=8: sum 8 partials per batch; np=1: single pre-accumulated float.
__device__ __forceinline__ float rms_inv(const float* part, int b, int np) {
  float ssum = 0.f;
  if (np == 8) {
#pragma unroll
    for (int i = 0; i < 8; i++) ssum += part[b * 8 + i];
  } else {
    ssum = part[b];
  }
  return sqrtf((float)(NM * ND) / ssum);
}

// Vectorized x4: grid 788 x 256 (XSZ/4 = 201728 float4 threads).
__global__ void rms_apply_kernel(const float* __restrict__ x, const float* __restrict__ scale,
                                 const float* __restrict__ part, int np, float* __restrict__ xn,
                                 u16* __restrict__ xnb) {
  int idx4 = blockIdx.x * 256 + threadIdx.x;
  int b = idx4 / (BMD / 4);
  int md4 = idx4 - b * (BMD / 4);
  float ri = rms_inv(part, b, np);
  float4 xv = ((const float4*)x)[idx4];
  float4 sv = ((const float4*)(scale))[md4];
  float4 v;
  v.x = xv.x * sv.x * ri; v.y = xv.y * sv.y * ri;
  v.z = xv.z * sv.z * ri; v.w = xv.w * sv.w * ri;
  ((float4*)xn)[idx4] = v;
  u16x4 h = { f2bf(v.x), f2bf(v.y), f2bf(v.z), f2bf(v.w) };
  ((u16x4*)xnb)[idx4] = h;
}

// Phase-B vectorized: writes xn and permuted yb[(b*64+c)*1576 + f*197+mm].
__global__ void rms_apply_tok_kernel(const float* __restrict__ x, const float* __restrict__ scale,
                                     const float* __restrict__ part, int np, float* __restrict__ xn,
                                     u16* __restrict__ yb) {
  int idx4 = blockIdx.x * 256 + threadIdx.x;
  int b = idx4 / (BMD / 4);
  int md4 = idx4 - b * (BMD / 4);
  float ri = rms_inv(part, b, np);
  float4 xv = ((const float4*)x)[idx4];
  float4 sv = ((const float4*)(scale))[md4];
  float4 v;
  v.x = xv.x * sv.x * ri; v.y = xv.y * sv.y * ri;
  v.z = xv.z * sv.z * ri; v.w = xv.w * sv.w * ri;
  ((float4*)xn)[idx4] = v;
  int md = md4 * 4;
  int mm = md / ND, d0 = md - mm * ND;     // d0 % 4 == 0
  int c = d0 >> 3, f0 = d0 & 7;            // f0 in {0,4}; f = f0..f0+3
  u16* row = yb + ((long)b * 64 + c) * NTD + mm;
  row[(f0 + 0) * 197] = f2bf(v.x);
  row[(f0 + 1) * 197] = f2bf(v.y);
  row[(f0 + 2) * 197] = f2bf(v.z);
  row[(f0 + 3) * 197] = f2bf(v.w);
}

// ---------------------------------------------------------------------------
// Patch split-K reduce: x[b][1+p][col] = sum of 3 partials + bias; fused
// per-batch sum(x^2) into sq[b] (plus cls-row ssq via the extra block 784).
// grid 785 x 256. 98 blocks per batch exactly (196*512/1024) -> no straddle.
__global__ void patch_reduce_kernel(const float* __restrict__ pp, const float* __restrict__ bias,
                                    const float* __restrict__ cls, float* __restrict__ x,
                                    float* __restrict__ sq) {
  __shared__ float red[256];
  int t = threadIdx.x;
  if (blockIdx.x == 784) {   // cls ssq, identical for all batches
    float v0 = cls[t], v1 = cls[256 + t];
    red[t] = v0 * v0 + v1 * v1; __syncthreads();
    for (int o = 128; o; o >>= 1) {
      if (t < o) red[t] += red[t + o];
      __syncthreads();
    }
    if (t < 8) atomicAdd(&sq[t], red[0]);
    return;
  }
  int idx4 = blockIdx.x * 256 + t;
  long e0 = (long)idx4 * 4;
  int prow = (int)(e0 >> 9), col = (int)(e0 & 511);
  int b = prow / 196, p = prow - b * 196;
  float4 s0 = ((const float4*)pp)[idx4];
  float4 s1 = ((const float4*)pp)[200704 + idx4];
  float4 s2 = ((const float4*)pp)[401408 + idx4];
  float4 bv = *(const float4*)(bias + col);
  float4 r;
  r.x = s0.x + s1.x + s2.x + bv.x;
  r.y = s0.y + s1.y + s2.y + bv.y;
  r.z = s0.z + s1.z + s2.z + bv.z;
  r.w = s0.w + s1.w + s2.w + bv.w;
  *(float4*)(x + ((long)(b * 197 + 1 + p) * 512 + col)) = r;
  red[t] = r.x * r.x + r.y * r.y + r.z * r.z + r.w * r.w;
  __syncthreads();
  for (int o = 128; o; o >>= 1) {
    if (t < o) red[t] += red[t + o];
    __syncthreads();
  }
  if (t == 0) atomicAdd(&sq[blockIdx.x / 98], red[0]);
}

// ---------------------------------------------------------------------------
// Spatial QKV, one launch. grid (4,13,24) x 512 thr, z = w*8+h (after swizzle).
// w<2: q/k = xnb(1576x512) @ Wslab^T -> (h,b*m,e), RoPE fused in epilogue.
// w=2: v^T = Wv^T(512x512) @ xnb^T -> vt (h,b,e,m_pad).
__global__ __launch_bounds__(512) void qkv_kernel(const u16* __restrict__ xnb,
                                                  const u16* __restrict__ WtL,
                                                  u16* __restrict__ q,
                                                  const float* __restrict__ csP) {
  int wg = swz_flat();
  int bx = wg & 3, tmp = wg >> 2;
  int by = tmp % 13, bz = tmp / 13;
  int w = bz >> 3, h = bz & 7;
  __shared__ __align__(16) u16 As[3 * 4096];
  __shared__ __align__(16) u16 Bs[3 * 4096];
  const int tid = threadIdx.x;
  const int lane = tid & 63, wave = tid >> 6;
  const int wm = wave >> 2, wn = wave & 3;
  const int l15 = lane & 15, quad = lane >> 4;
  f32x4 acc[4][2] = {};

  if (w < 2) {
    int row0 = by * 128, col0 = bx * 128;
    const u16* B = WtL + ((long)(w * 8 + h)) * 262144;
    gemm_core(xnb, 512, 1576, row0, B, 512, 512, col0, 512, As, Bs, acc,
              tid, wm, wn, l15, quad);
    long base = (long)w * QSZ + (long)h * XSZ;
    const float2* cs2 = (const float2*)csP;
#pragma unroll
    for (int i = 0; i < 4; i++)
#pragma unroll
      for (int j = 0; j < 2; j++)
#pragma unroll
        for (int reg = 0; reg < 4; reg++) {
          int gr = row0 + wm * 64 + i * 16 + quad * 4 + reg;
          int gc = col0 + wn * 32 + j * 16 + l15;
          float v = acc[i][j][reg];
          float p = __shfl_xor(v, 1);            // all lanes execute (guard below)
          int t = gr % 197;                      // token index (bogus rows unused)
          float2 cs = cs2[t * 256 + (gc >> 1)];
          float outv = v * cs.x + ((gc & 1) ? -p * cs.y : p * cs.y);
          if (gr < 1576)
            q[base + (long)gr * 512 + gc] = f2bf(outv);
        }
  } else {
    int row0 = bx * 128, col0 = by * 128;
    const u16* A = WtL + ((long)(16 + h)) * 262144;
    gemm_core(A, 512, 512, row0, xnb, 512, 1576, col0, 512, As, Bs, acc,
              tid, wm, wn, l15, quad);
#pragma unroll
    for (int i = 0; i < 4; i++)
#pragma unroll
      for (int j = 0; j < 2; j++)
#pragma unroll
        for (int reg = 0; reg < 4; reg++) {
          int gr = row0 + wm * 64 + i * 16 + quad * 4 + reg;  // e
          int gc = col0 + wn * 32 + j * 16 + l15;             // b*197+mm
          if (gr < 512 && gc < 1576) {
            int b = gc / 197, mm = gc - b * 197;
            q[2 * QSZ + ((long)(h * 8 + b) * 512 + gr) * MP + mm] = f2bf(acc[i][j][reg]);
          }
        }
  }
}

// ---------------------------------------------------------------------------
// Token QKV, one launch. grid (4,13,12) x 512 thr, XCD-chunked. 4-way K split:
// segs 416/416/416/328 (only last has a BK tail).
// z<8 : tq/tk partials (w=z>>2, seg=z&3): C = yb(512x1576) @ tW^T -> tprt[z].
// z>=8: tv^T partials (seg=z-8): C = tWv^T(1576x1576) @ yb^T -> tprt[8+seg].
__global__ __launch_bounds__(512) void tok_qkv_kernel(const u16* __restrict__ yb,
                                                      const u16* __restrict__ tWt, int l,
                                                      float* __restrict__ tprt) {
  int wg = swz_flat();
  int bx = wg & 3, tmp = wg >> 2;
  int by = tmp % 13, z = tmp / 13;
  __shared__ __align__(16) u16 As[3 * 4096];
  __shared__ __align__(16) u16 Bs[3 * 4096];
  const int tid = threadIdx.x;
  const int lane = tid & 63, wave = tid >> 6;
  const int wm = wave >> 2, wn = wave & 3;
  const int l15 = lane & 15, quad = lane >> 4;
  f32x4 acc[4][2] = {};

  if (z < 8) {
    int w = z >> 2, seg = z & 3;
    int kbeg = seg * 416, KL = (seg < 3) ? 416 : 328;
    int row0 = bx * 128, col0 = by * 128;
    const u16* A = yb + kbeg;
    const u16* B = tWt + ((long)(w * 2 + l)) * 2483776 + kbeg;
    gemm_core(A, 1576, 512, row0, B, 1576, 1576, col0, KL, As, Bs, acc,
              tid, wm, wn, l15, quad);
    float* dst = tprt + (long)z * XSZ;
#pragma unroll
    for (int i = 0; i < 4; i++)
#pragma unroll
      for (int j = 0; j < 2; j++)
#pragma unroll
        for (int reg = 0; reg < 4; reg++) {
          int gr = row0 + wm * 64 + i * 16 + quad * 4 + reg;
          int gc = col0 + wn * 32 + j * 16 + l15;
          if (gr < 512 && gc < 1576) dst[(long)gr * 1576 + gc] = acc[i][j][reg];
        }
  } else {
    int seg = z - 8;
    int kbeg = seg * 416, KL = (seg < 3) ? 416 : 328;
    int row0 = by * 128, col0 = bx * 128;
    const u16* A = tWt + ((long)(4 + l)) * 2483776 + kbeg;
    const u16* B = yb + kbeg;
    gemm_core(A, 1576, 1576, row0, B, 1576, 512, col0, KL, As, Bs, acc,
              tid, wm, wn, l15, quad);
    float* dst = tprt + (long)(8 + seg) * XSZ;
#pragma unroll
    for (int i = 0; i < 4; i++)
#pragma unroll
      for (int j = 0; j < 2; j++)
#pragma unroll
        for (int reg = 0; reg < 4; reg++) {
          int gr = row0 + wm * 64 + i * 16 + quad * 4 + reg;
          int gc = col0 + wn * 32 + j * 16 + l15;
          if (gr < 1576 && gc < 512) dst[(long)gr * 512 + gc] = acc[i][j][reg];
        }
  }
}

// Reduce token split-K partials: rope(tq), rope(tk), transpose(tv) -> bf16.
// tq = slabs 0..3, tk = 4..7, tv = 8..11. Pair-vectorized, grid 1576 x 256.
// tqb layout contract: tkb = tqb + XSZ, tvt = tqb + 2*XSZ.
__global__ void token_finish_kernel(const float* __restrict__ tp,
                                    const float* __restrict__ cosT,
                                    const float* __restrict__ sinT,
                                    u16* __restrict__ tqb) {
  int p2 = blockIdx.x * 256 + threadIdx.x;   // pair index, < XSZ/2
  int r = p2 / 788, gp = p2 - r * 788;       // row, pair-in-row (NTD/2=788)
  int t = r & 63;
  float cv = cosT[(long)t * 788 + gp];
  float sv = sinT[(long)t * 788 + gp];
  const float2* tp2 = (const float2*)tp;
  const long H = XSZ >> 1;                   // float2 elems per slab
  long pr = (long)r * 788 + gp;              // float2 index of the pair
  // tq = sum of 4 seg partials
  float2 a0 = tp2[pr], a1 = tp2[H + pr], a2 = tp2[2 * H + pr], a3 = tp2[3 * H + pr];
  float ve = a0.x + a1.x + a2.x + a3.x, vo = a0.y + a1.y + a2.y + a3.y;
  u16x2 hq = { f2bf(ve * cv + vo * sv), f2bf(-ve * sv + vo * cv) };
  ((u16x2*)tqb)[pr] = hq;
  // tk
  float2 b0 = tp2[4 * H + pr], b1 = tp2[5 * H + pr], b2 = tp2[6 * H + pr], b3 = tp2[7 * H + pr];
  ve = b0.x + b1.x + b2.x + b3.x; vo = b0.y + b1.y + b2.y + b3.y;
  u16x2 hk = { f2bf(ve * cv + vo * sv), f2bf(-ve * sv + vo * cv) };
  ((u16x2*)(tqb + XSZ))[pr] = hk;
  // tv: two consecutive idx = 2*p2, 2*p2+1 in the (1576 x 512) partial layout
  long i0 = (long)p2 * 2;
  int g2 = (int)(i0 >> 9), r2 = (int)(i0 & 511);    // r2 even
  float2 c0 = tp2[8 * H + p2], c1 = tp2[9 * H + p2];
  float2 c2 = tp2[10 * H + p2], c3 = tp2[11 * H + p2];
  u16x2 hv = { f2bf(c0.x + c1.x + c2.x + c3.x), f2bf(c0.y + c1.y + c2.y + c3.y) };
  long vo2 = 2 * XSZ + ((long)(r2 >> 6) * NTD + g2) * 64 + (r2 & 63);
  *(u16x2*)(tqb + vo2) = hv;
}

// ---------------------------------------------------------------------------
// Generic MFMA GEMM for the remaining shapes. 512 thr. XCD-chunked mapping.
// z = z1*nz2 + z2; A += z1*aS1 + z2*aS2 (aS1 enables K-segment split-K).
// EPI_TOKPV additionally accumulates per-batch sum(x^2) into sqout[z2].
enum { EPI_BF16 = 0, EPI_F32 = 1, EPI_TOKPV = 3, EPI_PATCH = 4 };

template <int EPI>
__global__ __launch_bounds__(512) void mfma_gemm(
    const u16* __restrict__ A, const u16* __restrict__ B, void* __restrict__ Cv,
    const float* __restrict__ resid, float* __restrict__ sqout,
    int M, int N, int K, int lda, int ldb, int ldc, float alpha, int nz2,
    long aS1, long aS2, long bS1, long bS2, long cS1, long cS2) {
  int wg = swz_flat();
  int bx = wg % gridDim.x; int tmp = wg / gridDim.x;
  int by = tmp % gridDim.y; int z = tmp / gridDim.y;
  int z1 = z / nz2, z2 = z - z1 * nz2;
  A += z1 * aS1 + z2 * aS2;
  B += z1 * bS1 + z2 * bS2;
  __shared__ __align__(16) u16 As[3 * 4096];
  __shared__ __align__(16) u16 Bs[3 * 4096];
  const int tid = threadIdx.x;
  const int lane = tid & 63, wave = tid >> 6;
  const int wm = wave >> 2, wn = wave & 3;
  const int l15 = lane & 15, quad = lane >> 4;
  const int row0 = by * 128, col0 = bx * 128;
  f32x4 acc[4][2] = {};
  gemm_core(A, lda, M, row0, B, ldb, N, col0, K, As, Bs, acc, tid, wm, wn, l15, quad);

  float* Cf = (float*)Cv;
  u16* Ch = (u16*)Cv;
  const long cbase = z1 * cS1 + z2 * cS2;
  float ssq = 0.f;
#pragma unroll
  for (int i = 0; i < 4; i++)
#pragma unroll
    for (int j = 0; j < 2; j++)
#pragma unroll
      for (int reg = 0; reg < 4; reg++) {
        int gr = row0 + wm * 64 + i * 16 + quad * 4 + reg;
        int gc = col0 + wn * 32 + j * 16 + l15;
        if (gr >= M || gc >= N) continue;
        float vv = acc[i][j][reg] * alpha;
        if (EPI == EPI_BF16) {
          Ch[cbase + (long)gr * ldc + gc] = f2bf(vv);
        } else if (EPI == EPI_F32) {
          Cf[cbase + (long)gr * ldc + gc] = vv;
        } else if (EPI == EPI_TOKPV) {    // x[b][mm][c*8+f] = acc + xn
          int f = gc / 197, mm = gc - f * 197;
          long o = ((long)z2 * 197 + mm) * 512 + gr * 8 + f;
          float xv = vv + resid[o];
          Cf[o] = xv;
          ssq += xv * xv;
        } else {                          // PATCH: x[b][1+p][gc] = acc + bias
          int b = gr / 196, p = gr - b * 196;
          Cf[((long)b * 197 + 1 + p) * 512 + gc] = vv + resid[gc];
        }
      }
  if (EPI == EPI_TOKPV) {
    __syncthreads();                       // LDS no longer needed by gemm
    float* red = (float*)As;
    red[tid] = ssq; __syncthreads();
    for (int o2 = 256; o2; o2 >>= 1) {
      if (tid < o2) red[tid] += red[tid + o2];
      __syncthreads();
    }
    if (tid == 0) atomicAdd(&sqout[z2], red[0]);
  }
}

// ---------------------------------------------------------------------------
// Token scores, split-K: grid (split=8, b=8) x 256 thr (own structure).
// tsp[(s*8+b)][64][64] partials. 3-slot ring + counted vmcnt.
__global__ __launch_bounds__(256) void token_scores_kernel(const u16* __restrict__ tq,
                                                           const u16* __restrict__ tk,
                                                           float* __restrict__ tsp) {
  int s = blockIdx.x, b = blockIdx.y;
  const u16* A = tq + (long)b * 64 * NTD;
  const u16* B = tk + (long)b * 64 * NTD;
  __shared__ __align__(16) u16 As[3 * 2048];
  __shared__ __align__(16) u16 Bs[3 * 2048];
  int tid = threadIdx.x, lane = tid & 63, w = tid >> 6;
  int l15 = lane & 15, quad = lane >> 4;
  f32x4 acc[4] = {};
  const int r = tid >> 2;
  const int cs = (((tid & 3) ^ ((r >> 1) & 3)) << 3);
  const u16* pa = A + (long)r * NTD + cs;
  const u16* pbp = B + (long)r * NTD + cs;
  const int lb = (tid & ~63) * 8;

  auto stage = [&](int ch, int bi) {
    async_cp16(pa + ch * 32, &As[bi + lb]);
    async_cp16(pbp + ch * 32, &Bs[bi + lb]);
  };
  auto compute = [&](int bi) {
    int row = w * 16 + l15;
    bf16x8 av = *(const bf16x8*)&As[bi + row * 32 + ((quad ^ ((row >> 1) & 3)) << 3)];
#pragma unroll
    for (int j = 0; j < 4; j++) {
      int rb = j * 16 + l15;
      bf16x8 bv = *(const bf16x8*)&Bs[bi + rb * 32 + ((quad ^ ((rb >> 1) & 3)) << 3)];
      acc[j] = __builtin_amdgcn_mfma_f32_16x16x32_bf16(av, bv, acc[j], 0, 0, 0);
    }
  };

  int ch0 = s * 6, nch = (s == 7) ? 7 : 6;
  stage(ch0, 0);
  stage(ch0 + 1, 2048);
  for (int c = 0; c < nch; c++) {
    if (c + 1 < nch) {
      asm volatile("s_waitcnt vmcnt(2)" ::: "memory");
    } else {
      asm volatile("s_waitcnt vmcnt(0)" ::: "memory");
    }
    __builtin_amdgcn_s_barrier();
    if (c + 2 < nch) stage(ch0 + c + 2, ((c + 2) % 3) * 2048);
    compute((c % 3) * 2048);
  }
  if (s == 7) {  // 8-element K tail at k=1568
    const int tb = (nch % 3) * 2048;
    __syncthreads();
    for (int idx = tid; idx < 2048; idx += 256) {
      int rr = idx >> 5, cc = idx & 31;
      int g = ((((cc >> 3) ^ ((rr >> 1) & 3)) << 3)) | (cc & 7);
      As[tb + idx] = (g < 8) ? A[(long)rr * NTD + 1568 + g] : (u16)0;
      Bs[tb + idx] = (g < 8) ? B[(long)rr * NTD + 1568 + g] : (u16)0;
    }
    __syncthreads();
    compute(tb);
  }
  const float sc = rsqrtf(1576.f);
  float* dst = tsp + ((long)(s * 8 + b)) * 4096;
#pragma unroll
  for (int j = 0; j < 4; j++)
#pragma unroll
    for (int reg = 0; reg < 4; reg++) {
      int row = w * 16 + quad * 4 + reg, col = j * 16 + l15;
      dst[row * 64 + col] = acc[j][reg] * sc;
    }
}

// ---------------------------------------------------------------------------
// Spatial softmax: sums 2 split-K partials s[0],s[1] (each 64x197x197 fp32)
// -> pb bf16 (64,197,208). 4 rows/block; row cached in registers.
__global__ void softmax_spatial_kernel(const float* __restrict__ s, u16* __restrict__ pb) {
  int row = blockIdx.x * 4 + (threadIdx.x >> 6);
  int lane = threadIdx.x & 63;
  const float* p0 = s + (long)row * 197;
  const float* p1 = p0 + 2483776;
  int hb = row / 197, mm = row - hb * 197;
  u16* q = pb + (long)hb * 197 * MP + (long)mm * MP;
  float vv[4];
  float mx = -INFINITY;
  int cnt = 0;
  for (int j = lane; j < 197; j += 64) {
    vv[cnt] = p0[j] + p1[j];
    mx = fmaxf(mx, vv[cnt]);
    cnt++;
  }
#pragma unroll
  for (int off = 32; off; off >>= 1) mx = fmaxf(mx, __shfl_xor(mx, off));
  float sum = 0.f;
  for (int i = 0; i < cnt; i++) { vv[i] = expf(vv[i] - mx); sum += vv[i]; }
#pragma unroll
  for (int off = 32; off; off >>= 1) sum += __shfl_xor(sum, off);
  float inv = 1.f / sum;
  cnt = 0;
  for (int j = lane; j < 197; j += 64) { q[j] = f2bf(vv[cnt] * inv); cnt++; }
}

// Token softmax: sums 8 split-K partials, softmaxes, writes Pb bf16.
__global__ void softmax_token_kernel(const float* __restrict__ tsp, u16* __restrict__ Pb) {
  int row = blockIdx.x * 4 + (threadIdx.x >> 6);  // 0..511 = b*64+r
  int lane = threadIdx.x & 63;
  int b = row >> 6, r = row & 63;
  float v = 0.f;
#pragma unroll
  for (int p = 0; p < 8; p++) v += tsp[((long)(p * 8 + b)) * 4096 + r * 64 + lane];
  float mx = v;
#pragma unroll
  for (int off = 32; off; off >>= 1) mx = fmaxf(mx, __shfl_xor(mx, off));
  float e = expf(v - mx);
  float sum = e;
#pragma unroll
  for (int off = 32; off; off >>= 1) sum += __shfl_xor(sum, off);
  Pb[(long)row * 64 + lane] = f2bf(e / sum);
}

// ---------------------------------------------------------------------------
// Attn output reduce + residual, vectorized x4; fused per-batch sum(x^2).
// grid 788 x 256. A block (1024 elems) may straddle ONE batch boundary ->
// segmented 2-slot reduce.
__global__ void attn_reduce_kernel(const float* __restrict__ part, const float* __restrict__ bias,
                                   const float* __restrict__ resid, float* __restrict__ x,
                                   float* __restrict__ sqslot) {
  int idx4 = blockIdx.x * 256 + threadIdx.x;
  long base = (long)idx4 * 4;
  int col = (int)(base % ND);
  float4 sv = *(const float4*)(bias + col);
  float4 rv = ((const float4*)resid)[idx4];
  sv.x += rv.x; sv.y += rv.y; sv.z += rv.z; sv.w += rv.w;
#pragma unroll
  for (int h = 0; h < 8; h++) {
    float4 pv = ((const float4*)part)[(h * (XSZ >> 2)) + idx4];
    sv.x += pv.x; sv.y += pv.y; sv.z += pv.z; sv.w += pv.w;
  }
  ((float4*)x)[idx4] = sv;
  float ssq = sv.x * sv.x + sv.y * sv.y + sv.z * sv.z + sv.w * sv.w;
  int b = (int)(base / BMD);
  int bfirst = (int)(((long)blockIdx.x * 1024) / BMD);
  float s0 = (b == bfirst) ? ssq : 0.f;
  float s1 = ssq - s0;
  __shared__ float red0[256], red1[256];
  red0[threadIdx.x] = s0; red1[threadIdx.x] = s1; __syncthreads();
  for (int o = 128; o; o >>= 1) {
    if (threadIdx.x < o) {
      red0[threadIdx.x] += red0[threadIdx.x + o];
      red1[threadIdx.x] += red1[threadIdx.x + o];
    }
    __syncthreads();
  }
  if (threadIdx.x == 0) {
    atomicAdd(&sqslot[bfirst], red0[0]);
    if (red1[0] != 0.f) atomicAdd(&sqslot[bfirst + 1], red1[0]);
  }
}

// ---------------------------------------------------------------------------
// Merged transposes: Wqkv (48 slabs, z = l*24 + w*8 + h) + attn_W (16 slabs:
// z-48 = l*8 + i) + patch_W (z=64). grid (16,24,65); z<64 uses by<16 only.
__global__ void transpose_wa_kernel(const float* __restrict__ Wq, const float* __restrict__ Wk,
                                    const float* __restrict__ Wv, const float* __restrict__ attn_W,
                                    const float* __restrict__ patch_W,
                                    u16* __restrict__ Wt16, u16* __restrict__ Wat16,
                                    u16* __restrict__ pWt) {
  int z = blockIdx.z;
  __shared__ float t[32][33];
  int c0 = blockIdx.x * 32, r0 = blockIdx.y * 32;
  int tx = threadIdx.x, ty = threadIdx.y;
  if (z == 64) {
    // patch_W fp32 (768x512) -> pWt bf16 (512x768); r0<768, c0<512, exact tiles
#pragma unroll
    for (int i = 0; i < 4; i++)
      t[ty + i * 8][tx] = patch_W[(long)(r0 + ty + i * 8) * 512 + c0 + tx];
    __syncthreads();
#pragma unroll
    for (int i = 0; i < 4; i++)
      pWt[(long)(c0 + ty + i * 8) * 768 + r0 + tx] = f2bf(t[tx][ty + i * 8]);
    return;
  }
  if (blockIdx.y >= 16) return;
  const float* src;
  u16* dst;
  long dld;
  if (z < 48) {
    int l = z / 24, rem = z - l * 24, w = rem >> 3, h = rem & 7;
    src = (w == 0 ? Wq : w == 1 ? Wk : Wv) + (long)(l * 8 + h) * 262144;
    dst = Wt16 + (long)z * 262144;
    dld = 512;
  } else {
    int za = z - 48, l = za >> 3, i = za & 7;   // 8 row-blocks per layer
    src = attn_W + (long)l * 4096 * 512 + (long)i * 512 * 512;
    dst = Wat16 + (long)l * 512 * 4096 + (long)i * 512;
    dld = 4096;
  }
#pragma unroll
  for (int i = 0; i < 4; i++)
    t[ty + i * 8][tx] = src[(long)(r0 + ty + i * 8) * 512 + c0 + tx];
  __syncthreads();
#pragma unroll
  for (int i = 0; i < 4; i++)
    dst[(long)(c0 + ty + i * 8) * dld + r0 + tx] = f2bf(t[tx][ty + i * 8]);
}

// Merged tWq/tWk/tWv transpose: grid (50,50,6), z = w*2 + l.
__global__ void t_transpose3_kernel(const float* __restrict__ Wq, const float* __restrict__ Wk,
                                    const float* __restrict__ Wv, u16* __restrict__ dst0) {
  int z = blockIdx.z;
  int w = z >> 1, l = z & 1;
  const float* src = (w == 0 ? Wq : w == 1 ? Wk : Wv) + (long)l * NTD * NTD;
  u16* d = dst0 + (long)z * NTD * NTD;
  __shared__ float t[32][33];
  int c0 = blockIdx.x * 32, r0 = blockIdx.y * 32;
  int tx = threadIdx.x, ty = threadIdx.y;
#pragma unroll
  for (int i = 0; i < 4; i++) {
    int r = r0 + ty + i * 8;
    if (r < NTD && c0 + tx < NTD) t[ty + i * 8][tx] = src[(long)r * NTD + c0 + tx];
  }
  __syncthreads();
#pragma unroll
  for (int i = 0; i < 4; i++) {
    int c = c0 + ty + i * 8;
    if (c < NTD && r0 + tx < NTD) d[(long)c * NTD + r0 + tx] = f2bf(t[tx][ty + i * 8]);
  }
}

// ---------------------------------------------------------------------------
// Fused cls LayerNorm + head GEMM. grid (4,8), 256 thr (LN redone per block).
__global__ void ln_head_kernel(const float* __restrict__ x, const float* __restrict__ g,
                               const float* __restrict__ bb, const float* __restrict__ W,
                               const float* __restrict__ hb, float* __restrict__ out) {
  int b = blockIdx.y, t = threadIdx.x;
  __shared__ float xs[512];
  __shared__ float red[256];
  float v0 = x[(long)b * NM * ND + t];
  float v1 = x[(long)b * NM * ND + 256 + t];
  red[t] = v0 + v1; __syncthreads();
  for (int o = 128; o; o >>= 1) { if (t < o) red[t] += red[t + o]; __syncthreads(); }
  float mu = red[0] / 512.f; __syncthreads();
  float d0 = v0 - mu, d1 = v1 - mu;
  red[t] = d0 * d0 + d1 * d1; __syncthreads();
  for (int o = 128; o; o >>= 1) { if (t < o) red[t] += red[t + o]; __syncthreads(); }
  float inv = rsqrtf(red[0] / 512.f + 1e-5f); __syncthreads();
  xs[t] = d0 * inv * g[t] + bb[t];
  xs[256 + t] = d1 * inv * g[256 + t] + bb[256 + t];
  __syncthreads();
  int n = blockIdx.x * 250 + t;
  if (t < 250 && n < 1000) {
    float acc = hb[n];
    for (int dd = 0; dd < 512; dd++) acc += xs[dd] * W[(long)dd * 1000 + n];
    out[(long)b * 1000 + n] = acc;
  }
}

}  // namespace

extern "C" void kernel_launch(void* const* d_in, const int* in_sizes, int n_in,
                              void* d_out, int out_size, void* d_ws, size_t ws_size,
                              hipStream_t stream) {
  const float* img     = (const float*)d_in[0];
  const float* patch_W = (const float*)d_in[1];
  const float* patch_b = (const float*)d_in[2];
  const float* cls_tok = (const float*)d_in[3];
  const float* rms_s   = (const float*)d_in[4];
  const float* Wq      = (const float*)d_in[5];
  const float* Wk      = (const float*)d_in[6];
  const float* Wv      = (const float*)d_in[7];
  const float* attn_W  = (const float*)d_in[8];
  const float* attn_b  = (const float*)d_in[9];
  const float* tWq     = (const float*)d_in[10];
  const float* tWk     = (const float*)d_in[11];
  const float* tWv     = (const float*)d_in[12];
  const float* ln_g    = (const float*)d_in[13];
  const float* ln_b    = (const float*)d_in[14];
  const float* head_W  = (const float*)d_in[15];
  const float* head_b  = (const float*)d_in[16];
  float* out = (float*)d_out;

  // ---- workspace layout (floats) ----
  float* base = (float*)d_ws;
  long off = 0;
  auto alloc = [&](long n) { float* r = base + off; off += (n + 15) & ~15L; return r; };
  float* cosP = alloc(TABSZ);       // interleaved (cos,sin) float2 table spans
  float* sinP = alloc(TABSZ);       //   cosP..sinP (2*TABSZ floats contiguous)
  float* cosT = alloc(TABSZ);
  float* sinT = alloc(TABSZ);
  float* x    = alloc(XSZ);
  float* xn   = alloc(XSZ);
  float* Wt_f   = alloc(6291456);   // 48 slabs 512x512 bf16, z = l*24+w*8+h
  float* Wat_f  = alloc(2097152);   // (l) 512x4096 bf16
  float* tWt_f  = alloc(7451328);   // (w,l) 1576x1576 bf16
  float* xnb_f  = alloc(XSZ / 2);
  float* pimg_f = alloc(602112);    // 1568x768 bf16
  float* pWt_f  = alloc(196608);    // 512x768 bf16
  float* U      = alloc(16885824);  // union region
  float* ffs    = alloc(64);        // fused sq-sum slots:
                                    //   [0..7]=attn l0, [8..15]=tok l0,
                                    //   [16..23]=attn l1, [24..31]=tok l1 (dead),
                                    //   [32..39]=patch embed (layer-0 RMS)

  u16* Wt16  = (u16*)Wt_f;
  u16* Wat16 = (u16*)Wat_f;
  u16* tWt16 = (u16*)tWt_f;
  u16* xnb   = (u16*)xnb_f;
  u16* pimg  = (u16*)pimg_f;
  u16* pWt   = (u16*)pWt_f;
  // patch split-K partials: 3 x 1568*512 fp32 in U (dead until qkv writes q)
  float* patchp = (float*)U;
  // phase A overlay (contract: kk = q + QSZ, vt = q + 2*QSZ)
  u16* q   = (u16*)U;                 // 6455296 (h, b*m, e)
  u16* kk  = q + QSZ;                 // 6455296
  u16* vt  = kk + QSZ;                // 6815744 (h,b,e,m_pad)
  float* s = (float*)(vt + 6815744);  // 2x 2483776 f split-K score partials
  u16* pb  = (u16*)(s + 2 * 2483776); // 2622464 (hb,197,208)
  u16* o   = (u16*)s;                 // 6455296 (aliases dead s after softmax)
  float* part = (float*)q;            // 8*XSZ fp32 (aliases dead q,kk)
  // phase B overlay (contract: tkb = tqb + XSZ, tvt = tqb + 2*XSZ)
  u16* yb     = (u16*)U;              // 806912 (b*64+c, 1576)
  float* tprt = (float*)(yb + XSZ);   // 12*XSZ fp32 split partials
  u16* tqb    = (u16*)(tprt + 12 * XSZ);
  u16* tvt    = tqb + 2 * XSZ;        // (b, 1576, 64)
  float* tsp  = (float*)(tvt + XSZ);  // 8 x 8 x 64 x 64
  u16* Pb     = (u16*)(tsp + 262144); // 8*64*64

  const float rs512 = 1.f / sqrtf(512.f);
  const dim3 tt(32, 8);

  // ---- setup ----
  init_kernel<<<5115, 256, 0, stream>>>(img, cls_tok, cosP, sinP, cosT, sinT, pimg, x, ffs);
  transpose_wa_kernel<<<dim3(16, 24, 65), tt, 0, stream>>>(
      Wq, Wk, Wv, attn_W, patch_W, Wt16, Wat16, pWt);
  t_transpose3_kernel<<<dim3(50, 50, 6), tt, 0, stream>>>(tWq, tWk, tWv, tWt16);
  // patch embed, 3-way split-K (K=256 each), fp32 partials -> patchp
  mfma_gemm<EPI_F32><<<dim3(4, 13, 3), 512, 0, stream>>>(
      pimg, pWt, patchp, nullptr, nullptr, 1568, 512, 256, 768, 768, 512, 1.f, 1,
      256, 0, 256, 0, 802816L, 0);
  // reduce partials + bias -> x; fused per-batch ssq (+cls row) -> ffs[32..39]
  patch_reduce_kernel<<<785, 256, 0, stream>>>(patchp, patch_b, cls_tok, x, ffs + 32);

  for (int l = 0; l < 2; l++) {
    const float* scale = rms_s + (long)l * NM * ND;
    float* slotA = ffs + l * 16;       // attn-phase sq-sums for this layer
    float* slotT = ffs + l * 16 + 8;   // token-phase sq-sums for this layer
    // ---- spatial attention ----
    // sq-sums pre-accumulated: patch_reduce (l=0) / previous token-PV (l=1)
    rms_apply_kernel<<<788, 256, 0, stream>>>(
        x, scale, (l == 0) ? ffs + 32 : ffs + 8, 1, xn, xnb);

    // qkv with fused RoPE on q,k
    qkv_kernel<<<dim3(4, 13, 24), 512, 0, stream>>>(xnb, Wt16 + (long)l * 24 * 262144, q, cosP);

    // scores, 2-way split-K (fp32 partials, scaled)
    mfma_gemm<EPI_F32><<<dim3(2, 2, 128), 512, 0, stream>>>(
        q, kk, s, nullptr, nullptr, 197, 197, 256, 512, 512, 197, rs512, 64,
        256, 197L * 512, 256, 197L * 512, 2483776, 197L * 197);
    softmax_spatial_kernel<<<3152, 256, 0, stream>>>(s, pb);
    // o = P @ v   (o aliases the now-dead s region)
    mfma_gemm<EPI_BF16><<<dim3(4, 2, 64), 512, 0, stream>>>(
        pb, vt, o, nullptr, nullptr, 197, 512, 197, MP, MP, 512, 1.f, 64,
        0, 197L * MP, 0, 512L * MP, 0, 197L * 512);
    // attn-proj head partials
    mfma_gemm<EPI_F32><<<dim3(4, 13, 8), 512, 0, stream>>>(
        o, Wat16 + (long)l * 2097152, part, nullptr, nullptr, 1576, 512, 512, 512, 4096, 512,
        1.f, 8, 0, XSZ, 0, 512, 0, XSZ);
    // reduce + residual + fused sum(x^2) into slotA
    attn_reduce_kernel<<<788, 256, 0, stream>>>(part, attn_b + (long)l * ND, xn, x, slotA);

    // ---- token mixing ----
    rms_apply_tok_kernel<<<788, 256, 0, stream>>>(x, scale, slotA, 1, xn, yb);

    // 4-way K split (624 blocks)
    tok_qkv_kernel<<<dim3(4, 13, 12), 512, 0, stream>>>(yb, tWt16, l, tprt);
    token_finish_kernel<<<1576, 256, 0, stream>>>(tprt, cosT, sinT, tqb);

    token_scores_kernel<<<dim3(8, 8), 256, 0, stream>>>(tqb, tqb + XSZ, tsp);
    softmax_token_kernel<<<128, 256, 0, stream>>>(tsp, Pb);
    // token PV: scatter + residual into fp32 x; fused sum(x^2) into slotT
    mfma_gemm<EPI_TOKPV><<<dim3(13, 1, 8), 512, 0, stream>>>(
        Pb, tvt, x, xn, slotT, 64, 1576, 64, 64, 64, 0, 1.f, 8,
        0, 4096, 0, 1576L * 64, 0, 0);
  }

  ln_head_kernel<<<dim3(4, 8), 256, 0, stream>>>(x, ln_g, ln_b, head_W, head_b, out);
}

// Round 9
// 612.734 us; speedup vs baseline: 1.2378x; 1.0025x over previous
//
#include <hip/hip_runtime.h>
#include <math.h>

// B=8, m=197, dim=512, heads=8, depth=2, F=8, tdim=1576, cdim=64, ncls=1000.
namespace {

typedef unsigned short u16;
typedef __attribute__((ext_vector_type(8))) short bf16x8;
typedef __attribute__((ext_vector_type(4))) float f32x4;
typedef __attribute__((ext_vector_type(4))) unsigned short u16x4;
typedef __attribute__((ext_vector_type(2))) unsigned short u16x2;

constexpr int NB = 8, NM = 197, ND = 512, NH = 8, NTD = 1576, NC = 64;
constexpr long XSZ = (long)NB * NM * ND;        // 806912
constexpr long QSZ = (long)NH * XSZ;            // 6455296 (h, b*m, e)
constexpr long TABSZ = 50432;                   // 197*256 == 64*788
constexpr int MP = 208;                         // padded 197 (16B-aligned bf16 rows)
constexpr int BMD = NM * ND;                    // 100864 per-batch elems

__device__ __forceinline__ u16 f2bf(float f) {
  union { float f; unsigned u; } v; v.f = f;
  unsigned r = v.u + 0x7FFF + ((v.u >> 16) & 1);
  return (u16)(r >> 16);
}
__device__ __forceinline__ void async_cp16(const void* g, void* l) {
  __builtin_amdgcn_global_load_lds((const __attribute__((address_space(1))) unsigned*)g,
                                   (__attribute__((address_space(3))) unsigned*)l, 16, 0, 0);
}

// Bijective XCD-chunk swizzle (m204).
__device__ __forceinline__ int xcd_swz(int orig, int nwg) {
  int q = nwg >> 3, r = nwg & 7, x = orig & 7, i = orig >> 3;
  return (x < r ? x * (q + 1) : r * (q + 1) + (x - r) * q) + i;
}
__device__ __forceinline__ int swz_flat() {
  int nwg = gridDim.x * gridDim.y * gridDim.z;
  int orig = blockIdx.x + gridDim.x * (blockIdx.y + gridDim.y * blockIdx.z);
  return xcd_swz(orig, nwg);
}

// ---------------------------------------------------------------------------
// Shared MFMA GEMM core: acc += A(M x KL) * B^T(N x KL), 128x128 tile, BK=32.
// 512 threads / 8 waves (2 M-tiles x 4 N-tiles), acc[4][2] per wave.
// Depth-2 prefetch: 3-slot LDS ring, raw s_barrier + counted vmcnt(2).
__device__ __forceinline__ void gemm_core(
    const u16* __restrict__ A, int lda, int M, int row0,
    const u16* __restrict__ B, int ldb, int N, int col0,
    int KL, u16* As, u16* Bs, f32x4 (&acc)[4][2],
    int tid, int wm, int wn, int l15, int quad) {
  const int nfull = KL >> 5, tail = KL & 31;
  const int r = tid >> 2;                      // 0..127 (512 threads)
  const int cs = (((tid & 3) ^ ((r >> 1) & 3)) << 3);
  int gr0 = row0 + r; if (gr0 >= M) gr0 = M - 1;
  int gc0 = col0 + r; if (gc0 >= N) gc0 = N - 1;
  const u16* pa0 = A + (long)gr0 * lda + cs;
  const u16* pb0 = B + (long)gc0 * ldb + cs;
  const int lb0 = (tid & ~63) * 8;             // wave wv -> wv*512 u16

  auto stage = [&](int k0, int bi) {
    async_cp16(pa0 + k0, &As[bi + lb0]);
    async_cp16(pb0 + k0, &Bs[bi + lb0]);
  };
  auto compute = [&](int bi) {
    bf16x8 af[4], bg[2];
#pragma unroll
    for (int i = 0; i < 4; i++) {
      int row = wm * 64 + i * 16 + l15;
      af[i] = *(const bf16x8*)&As[bi + row * 32 + ((quad ^ ((row >> 1) & 3)) << 3)];
    }
#pragma unroll
    for (int j = 0; j < 2; j++) {
      int row = wn * 32 + j * 16 + l15;
      bg[j] = *(const bf16x8*)&Bs[bi + row * 32 + ((quad ^ ((row >> 1) & 3)) << 3)];
    }
#pragma unroll
    for (int i = 0; i < 4; i++)
#pragma unroll
      for (int j = 0; j < 2; j++)
        acc[i][j] = __builtin_amdgcn_mfma_f32_16x16x32_bf16(af[i], bg[j], acc[i][j], 0, 0, 0);
  };

  if (nfull > 0) {
    stage(0, 0);
    if (nfull > 1) stage(32, 4096);
    for (int ch = 0; ch < nfull; ch++) {
      if (ch + 1 < nfull) {
        asm volatile("s_waitcnt vmcnt(2)" ::: "memory");
      } else {
        asm volatile("s_waitcnt vmcnt(0)" ::: "memory");
      }
      __builtin_amdgcn_s_barrier();
      if (ch + 2 < nfull) stage((ch + 2) << 5, ((ch + 2) % 3) * 4096);
      compute((ch % 3) * 4096);
    }
  }
  if (tail) {
    const int tb = (nfull % 3) * 4096;
    const int k0f = nfull << 5;
    if (nfull > 0) __syncthreads();
    for (int idx2 = tid; idx2 < 4096; idx2 += 512) {
      int rr = idx2 >> 5, cc = idx2 & 31;
      int g = ((((cc >> 3) ^ ((rr >> 1) & 3)) << 3)) | (cc & 7);
      int grr = row0 + rr; if (grr >= M) grr = M - 1;
      int gcc = col0 + rr; if (gcc >= N) gcc = N - 1;
      As[tb + idx2] = (g < tail) ? A[(long)grr * lda + k0f + g] : (u16)0;
      Bs[tb + idx2] = (g < tail) ? B[(long)gcc * ldb + k0f + g] : (u16)0;
    }
    __syncthreads();
    compute(tb);
  }
}

// ---------------------------------------------------------------------------
// init: RoPE tables + patch gather + cls fill + zero sq-sum slots. One launch.
// grid 5115 x 256. Spatial table is INTERLEAVED (cos,sin) float2 in cosP.
__global__ void init_kernel(const float* __restrict__ img, const float* __restrict__ cls,
                            float* cosP, float* sinP, float* cosT, float* sinT,
                            u16* __restrict__ pimg, float* __restrict__ x,
                            float* __restrict__ ffs) {
  long idx = (long)blockIdx.x * 256 + threadIdx.x;
  if (idx < 197 * 256) {
    int p = (int)(idx / 256), i = (int)(idx % 256);
    float theta = powf(10000.f, -2.f * ((float)i - 1.f) / 512.f);
    float a = (float)p * theta;
    cosP[2 * idx] = cosf(a); cosP[2 * idx + 1] = sinf(a);
    return;
  }
  long j = idx - 197 * 256;
  if (j < 64 * 788) {
    int p = (int)(j / 788), i = (int)(j % 788);
    float theta = powf(10000.f, -2.f * ((float)i - 1.f) / 1576.f);
    float a = (float)p * theta;
    cosT[j] = cosf(a); sinT[j] = sinf(a);
    return;
  }
  long k2 = j - 64 * 788;
  if (k2 < 1568L * 768) {
    int r = (int)(k2 / 768), k = (int)(k2 % 768);
    int b = r / 196, p = r - b * 196;
    int pi = p / 14, pj = p - pi * 14;
    int cc = k % 3, pq = k / 3, pp = pq >> 4, qq = pq & 15;
    pimg[k2] = f2bf(img[((long)(b * 3 + cc) * 224 + pi * 16 + pp) * 224 + pj * 16 + qq]);
    return;
  }
  long c2 = k2 - 1568L * 768;
  if (c2 < 8 * 512) {
    int b = (int)(c2 >> 9), e = (int)(c2 & 511);
    x[((long)b * NM) * ND + e] = cls[e];
    return;
  }
  long c3 = c2 - 8 * 512;
  if (c3 < 64) ffs[c3] = 0.f;   // zero all fused sq-sum slots (incl. patch @32)
}

// np=8: sum 8 partials per batch; np=1: single pre-accumulated float.
__device__ __forceinline__ float rms_inv(const float* part, int b, int np) {
  float ssum = 0.f;
  if (np == 8) {
#pragma unroll
    for (int i = 0; i < 8; i++) ssum += part[b * 8 + i];
  } else {
    ssum = part[b];
  }
  return sqrtf((float)(NM * ND) / ssum);
}

// Vectorized x4: grid 788 x 256 (XSZ/4 = 201728 float4 threads).
__global__ void rms_apply_kernel(const float* __restrict__ x, const float* __restrict__ scale,
                                 const float* __restrict__ part, int np, float* __restrict__ xn,
                                 u16* __restrict__ xnb) {
  int idx4 = blockIdx.x * 256 + threadIdx.x;
  int b = idx4 / (BMD / 4);
  int md4 = idx4 - b * (BMD / 4);
  float ri = rms_inv(part, b, np);
  float4 xv = ((const float4*)x)[idx4];
  float4 sv = ((const float4*)(scale))[md4];
  float4 v;
  v.x = xv.x * sv.x * ri; v.y = xv.y * sv.y * ri;
  v.z = xv.z * sv.z * ri; v.w = xv.w * sv.w * ri;
  ((float4*)xn)[idx4] = v;
  u16x4 h = { f2bf(v.x), f2bf(v.y), f2bf(v.z), f2bf(v.w) };
  ((u16x4*)xnb)[idx4] = h;
}

// Phase-B vectorized: writes xn and permuted yb[(b*64+c)*1576 + f*197+mm].
__global__ void rms_apply_tok_kernel(const float* __restrict__ x, const float* __restrict__ scale,
                                     const float* __restrict__ part, int np, float* __restrict__ xn,
                                     u16* __restrict__ yb) {
  int idx4 = blockIdx.x * 256 + threadIdx.x;
  int b = idx4 / (BMD / 4);
  int md4 = idx4 - b * (BMD / 4);
  float ri = rms_inv(part, b, np);
  float4 xv = ((const float4*)x)[idx4];
  float4 sv = ((const float4*)(scale))[md4];
  float4 v;
  v.x = xv.x * sv.x * ri; v.y = xv.y * sv.y * ri;
  v.z = xv.z * sv.z * ri; v.w = xv.w * sv.w * ri;
  ((float4*)xn)[idx4] = v;
  int md = md4 * 4;
  int mm = md / ND, d0 = md - mm * ND;     // d0 % 4 == 0
  int c = d0 >> 3, f0 = d0 & 7;            // f0 in {0,4}; f = f0..f0+3
  u16* row = yb + ((long)b * 64 + c) * NTD + mm;
  row[(f0 + 0) * 197] = f2bf(v.x);
  row[(f0 + 1) * 197] = f2bf(v.y);
  row[(f0 + 2) * 197] = f2bf(v.z);
  row[(f0 + 3) * 197] = f2bf(v.w);
}

// ---------------------------------------------------------------------------
// Patch split-K reduce: x[b][1+p][col] = sum of 3 partials + bias; fused
// per-batch sum(x^2) into sq[b] (plus cls-row ssq via the extra block 784).
// grid 785 x 256. 98 blocks per batch exactly (196*512/1024) -> no straddle.
__global__ void patch_reduce_kernel(const float* __restrict__ pp, const float* __restrict__ bias,
                                    const float* __restrict__ cls, float* __restrict__ x,
                                    float* __restrict__ sq) {
  __shared__ float red[256];
  int t = threadIdx.x;
  if (blockIdx.x == 784) {   // cls ssq, identical for all batches
    float v0 = cls[t], v1 = cls[256 + t];
    red[t] = v0 * v0 + v1 * v1; __syncthreads();
    for (int o = 128; o; o >>= 1) {
      if (t < o) red[t] += red[t + o];
      __syncthreads();
    }
    if (t < 8) atomicAdd(&sq[t], red[0]);
    return;
  }
  int idx4 = blockIdx.x * 256 + t;
  long e0 = (long)idx4 * 4;
  int prow = (int)(e0 >> 9), col = (int)(e0 & 511);
  int b = prow / 196, p = prow - b * 196;
  float4 s0 = ((const float4*)pp)[idx4];
  float4 s1 = ((const float4*)pp)[200704 + idx4];
  float4 s2 = ((const float4*)pp)[401408 + idx4];
  float4 bv = *(const float4*)(bias + col);
  float4 r;
  r.x = s0.x + s1.x + s2.x + bv.x;
  r.y = s0.y + s1.y + s2.y + bv.y;
  r.z = s0.z + s1.z + s2.z + bv.z;
  r.w = s0.w + s1.w + s2.w + bv.w;
  *(float4*)(x + ((long)(b * 197 + 1 + p) * 512 + col)) = r;
  red[t] = r.x * r.x + r.y * r.y + r.z * r.z + r.w * r.w;
  __syncthreads();
  for (int o = 128; o; o >>= 1) {
    if (t < o) red[t] += red[t + o];
    __syncthreads();
  }
  if (t == 0) atomicAdd(&sq[blockIdx.x / 98], red[0]);
}

// ---------------------------------------------------------------------------
// Spatial QKV, one launch. grid (4,13,24) x 512 thr, z = w*8+h (after swizzle).
// w<2: q/k = xnb(1576x512) @ Wslab^T -> (h,b*m,e), RoPE fused in epilogue.
// w=2: v^T = Wv^T(512x512) @ xnb^T -> vt (h,b,e,m_pad).
__global__ __launch_bounds__(512) void qkv_kernel(const u16* __restrict__ xnb,
                                                  const u16* __restrict__ WtL,
                                                  u16* __restrict__ q,
                                                  const float* __restrict__ csP) {
  int wg = swz_flat();
  int bx = wg & 3, tmp = wg >> 2;
  int by = tmp % 13, bz = tmp / 13;
  int w = bz >> 3, h = bz & 7;
  __shared__ __align__(16) u16 As[3 * 4096];
  __shared__ __align__(16) u16 Bs[3 * 4096];
  const int tid = threadIdx.x;
  const int lane = tid & 63, wave = tid >> 6;
  const int wm = wave >> 2, wn = wave & 3;
  const int l15 = lane & 15, quad = lane >> 4;
  f32x4 acc[4][2] = {};

  if (w < 2) {
    int row0 = by * 128, col0 = bx * 128;
    const u16* B = WtL + ((long)(w * 8 + h)) * 262144;
    gemm_core(xnb, 512, 1576, row0, B, 512, 512, col0, 512, As, Bs, acc,
              tid, wm, wn, l15, quad);
    long base = (long)w * QSZ + (long)h * XSZ;
    const float2* cs2 = (const float2*)csP;
#pragma unroll
    for (int i = 0; i < 4; i++)
#pragma unroll
      for (int j = 0; j < 2; j++)
#pragma unroll
        for (int reg = 0; reg < 4; reg++) {
          int gr = row0 + wm * 64 + i * 16 + quad * 4 + reg;
          int gc = col0 + wn * 32 + j * 16 + l15;
          float v = acc[i][j][reg];
          float p = __shfl_xor(v, 1);            // all lanes execute (guard below)
          int t = gr % 197;                      // token index (bogus rows unused)
          float2 cs = cs2[t * 256 + (gc >> 1)];
          float outv = v * cs.x + ((gc & 1) ? -p * cs.y : p * cs.y);
          if (gr < 1576)
            q[base + (long)gr * 512 + gc] = f2bf(outv);
        }
  } else {
    int row0 = bx * 128, col0 = by * 128;
    const u16* A = WtL + ((long)(16 + h)) * 262144;
    gemm_core(A, 512, 512, row0, xnb, 512, 1576, col0, 512, As, Bs, acc,
              tid, wm, wn, l15, quad);
#pragma unroll
    for (int i = 0; i < 4; i++)
#pragma unroll
      for (int j = 0; j < 2; j++)
#pragma unroll
        for (int reg = 0; reg < 4; reg++) {
          int gr = row0 + wm * 64 + i * 16 + quad * 4 + reg;  // e
          int gc = col0 + wn * 32 + j * 16 + l15;             // b*197+mm
          if (gr < 512 && gc < 1576) {
            int b = gc / 197, mm = gc - b * 197;
            q[2 * QSZ + ((long)(h * 8 + b) * 512 + gr) * MP + mm] = f2bf(acc[i][j][reg]);
          }
        }
  }
}

// ---------------------------------------------------------------------------
// Fused spatial scores + softmax. grid (2, 64) x 512 thr, z = h*8+b.
// Tile 128(M) x 256(N) covers ALL 197 cols -> softmax is block-local.
// Same 3-slot ring + counted vmcnt discipline (3 loads/stage: 1 A + 2 B).
// Epilogue: row-max / row-sum via in-lane j-reduce + shfl_xor over l15 +
// 2KB LDS cross-wave (4 N-waves per row); writes pb bf16 directly.
__global__ __launch_bounds__(512) void scores_softmax_kernel(const u16* __restrict__ qq,
                                                             const u16* __restrict__ kk,
                                                             u16* __restrict__ pb) {
  int by = blockIdx.x;         // row half: rows by*128 ..
  int z = blockIdx.y;          // hb = h*8+b
  int h = z >> 3, b = z & 7;
  const u16* A = qq + (long)h * XSZ + (long)b * 197 * 512;
  const u16* B = kk + (long)h * XSZ + (long)b * 197 * 512;
  __shared__ __align__(16) u16 As[3 * 4096];   // 128 x 32 per slot
  __shared__ __align__(16) u16 Bs[3 * 8192];   // 256 x 32 per slot
  const int tid = threadIdx.x;
  const int lane = tid & 63, wave = tid >> 6;
  const int wm = wave >> 2, wn = wave & 3;     // 2 x 4 waves of 64x64
  const int l15 = lane & 15, quad = lane >> 4;
  const int row0 = by * 128;
  f32x4 acc[4][4] = {};

  const int r = tid >> 2;
  const int cs = (((tid & 3) ^ ((r >> 1) & 3)) << 3);
  int ga = row0 + r;  if (ga >= 197) ga = 196;
  int gb1 = r + 128;  if (gb1 >= 197) gb1 = 196;
  const u16* pa = A + (long)ga * 512 + cs;
  const u16* pb0p = B + (long)r * 512 + cs;      // r < 128 < 197
  const u16* pb1p = B + (long)gb1 * 512 + cs;
  const int lb = (tid & ~63) * 8;

  auto stage = [&](int k0, int sa, int sb) {
    async_cp16(pa + k0, &As[sa + lb]);
    async_cp16(pb0p + k0, &Bs[sb + lb]);
    async_cp16(pb1p + k0, &Bs[sb + 4096 + lb]);
  };
  auto compute = [&](int sa, int sb) {
    bf16x8 af[4], bg[4];
#pragma unroll
    for (int i = 0; i < 4; i++) {
      int row = wm * 64 + i * 16 + l15;
      af[i] = *(const bf16x8*)&As[sa + row * 32 + ((quad ^ ((row >> 1) & 3)) << 3)];
    }
#pragma unroll
    for (int j = 0; j < 4; j++) {
      int row = wn * 64 + j * 16 + l15;
      bg[j] = *(const bf16x8*)&Bs[sb + row * 32 + ((quad ^ ((row >> 1) & 3)) << 3)];
    }
#pragma unroll
    for (int i = 0; i < 4; i++)
#pragma unroll
      for (int j = 0; j < 4; j++)
        acc[i][j] = __builtin_amdgcn_mfma_f32_16x16x32_bf16(af[i], bg[j], acc[i][j], 0, 0, 0);
  };

  stage(0, 0, 0);
  stage(32, 4096, 8192);
  for (int ch = 0; ch < 16; ch++) {
    if (ch + 1 < 16) {
      asm volatile("s_waitcnt vmcnt(3)" ::: "memory");
    } else {
      asm volatile("s_waitcnt vmcnt(0)" ::: "memory");
    }
    __builtin_amdgcn_s_barrier();
    if (ch + 2 < 16) stage((ch + 2) << 5, ((ch + 2) % 3) * 4096, ((ch + 2) % 3) * 8192);
    compute((ch % 3) * 4096, (ch % 3) * 8192);
  }

  // ---- block-local softmax epilogue ----
  __syncthreads();                 // drains lgkmcnt; LDS reusable
  float* red = (float*)As;         // [128 rows][4 wn] floats (2KB)
  const float sc = 0.044194173824159216f;  // 1/sqrt(512)

  float pm[4][4];                  // per-(i,reg) row max
#pragma unroll
  for (int i = 0; i < 4; i++)
#pragma unroll
    for (int rg = 0; rg < 4; rg++) {
      float m = -INFINITY;
#pragma unroll
      for (int j = 0; j < 4; j++) {
        int gc = wn * 64 + j * 16 + l15;
        if (gc < 197) m = fmaxf(m, acc[i][j][rg] * sc);
      }
#pragma unroll
      for (int off = 1; off < 16; off <<= 1) m = fmaxf(m, __shfl_xor(m, off));
      pm[i][rg] = m;
    }
  if (l15 == 0) {
#pragma unroll
    for (int i = 0; i < 4; i++)
#pragma unroll
      for (int rg = 0; rg < 4; rg++)
        red[(wm * 64 + i * 16 + quad * 4 + rg) * 4 + wn] = pm[i][rg];
  }
  __syncthreads();
#pragma unroll
  for (int i = 0; i < 4; i++)
#pragma unroll
    for (int rg = 0; rg < 4; rg++) {
      const float* p = &red[(wm * 64 + i * 16 + quad * 4 + rg) * 4];
      pm[i][rg] = fmaxf(fmaxf(p[0], p[1]), fmaxf(p[2], p[3]));
    }
  __syncthreads();                 // before reusing red for sums

  float ps[4][4];
#pragma unroll
  for (int i = 0; i < 4; i++)
#pragma unroll
    for (int rg = 0; rg < 4; rg++) {
      float s = 0.f;
#pragma unroll
      for (int j = 0; j < 4; j++) {
        int gc = wn * 64 + j * 16 + l15;
        float e = 0.f;
        if (gc < 197) e = expf(acc[i][j][rg] * sc - pm[i][rg]);
        acc[i][j][rg] = e;
        s += e;
      }
#pragma unroll
      for (int off = 1; off < 16; off <<= 1) s += __shfl_xor(s, off);
      ps[i][rg] = s;
    }
  if (l15 == 0) {
#pragma unroll
    for (int i = 0; i < 4; i++)
#pragma unroll
      for (int rg = 0; rg < 4; rg++)
        red[(wm * 64 + i * 16 + quad * 4 + rg) * 4 + wn] = ps[i][rg];
  }
  __syncthreads();
#pragma unroll
  for (int i = 0; i < 4; i++)
#pragma unroll
    for (int rg = 0; rg < 4; rg++) {
      const float* p = &red[(wm * 64 + i * 16 + quad * 4 + rg) * 4];
      ps[i][rg] = 1.f / (p[0] + p[1] + p[2] + p[3]);
    }

  u16* dst = pb + (long)z * 197 * MP;
#pragma unroll
  for (int i = 0; i < 4; i++)
#pragma unroll
    for (int rg = 0; rg < 4; rg++) {
      int gr = row0 + wm * 64 + i * 16 + quad * 4 + rg;
      if (gr >= 197) continue;
#pragma unroll
      for (int j = 0; j < 4; j++) {
        int gc = wn * 64 + j * 16 + l15;
        if (gc < 197) dst[(long)gr * MP + gc] = f2bf(acc[i][j][rg] * ps[i][rg]);
      }
    }
}

// ---------------------------------------------------------------------------
// Token QKV, one launch. grid (4,13,12) x 512 thr, XCD-chunked. 4-way K split:
// segs 416/416/416/328 (only last has a BK tail).
__global__ __launch_bounds__(512) void tok_qkv_kernel(const u16* __restrict__ yb,
                                                      const u16* __restrict__ tWt, int l,
                                                      float* __restrict__ tprt) {
  int wg = swz_flat();
  int bx = wg & 3, tmp = wg >> 2;
  int by = tmp % 13, z = tmp / 13;
  __shared__ __align__(16) u16 As[3 * 4096];
  __shared__ __align__(16) u16 Bs[3 * 4096];
  const int tid = threadIdx.x;
  const int lane = tid & 63, wave = tid >> 6;
  const int wm = wave >> 2, wn = wave & 3;
  const int l15 = lane & 15, quad = lane >> 4;
  f32x4 acc[4][2] = {};

  if (z < 8) {
    int w = z >> 2, seg = z & 3;
    int kbeg = seg * 416, KL = (seg < 3) ? 416 : 328;
    int row0 = bx * 128, col0 = by * 128;
    const u16* A = yb + kbeg;
    const u16* B = tWt + ((long)(w * 2 + l)) * 2483776 + kbeg;
    gemm_core(A, 1576, 512, row0, B, 1576, 1576, col0, KL, As, Bs, acc,
              tid, wm, wn, l15, quad);
    float* dst = tprt + (long)z * XSZ;
#pragma unroll
    for (int i = 0; i < 4; i++)
#pragma unroll
      for (int j = 0; j < 2; j++)
#pragma unroll
        for (int reg = 0; reg < 4; reg++) {
          int gr = row0 + wm * 64 + i * 16 + quad * 4 + reg;
          int gc = col0 + wn * 32 + j * 16 + l15;
          if (gr < 512 && gc < 1576) dst[(long)gr * 1576 + gc] = acc[i][j][reg];
        }
  } else {
    int seg = z - 8;
    int kbeg = seg * 416, KL = (seg < 3) ? 416 : 328;
    int row0 = by * 128, col0 = bx * 128;
    const u16* A = tWt + ((long)(4 + l)) * 2483776 + kbeg;
    const u16* B = yb + kbeg;
    gemm_core(A, 1576, 1576, row0, B, 1576, 512, col0, KL, As, Bs, acc,
              tid, wm, wn, l15, quad);
    float* dst = tprt + (long)(8 + seg) * XSZ;
#pragma unroll
    for (int i = 0; i < 4; i++)
#pragma unroll
      for (int j = 0; j < 2; j++)
#pragma unroll
        for (int reg = 0; reg < 4; reg++) {
          int gr = row0 + wm * 64 + i * 16 + quad * 4 + reg;
          int gc = col0 + wn * 32 + j * 16 + l15;
          if (gr < 1576 && gc < 512) dst[(long)gr * 512 + gc] = acc[i][j][reg];
        }
  }
}

// Reduce token split-K partials: rope(tq), rope(tk), transpose(tv) -> bf16.
// tq = slabs 0..3, tk = 4..7, tv = 8..11. Pair-vectorized, grid 1576 x 256.
// tqb layout contract: tkb = tqb + XSZ, tvt = tqb + 2*XSZ.
__global__ void token_finish_kernel(const float* __restrict__ tp,
                                    const float* __restrict__ cosT,
                                    const float* __restrict__ sinT,
                                    u16* __restrict__ tqb) {
  int p2 = blockIdx.x * 256 + threadIdx.x;   // pair index, < XSZ/2
  int r = p2 / 788, gp = p2 - r * 788;       // row, pair-in-row (NTD/2=788)
  int t = r & 63;
  float cv = cosT[(long)t * 788 + gp];
  float sv = sinT[(long)t * 788 + gp];
  const float2* tp2 = (const float2*)tp;
  const long H = XSZ >> 1;                   // float2 elems per slab
  long pr = (long)r * 788 + gp;              // float2 index of the pair
  // tq = sum of 4 seg partials
  float2 a0 = tp2[pr], a1 = tp2[H + pr], a2 = tp2[2 * H + pr], a3 = tp2[3 * H + pr];
  float ve = a0.x + a1.x + a2.x + a3.x, vo = a0.y + a1.y + a2.y + a3.y;
  u16x2 hq = { f2bf(ve * cv + vo * sv), f2bf(-ve * sv + vo * cv) };
  ((u16x2*)tqb)[pr] = hq;
  // tk
  float2 b0 = tp2[4 * H + pr], b1 = tp2[5 * H + pr], b2 = tp2[6 * H + pr], b3 = tp2[7 * H + pr];
  ve = b0.x + b1.x + b2.x + b3.x; vo = b0.y + b1.y + b2.y + b3.y;
  u16x2 hk = { f2bf(ve * cv + vo * sv), f2bf(-ve * sv + vo * cv) };
  ((u16x2*)(tqb + XSZ))[pr] = hk;
  // tv: two consecutive idx = 2*p2, 2*p2+1 in the (1576 x 512) partial layout
  long i0 = (long)p2 * 2;
  int g2 = (int)(i0 >> 9), r2 = (int)(i0 & 511);    // r2 even
  float2 c0 = tp2[8 * H + p2], c1 = tp2[9 * H + p2];
  float2 c2 = tp2[10 * H + p2], c3 = tp2[11 * H + p2];
  u16x2 hv = { f2bf(c0.x + c1.x + c2.x + c3.x), f2bf(c0.y + c1.y + c2.y + c3.y) };
  long vo2 = 2 * XSZ + ((long)(r2 >> 6) * NTD + g2) * 64 + (r2 & 63);
  *(u16x2*)(tqb + vo2) = hv;
}

// ---------------------------------------------------------------------------
// Generic MFMA GEMM for the remaining shapes. 512 thr. XCD-chunked mapping.
// z = z1*nz2 + z2; A += z1*aS1 + z2*aS2 (aS1 enables K-segment split-K).
// EPI_TOKPV additionally accumulates per-batch sum(x^2) into sqout[z2].
enum { EPI_BF16 = 0, EPI_F32 = 1, EPI_TOKPV = 3, EPI_PATCH = 4 };

template <int EPI>
__global__ __launch_bounds__(512) void mfma_gemm(
    const u16* __restrict__ A, const u16* __restrict__ B, void* __restrict__ Cv,
    const float* __restrict__ resid, float* __restrict__ sqout,
    int M, int N, int K, int lda, int ldb, int ldc, float alpha, int nz2,
    long aS1, long aS2, long bS1, long bS2, long cS1, long cS2) {
  int wg = swz_flat();
  int bx = wg % gridDim.x; int tmp = wg / gridDim.x;
  int by = tmp % gridDim.y; int z = tmp / gridDim.y;
  int z1 = z / nz2, z2 = z - z1 * nz2;
  A += z1 * aS1 + z2 * aS2;
  B += z1 * bS1 + z2 * bS2;
  __shared__ __align__(16) u16 As[3 * 4096];
  __shared__ __align__(16) u16 Bs[3 * 4096];
  const int tid = threadIdx.x;
  const int lane = tid & 63, wave = tid >> 6;
  const int wm = wave >> 2, wn = wave & 3;
  const int l15 = lane & 15, quad = lane >> 4;
  const int row0 = by * 128, col0 = bx * 128;
  f32x4 acc[4][2] = {};
  gemm_core(A, lda, M, row0, B, ldb, N, col0, K, As, Bs, acc, tid, wm, wn, l15, quad);

  float* Cf = (float*)Cv;
  u16* Ch = (u16*)Cv;
  const long cbase = z1 * cS1 + z2 * cS2;
  float ssq = 0.f;
#pragma unroll
  for (int i = 0; i < 4; i++)
#pragma unroll
    for (int j = 0; j < 2; j++)
#pragma unroll
      for (int reg = 0; reg < 4; reg++) {
        int gr = row0 + wm * 64 + i * 16 + quad * 4 + reg;
        int gc = col0 + wn * 32 + j * 16 + l15;
        if (gr >= M || gc >= N) continue;
        float vv = acc[i][j][reg] * alpha;
        if (EPI == EPI_BF16) {
          Ch[cbase + (long)gr * ldc + gc] = f2bf(vv);
        } else if (EPI == EPI_F32) {
          Cf[cbase + (long)gr * ldc + gc] = vv;
        } else if (EPI == EPI_TOKPV) {    // x[b][mm][c*8+f] = acc + xn
          int f = gc / 197, mm = gc - f * 197;
          long o = ((long)z2 * 197 + mm) * 512 + gr * 8 + f;
          float xv = vv + resid[o];
          Cf[o] = xv;
          ssq += xv * xv;
        } else {                          // PATCH: x[b][1+p][gc] = acc + bias
          int b = gr / 196, p = gr - b * 196;
          Cf[((long)b * 197 + 1 + p) * 512 + gc] = vv + resid[gc];
        }
      }
  if (EPI == EPI_TOKPV) {
    __syncthreads();                       // LDS no longer needed by gemm
    float* red = (float*)As;
    red[tid] = ssq; __syncthreads();
    for (int o2 = 256; o2; o2 >>= 1) {
      if (tid < o2) red[tid] += red[tid + o2];
      __syncthreads();
    }
    if (tid == 0) atomicAdd(&sqout[z2], red[0]);
  }
}

// ---------------------------------------------------------------------------
// Token scores, split-K: grid (split=8, b=8) x 256 thr (own structure).
// tsp[(s*8+b)][64][64] partials. 3-slot ring + counted vmcnt.
__global__ __launch_bounds__(256) void token_scores_kernel(const u16* __restrict__ tq,
                                                           const u16* __restrict__ tk,
                                                           float* __restrict__ tsp) {
  int s = blockIdx.x, b = blockIdx.y;
  const u16* A = tq + (long)b * 64 * NTD;
  const u16* B = tk + (long)b * 64 * NTD;
  __shared__ __align__(16) u16 As[3 * 2048];
  __shared__ __align__(16) u16 Bs[3 * 2048];
  int tid = threadIdx.x, lane = tid & 63, w = tid >> 6;
  int l15 = lane & 15, quad = lane >> 4;
  f32x4 acc[4] = {};
  const int r = tid >> 2;
  const int cs = (((tid & 3) ^ ((r >> 1) & 3)) << 3);
  const u16* pa = A + (long)r * NTD + cs;
  const u16* pbp = B + (long)r * NTD + cs;
  const int lb = (tid & ~63) * 8;

  auto stage = [&](int ch, int bi) {
    async_cp16(pa + ch * 32, &As[bi + lb]);
    async_cp16(pbp + ch * 32, &Bs[bi + lb]);
  };
  auto compute = [&](int bi) {
    int row = w * 16 + l15;
    bf16x8 av = *(const bf16x8*)&As[bi + row * 32 + ((quad ^ ((row >> 1) & 3)) << 3)];
#pragma unroll
    for (int j = 0; j < 4; j++) {
      int rb = j * 16 + l15;
      bf16x8 bv = *(const bf16x8*)&Bs[bi + rb * 32 + ((quad ^ ((rb >> 1) & 3)) << 3)];
      acc[j] = __builtin_amdgcn_mfma_f32_16x16x32_bf16(av, bv, acc[j], 0, 0, 0);
    }
  };

  int ch0 = s * 6, nch = (s == 7) ? 7 : 6;
  stage(ch0, 0);
  stage(ch0 + 1, 2048);
  for (int c = 0; c < nch; c++) {
    if (c + 1 < nch) {
      asm volatile("s_waitcnt vmcnt(2)" ::: "memory");
    } else {
      asm volatile("s_waitcnt vmcnt(0)" ::: "memory");
    }
    __builtin_amdgcn_s_barrier();
    if (c + 2 < nch) stage(ch0 + c + 2, ((c + 2) % 3) * 2048);
    compute((c % 3) * 2048);
  }
  if (s == 7) {  // 8-element K tail at k=1568
    const int tb = (nch % 3) * 2048;
    __syncthreads();
    for (int idx = tid; idx < 2048; idx += 256) {
      int rr = idx >> 5, cc = idx & 31;
      int g = ((((cc >> 3) ^ ((rr >> 1) & 3)) << 3)) | (cc & 7);
      As[tb + idx] = (g < 8) ? A[(long)rr * NTD + 1568 + g] : (u16)0;
      Bs[tb + idx] = (g < 8) ? B[(long)rr * NTD + 1568 + g] : (u16)0;
    }
    __syncthreads();
    compute(tb);
  }
  const float sc = rsqrtf(1576.f);
  float* dst = tsp + ((long)(s * 8 + b)) * 4096;
#pragma unroll
  for (int j = 0; j < 4; j++)
#pragma unroll
    for (int reg = 0; reg < 4; reg++) {
      int row = w * 16 + quad * 4 + reg, col = j * 16 + l15;
      dst[row * 64 + col] = acc[j][reg] * sc;
    }
}

// Token softmax: sums 8 split-K partials, softmaxes, writes Pb bf16.
__global__ void softmax_token_kernel(const float* __restrict__ tsp, u16* __restrict__ Pb) {
  int row = blockIdx.x * 4 + (threadIdx.x >> 6);  // 0..511 = b*64+r
  int lane = threadIdx.x & 63;
  int b = row >> 6, r = row & 63;
  float v = 0.f;
#pragma unroll
  for (int p = 0; p < 8; p++) v += tsp[((long)(p * 8 + b)) * 4096 + r * 64 + lane];
  float mx = v;
#pragma unroll
  for (int off = 32; off; off >>= 1) mx = fmaxf(mx, __shfl_xor(mx, off));
  float e = expf(v - mx);
  float sum = e;
#pragma unroll
  for (int off = 32; off; off >>= 1) sum += __shfl_xor(sum, off);
  Pb[(long)row * 64 + lane] = f2bf(e / sum);
}

// ---------------------------------------------------------------------------
// Attn output reduce + residual, vectorized x4; fused per-batch sum(x^2).
// grid 788 x 256. A block (1024 elems) may straddle ONE batch boundary ->
// segmented 2-slot reduce.
__global__ void attn_reduce_kernel(const float* __restrict__ part, const float* __restrict__ bias,
                                   const float* __restrict__ resid, float* __restrict__ x,
                                   float* __restrict__ sqslot) {
  int idx4 = blockIdx.x * 256 + threadIdx.x;
  long base = (long)idx4 * 4;
  int col = (int)(base % ND);
  float4 sv = *(const float4*)(bias + col);
  float4 rv = ((const float4*)resid)[idx4];
  sv.x += rv.x; sv.y += rv.y; sv.z += rv.z; sv.w += rv.w;
#pragma unroll
  for (int h = 0; h < 8; h++) {
    float4 pv = ((const float4*)part)[(h * (XSZ >> 2)) + idx4];
    sv.x += pv.x; sv.y += pv.y; sv.z += pv.z; sv.w += pv.w;
  }
  ((float4*)x)[idx4] = sv;
  float ssq = sv.x * sv.x + sv.y * sv.y + sv.z * sv.z + sv.w * sv.w;
  int b = (int)(base / BMD);
  int bfirst = (int)(((long)blockIdx.x * 1024) / BMD);
  float s0 = (b == bfirst) ? ssq : 0.f;
  float s1 = ssq - s0;
  __shared__ float red0[256], red1[256];
  red0[threadIdx.x] = s0; red1[threadIdx.x] = s1; __syncthreads();
  for (int o = 128; o; o >>= 1) {
    if (threadIdx.x < o) {
      red0[threadIdx.x] += red0[threadIdx.x + o];
      red1[threadIdx.x] += red1[threadIdx.x + o];
    }
    __syncthreads();
  }
  if (threadIdx.x == 0) {
    atomicAdd(&sqslot[bfirst], red0[0]);
    if (red1[0] != 0.f) atomicAdd(&sqslot[bfirst + 1], red1[0]);
  }
}

// ---------------------------------------------------------------------------
// Merged transposes: Wqkv (48 slabs, z = l*24 + w*8 + h) + attn_W (16 slabs:
// z-48 = l*8 + i) + patch_W (z=64). grid (16,24,65); z<64 uses by<16 only.
__global__ void transpose_wa_kernel(const float* __restrict__ Wq, const float* __restrict__ Wk,
                                    const float* __restrict__ Wv, const float* __restrict__ attn_W,
                                    const float* __restrict__ patch_W,
                                    u16* __restrict__ Wt16, u16* __restrict__ Wat16,
                                    u16* __restrict__ pWt) {
  int z = blockIdx.z;
  __shared__ float t[32][33];
  int c0 = blockIdx.x * 32, r0 = blockIdx.y * 32;
  int tx = threadIdx.x, ty = threadIdx.y;
  if (z == 64) {
    // patch_W fp32 (768x512) -> pWt bf16 (512x768); r0<768, c0<512, exact tiles
#pragma unroll
    for (int i = 0; i < 4; i++)
      t[ty + i * 8][tx] = patch_W[(long)(r0 + ty + i * 8) * 512 + c0 + tx];
    __syncthreads();
#pragma unroll
    for (int i = 0; i < 4; i++)
      pWt[(long)(c0 + ty + i * 8) * 768 + r0 + tx] = f2bf(t[tx][ty + i * 8]);
    return;
  }
  if (blockIdx.y >= 16) return;
  const float* src;
  u16* dst;
  long dld;
  if (z < 48) {
    int l = z / 24, rem = z - l * 24, w = rem >> 3, h = rem & 7;
    src = (w == 0 ? Wq : w == 1 ? Wk : Wv) + (long)(l * 8 + h) * 262144;
    dst = Wt16 + (long)z * 262144;
    dld = 512;
  } else {
    int za = z - 48, l = za >> 3, i = za & 7;   // 8 row-blocks per layer
    src = attn_W + (long)l * 4096 * 512 + (long)i * 512 * 512;
    dst = Wat16 + (long)l * 512 * 4096 + (long)i * 512;
    dld = 4096;
  }
#pragma unroll
  for (int i = 0; i < 4; i++)
    t[ty + i * 8][tx] = src[(long)(r0 + ty + i * 8) * 512 + c0 + tx];
  __syncthreads();
#pragma unroll
  for (int i = 0; i < 4; i++)
    dst[(long)(c0 + ty + i * 8) * dld + r0 + tx] = f2bf(t[tx][ty + i * 8]);
}

// Merged tWq/tWk/tWv transpose: grid (50,50,6), z = w*2 + l.
__global__ void t_transpose3_kernel(const float* __restrict__ Wq, const float* __restrict__ Wk,
                                    const float* __restrict__ Wv, u16* __restrict__ dst0) {
  int z = blockIdx.z;
  int w = z >> 1, l = z & 1;
  const float* src = (w == 0 ? Wq : w == 1 ? Wk : Wv) + (long)l * NTD * NTD;
  u16* d = dst0 + (long)z * NTD * NTD;
  __shared__ float t[32][33];
  int c0 = blockIdx.x * 32, r0 = blockIdx.y * 32;
  int tx = threadIdx.x, ty = threadIdx.y;
#pragma unroll
  for (int i = 0; i < 4; i++) {
    int r = r0 + ty + i * 8;
    if (r < NTD && c0 + tx < NTD) t[ty + i * 8][tx] = src[(long)r * NTD + c0 + tx];
  }
  __syncthreads();
#pragma unroll
  for (int i = 0; i < 4; i++) {
    int c = c0 + ty + i * 8;
    if (c < NTD && r0 + tx < NTD) d[(long)c * NTD + r0 + tx] = f2bf(t[tx][ty + i * 8]);
  }
}

// ---------------------------------------------------------------------------
// Fused cls LayerNorm + head GEMM. grid (4,8), 256 thr (LN redone per block).
__global__ void ln_head_kernel(const float* __restrict__ x, const float* __restrict__ g,
                               const float* __restrict__ bb, const float* __restrict__ W,
                               const float* __restrict__ hb, float* __restrict__ out) {
  int b = blockIdx.y, t = threadIdx.x;
  __shared__ float xs[512];
  __shared__ float red[256];
  float v0 = x[(long)b * NM * ND + t];
  float v1 = x[(long)b * NM * ND + 256 + t];
  red[t] = v0 + v1; __syncthreads();
  for (int o = 128; o; o >>= 1) { if (t < o) red[t] += red[t + o]; __syncthreads(); }
  float mu = red[0] / 512.f; __syncthreads();
  float d0 = v0 - mu, d1 = v1 - mu;
  red[t] = d0 * d0 + d1 * d1; __syncthreads();
  for (int o = 128; o; o >>= 1) { if (t < o) red[t] += red[t + o]; __syncthreads(); }
  float inv = rsqrtf(red[0] / 512.f + 1e-5f); __syncthreads();
  xs[t] = d0 * inv * g[t] + bb[t];
  xs[256 + t] = d1 * inv * g[256 + t] + bb[256 + t];
  __syncthreads();
  int n = blockIdx.x * 250 + t;
  if (t < 250 && n < 1000) {
    float acc = hb[n];
    for (int dd = 0; dd < 512; dd++) acc += xs[dd] * W[(long)dd * 1000 + n];
    out[(long)b * 1000 + n] = acc;
  }
}

}  // namespace

extern "C" void kernel_launch(void* const* d_in, const int* in_sizes, int n_in,
                              void* d_out, int out_size, void* d_ws, size_t ws_size,
                              hipStream_t stream) {
  const float* img     = (const float*)d_in[0];
  const float* patch_W = (const float*)d_in[1];
  const float* patch_b = (const float*)d_in[2];
  const float* cls_tok = (const float*)d_in[3];
  const float* rms_s   = (const float*)d_in[4];
  const float* Wq      = (const float*)d_in[5];
  const float* Wk      = (const float*)d_in[6];
  const float* Wv      = (const float*)d_in[7];
  const float* attn_W  = (const float*)d_in[8];
  const float* attn_b  = (const float*)d_in[9];
  const float* tWq     = (const float*)d_in[10];
  const float* tWk     = (const float*)d_in[11];
  const float* tWv     = (const float*)d_in[12];
  const float* ln_g    = (const float*)d_in[13];
  const float* ln_b    = (const float*)d_in[14];
  const float* head_W  = (const float*)d_in[15];
  const float* head_b  = (const float*)d_in[16];
  float* out = (float*)d_out;

  // ---- workspace layout (floats) ----
  float* base = (float*)d_ws;
  long off = 0;
  auto alloc = [&](long n) { float* r = base + off; off += (n + 15) & ~15L; return r; };
  float* cosP = alloc(TABSZ);       // interleaved (cos,sin) float2 table spans
  float* sinP = alloc(TABSZ);       //   cosP..sinP (2*TABSZ floats contiguous)
  float* cosT = alloc(TABSZ);
  float* sinT = alloc(TABSZ);
  float* x    = alloc(XSZ);
  float* xn   = alloc(XSZ);
  float* Wt_f   = alloc(6291456);   // 48 slabs 512x512 bf16, z = l*24+w*8+h
  float* Wat_f  = alloc(2097152);   // (l) 512x4096 bf16
  float* tWt_f  = alloc(7451328);   // (w,l) 1576x1576 bf16
  float* xnb_f  = alloc(XSZ / 2);
  float* pimg_f = alloc(602112);    // 1568x768 bf16
  float* pWt_f  = alloc(196608);    // 512x768 bf16
  float* U      = alloc(16885824);  // union region
  float* ffs    = alloc(64);        // fused sq-sum slots:
                                    //   [0..7]=attn l0, [8..15]=tok l0,
                                    //   [16..23]=attn l1, [24..31]=tok l1 (dead),
                                    //   [32..39]=patch embed (layer-0 RMS)

  u16* Wt16  = (u16*)Wt_f;
  u16* Wat16 = (u16*)Wat_f;
  u16* tWt16 = (u16*)tWt_f;
  u16* xnb   = (u16*)xnb_f;
  u16* pimg  = (u16*)pimg_f;
  u16* pWt   = (u16*)pWt_f;
  // patch split-K partials: 3 x 1568*512 fp32 in U (dead until qkv writes q)
  float* patchp = (float*)U;
  // phase A overlay (contract: kk = q + QSZ, vt = q + 2*QSZ)
  u16* q   = (u16*)U;                 // 6455296 (h, b*m, e)
  u16* kk  = q + QSZ;                 // 6455296
  u16* vt  = kk + QSZ;                // 6815744 (h,b,e,m_pad)
  float* s = (float*)(vt + 6815744);  // region kept for layout (scores now fused)
  u16* pb  = (u16*)(s + 2 * 2483776); // 2622464 (hb,197,208)
  u16* o   = (u16*)s;                 // 6455296 (aliases dead s region)
  float* part = (float*)q;            // 8*XSZ fp32 (aliases dead q,kk)
  // phase B overlay (contract: tkb = tqb + XSZ, tvt = tqb + 2*XSZ)
  u16* yb     = (u16*)U;              // 806912 (b*64+c, 1576)
  float* tprt = (float*)(yb + XSZ);   // 12*XSZ fp32 split partials
  u16* tqb    = (u16*)(tprt + 12 * XSZ);
  u16* tvt    = tqb + 2 * XSZ;        // (b, 1576, 64)
  float* tsp  = (float*)(tvt + XSZ);  // 8 x 8 x 64 x 64
  u16* Pb     = (u16*)(tsp + 262144); // 8*64*64

  const dim3 tt(32, 8);

  // ---- setup ----
  init_kernel<<<5115, 256, 0, stream>>>(img, cls_tok, cosP, sinP, cosT, sinT, pimg, x, ffs);
  transpose_wa_kernel<<<dim3(16, 24, 65), tt, 0, stream>>>(
      Wq, Wk, Wv, attn_W, patch_W, Wt16, Wat16, pWt);
  t_transpose3_kernel<<<dim3(50, 50, 6), tt, 0, stream>>>(tWq, tWk, tWv, tWt16);
  // patch embed, 3-way split-K (K=256 each), fp32 partials -> patchp
  mfma_gemm<EPI_F32><<<dim3(4, 13, 3), 512, 0, stream>>>(
      pimg, pWt, patchp, nullptr, nullptr, 1568, 512, 256, 768, 768, 512, 1.f, 1,
      256, 0, 256, 0, 802816L, 0);
  // reduce partials + bias -> x; fused per-batch ssq (+cls row) -> ffs[32..39]
  patch_reduce_kernel<<<785, 256, 0, stream>>>(patchp, patch_b, cls_tok, x, ffs + 32);

  for (int l = 0; l < 2; l++) {
    const float* scale = rms_s + (long)l * NM * ND;
    float* slotA = ffs + l * 16;       // attn-phase sq-sums for this layer
    float* slotT = ffs + l * 16 + 8;   // token-phase sq-sums for this layer
    // ---- spatial attention ----
    // sq-sums pre-accumulated: patch_reduce (l=0) / previous token-PV (l=1)
    rms_apply_kernel<<<788, 256, 0, stream>>>(
        x, scale, (l == 0) ? ffs + 32 : ffs + 8, 1, xn, xnb);

    // qkv with fused RoPE on q,k
    qkv_kernel<<<dim3(4, 13, 24), 512, 0, stream>>>(xnb, Wt16 + (long)l * 24 * 262144, q, cosP);

    // fused scores + softmax -> pb (s buffer eliminated)
    scores_softmax_kernel<<<dim3(2, 64), 512, 0, stream>>>(q, kk, pb);
    // o = P @ v   (o aliases the dead s region)
    mfma_gemm<EPI_BF16><<<dim3(4, 2, 64), 512, 0, stream>>>(
        pb, vt, o, nullptr, nullptr, 197, 512, 197, MP, MP, 512, 1.f, 64,
        0, 197L * MP, 0, 512L * MP, 0, 197L * 512);
    // attn-proj head partials
    mfma_gemm<EPI_F32><<<dim3(4, 13, 8), 512, 0, stream>>>(
        o, Wat16 + (long)l * 2097152, part, nullptr, nullptr, 1576, 512, 512, 512, 4096, 512,
        1.f, 8, 0, XSZ, 0, 512, 0, XSZ);
    // reduce + residual + fused sum(x^2) into slotA
    attn_reduce_kernel<<<788, 256, 0, stream>>>(part, attn_b + (long)l * ND, xn, x, slotA);

    // ---- token mixing ----
    rms_apply_tok_kernel<<<788, 256, 0, stream>>>(x, scale, slotA, 1, xn, yb);

    // 4-way K split (624 blocks)
    tok_qkv_kernel<<<dim3(4, 13, 12), 512, 0, stream>>>(yb, tWt16, l, tprt);
    token_finish_kernel<<<1576, 256, 0, stream>>>(tprt, cosT, sinT, tqb);

    token_scores_kernel<<<dim3(8, 8), 256, 0, stream>>>(tqb, tqb + XSZ, tsp);
    softmax_token_kernel<<<128, 256, 0, stream>>>(tsp, Pb);
    // token PV: scatter + residual into fp32 x; fused sum(x^2) into slotT
    mfma_gemm<EPI_TOKPV><<<dim3(13, 1, 8), 512, 0, stream>>>(
        Pb, tvt, x, xn, slotT, 64, 1576, 64, 64, 64, 0, 1.f, 8,
        0, 4096, 0, 1576L * 64, 0, 0);
  }

  ln_head_kernel<<<dim3(4, 8), 256, 0, stream>>>(x, ln_g, ln_b, head_W, head_b, out);
}